// Round 15
// baseline (497.153 us; speedup 1.0000x reference)
//
#include <hip/hip_runtime.h>
#include <hip/hip_bf16.h>
#include <cstddef>

#define BB   2
#define CTX  1536
#define QQ   512
#define S_LEN 2048
#define DD   256
#define NH   8
#define DH   32
#define DFF  1024
#define NL   6
#define LIN  20
#define HOUTD 10
#define KHALF (CTX / 2)      // 768 keys per wave-group

typedef _Float16 f16x2 __attribute__((ext_vector_type(2)));
typedef _Float16 f16x4 __attribute__((ext_vector_type(4)));
typedef _Float16 f16x8 __attribute__((ext_vector_type(8)));
typedef float f32x4 __attribute__((ext_vector_type(4)));

#define N4_QKV (NL * 3 * DD * DD / 4)
#define N4_WO  (NL * DD * DD / 4)
#define N4_W1  (NL * DFF * DD / 4)
#define N4_W2  (NL * DD * DFF / 4)

// ---------------- fp32 -> f16 convert (all weights, one launch) ----------------
__global__ __launch_bounds__(256) void cvtall_k(
    const float* __restrict__ wqkv, const float* __restrict__ wo,
    const float* __restrict__ w1, const float* __restrict__ w2,
    _Float16* __restrict__ hqkv, _Float16* __restrict__ ho,
    _Float16* __restrict__ h1, _Float16* __restrict__ h2)
{
    int i = blockIdx.x * 256 + threadIdx.x;
    const float* s; _Float16* t; int j = i;
    if (j < N4_QKV) { s = wqkv; t = hqkv; }
    else if ((j -= N4_QKV) < N4_WO) { s = wo; t = ho; }
    else if ((j -= N4_WO) < N4_W1) { s = w1; t = h1; }
    else if ((j -= N4_W1) < N4_W2) { s = w2; t = h2; }
    else return;
    float4 v = ((const float4*)s)[j];
    f16x4 h = {(_Float16)v.x, (_Float16)v.y, (_Float16)v.z, (_Float16)v.w};
    ((f16x4*)t)[j] = h;
}

// ---------------- Embed: Z[b*S+s][d] (+f16 copy, +t_all float) ----------------
__global__ __launch_bounds__(256) void embed_k(
    const float* __restrict__ ctx_x, const float* __restrict__ ctx_z,
    const float* __restrict__ qry_x,
    const float* __restrict__ W_ctx, const float* __restrict__ b_ctx,
    const float* __restrict__ W_qry, const float* __restrict__ b_qry,
    const int* __restrict__ t_ctx, const int* __restrict__ t_qry,
    float* __restrict__ Z, _Float16* __restrict__ Zh, float* __restrict__ tf)
{
    int row = blockIdx.x;            // 0..4095
    int d = threadIdx.x;             // 0..255
    int b = row >> 11, s = row & (S_LEN - 1);
    float acc;
    if (s < CTX) {
        const float* x1 = ctx_x + (size_t)(b * CTX + s) * LIN;
        const float* x2 = ctx_z + (size_t)(b * CTX + s) * HOUTD;
        const float* w = W_ctx + (size_t)d * (LIN + HOUTD);
        acc = b_ctx[d];
        #pragma unroll
        for (int i = 0; i < LIN; i++) acc += x1[i] * w[i];
        #pragma unroll
        for (int i = 0; i < HOUTD; i++) acc += x2[i] * w[LIN + i];
        if (d == 0) tf[row] = (float)t_ctx[b * CTX + s];
    } else {
        int qi = s - CTX;
        const float* x1 = qry_x + (size_t)(b * QQ + qi) * LIN;
        const float* w = W_qry + (size_t)d * (LIN + HOUTD);
        acc = b_qry[d];
        #pragma unroll
        for (int i = 0; i < LIN; i++) acc += x1[i] * w[i];
        if (d == 0) tf[row] = (float)t_qry[b * QQ + qi];
    }
    Z[(size_t)row * DD + d] = acc;
    Zh[(size_t)row * DD + d] = (_Float16)acc;
}

// ---------------- MFMA f16 GEMM 64x64 (dbuf LDS, pad-40) ----------------
// mode 0: fp32 out Y
__global__ __launch_bounds__(256) void hgemm_k(
    const _Float16* __restrict__ X, const _Float16* __restrict__ W,
    const float* __restrict__ bias, float* __restrict__ Y,
    int M, int N, int K)
{
    __shared__ _Float16 Ah[2][64][40];
    __shared__ _Float16 Bh[2][64][40];
    const int tid = threadIdx.x;
    const int bm = blockIdx.x << 6, bn = blockIdx.y << 6;
    const int lr = tid >> 2;
    const int lk = (tid & 3) << 3;
    const int w = tid >> 6, lane = tid & 63;
    const int c = lane & 15, g = lane >> 4;
    const int wm = (w >> 1) << 5, wn = (w & 1) << 5;

    f32x4 acc00 = {0.f,0.f,0.f,0.f}, acc01 = {0.f,0.f,0.f,0.f};
    f32x4 acc10 = {0.f,0.f,0.f,0.f}, acc11 = {0.f,0.f,0.f,0.f};

    const _Float16* Xp = X + (size_t)(bm + lr) * K + lk;
    const _Float16* Wp = W + (size_t)(bn + lr) * K + lk;

    f16x8 xa = *(const f16x8*)Xp;
    f16x8 wb = *(const f16x8*)Wp;
    const int nt = K >> 5;
    int buf = 0;
    for (int t = 0; t < nt; t++) {
        *(f16x8*)&Ah[buf][lr][lk] = xa;
        *(f16x8*)&Bh[buf][lr][lk] = wb;
        __syncthreads();
        if (t + 1 < nt) {
            xa = *(const f16x8*)(Xp + ((size_t)(t + 1) << 5));
            wb = *(const f16x8*)(Wp + ((size_t)(t + 1) << 5));
        }
        f16x8 a0 = *(const f16x8*)&Ah[buf][wm + c][g << 3];
        f16x8 a1 = *(const f16x8*)&Ah[buf][wm + 16 + c][g << 3];
        f16x8 b0 = *(const f16x8*)&Bh[buf][wn + c][g << 3];
        f16x8 b1 = *(const f16x8*)&Bh[buf][wn + 16 + c][g << 3];
        acc00 = __builtin_amdgcn_mfma_f32_16x16x32_f16(a0, b0, acc00, 0, 0, 0);
        acc01 = __builtin_amdgcn_mfma_f32_16x16x32_f16(a0, b1, acc01, 0, 0, 0);
        acc10 = __builtin_amdgcn_mfma_f32_16x16x32_f16(a1, b0, acc10, 0, 0, 0);
        acc11 = __builtin_amdgcn_mfma_f32_16x16x32_f16(a1, b1, acc11, 0, 0, 0);
        buf ^= 1;
    }

    f32x4 accs[2][2] = {{acc00, acc01}, {acc10, acc11}};
    #pragma unroll
    for (int fm = 0; fm < 2; fm++) {
        #pragma unroll
        for (int fn = 0; fn < 2; fn++) {
            int colb = bn + wn + (fn << 4) + c;
            float bv = bias[colb];
            #pragma unroll
            for (int r = 0; r < 4; r++) {
                int row = bm + wm + (fm << 4) + (g << 2) + r;
                Y[(size_t)row * N + colb] = accs[fm][fn][r] + bv;
            }
        }
    }
}

// ---------------- MFMA f16 GEMM 128x128 (dbuf LDS, pad-40) ----------------
// mode 1: relu -> f16 Yh   mode 2: f16 Q,K:[B,NH,S,DH] V:[B,NH,DH,S]
__global__ __launch_bounds__(256) void hgemm128_k(
    const _Float16* __restrict__ X, const _Float16* __restrict__ W,
    const float* __restrict__ bias, _Float16* __restrict__ Yh,
    int M, int N, int K, int mode,
    _Float16* __restrict__ Qh, _Float16* __restrict__ Kh, _Float16* __restrict__ Vh)
{
    __shared__ _Float16 Ah[2][128][40];
    __shared__ _Float16 Bh[2][128][40];
    const int tid = threadIdx.x;
    const int bm = blockIdx.x << 7, bn = blockIdx.y << 7;
    const int lr = tid >> 1, lc = (tid & 1) << 4;   // staging: row, col base
    const int w = tid >> 6, lane = tid & 63;
    const int c = lane & 15, g = lane >> 4;
    const int wr = (w >> 1) << 6, wc = (w & 1) << 6;

    f32x4 acc[4][4] = {};

    const _Float16* Xp = X + (size_t)(bm + lr) * K + lc;
    const _Float16* Wp = W + (size_t)(bn + lr) * K + lc;

    f16x8 xa0 = *(const f16x8*)Xp;
    f16x8 xa1 = *(const f16x8*)(Xp + 8);
    f16x8 wb0 = *(const f16x8*)Wp;
    f16x8 wb1 = *(const f16x8*)(Wp + 8);
    const int nt = K >> 5;
    int buf = 0;
    for (int t = 0; t < nt; t++) {
        *(f16x8*)&Ah[buf][lr][lc] = xa0;
        *(f16x8*)&Ah[buf][lr][lc + 8] = xa1;
        *(f16x8*)&Bh[buf][lr][lc] = wb0;
        *(f16x8*)&Bh[buf][lr][lc + 8] = wb1;
        __syncthreads();
        if (t + 1 < nt) {
            int o = (t + 1) << 5;
            xa0 = *(const f16x8*)(Xp + o);
            xa1 = *(const f16x8*)(Xp + o + 8);
            wb0 = *(const f16x8*)(Wp + o);
            wb1 = *(const f16x8*)(Wp + o + 8);
        }
        f16x8 af[4], bf[4];
        #pragma unroll
        for (int fm = 0; fm < 4; fm++)
            af[fm] = *(const f16x8*)&Ah[buf][wr + (fm << 4) + c][g << 3];
        #pragma unroll
        for (int fn = 0; fn < 4; fn++)
            bf[fn] = *(const f16x8*)&Bh[buf][wc + (fn << 4) + c][g << 3];
        #pragma unroll
        for (int fm = 0; fm < 4; fm++)
            #pragma unroll
            for (int fn = 0; fn < 4; fn++)
                acc[fm][fn] = __builtin_amdgcn_mfma_f32_16x16x32_f16(af[fm], bf[fn], acc[fm][fn], 0, 0, 0);
        buf ^= 1;
    }

    #pragma unroll
    for (int fm = 0; fm < 4; fm++) {
        #pragma unroll
        for (int fn = 0; fn < 4; fn++) {
            int colb = bn + wc + (fn << 4) + c;
            float bv = bias[colb];
            #pragma unroll
            for (int r = 0; r < 4; r++) {
                int row = bm + wr + (fm << 4) + (g << 2) + r;
                float v = acc[fm][fn][r] + bv;
                if (mode == 1) {
                    Yh[(size_t)row * N + colb] = (_Float16)fmaxf(v, 0.0f);
                } else {
                    int which = colb >> 8, h = (colb >> 5) & 7, d = colb & 31;
                    int bb2 = row >> 11, ss = row & (S_LEN - 1);
                    int bhi = (bb2 << 3) + h;
                    _Float16 hv = (_Float16)v;
                    if (which == 0)      Qh[((size_t)bhi * S_LEN + ss) * DH + d] = hv;
                    else if (which == 1) Kh[((size_t)bhi * S_LEN + ss) * DH + d] = hv;
                    else                 Vh[((size_t)bhi * DH + d) * S_LEN + ss] = hv;
                }
            }
        }
    }
}

// ---------------- fused Wo GEMM + residual + LayerNorm (BM=16, grid 256) ----------------
__global__ __launch_bounds__(256) void gemmln_k(
    const _Float16* __restrict__ X, const _Float16* __restrict__ W,
    const float* __restrict__ bias, float* __restrict__ Z,
    _Float16* __restrict__ Zh, const float* __restrict__ sw,
    const float* __restrict__ bw)
{
    __shared__ _Float16 Ast[2][16][40];
    __shared__ _Float16 Bst[2][256][40];
    __shared__ float lred[4][16][2];
    const int tid = threadIdx.x;
    const int bm = blockIdx.x << 4;
    const int w = tid >> 6, lane = tid & 63;
    const int c = lane & 15, g = lane >> 4;
    const int br = tid >> 2, bk = (tid & 3) << 3;

    f32x4 acc[4] = {};
    const _Float16* Wp = W + (size_t)br * DD + bk;
    f16x8 p0 = *(const f16x8*)Wp;
    f16x8 p1 = *(const f16x8*)(Wp + (size_t)64 * DD);
    f16x8 p2 = *(const f16x8*)(Wp + (size_t)128 * DD);
    f16x8 p3 = *(const f16x8*)(Wp + (size_t)192 * DD);
    f16x8 xa;
    if (tid < 64) xa = *(const f16x8*)(X + (size_t)(bm + br) * DD + bk);
    int buf = 0;
    #pragma unroll
    for (int t = 0; t < 8; t++) {
        if (tid < 64) *(f16x8*)&Ast[buf][br][bk] = xa;
        *(f16x8*)&Bst[buf][br][bk] = p0;
        *(f16x8*)&Bst[buf][br + 64][bk] = p1;
        *(f16x8*)&Bst[buf][br + 128][bk] = p2;
        *(f16x8*)&Bst[buf][br + 192][bk] = p3;
        __syncthreads();
        if (t < 7) {
            int o = (t + 1) << 5;
            if (tid < 64) xa = *(const f16x8*)(X + (size_t)(bm + br) * DD + o + bk);
            p0 = *(const f16x8*)(Wp + o);
            p1 = *(const f16x8*)(Wp + (size_t)64 * DD + o);
            p2 = *(const f16x8*)(Wp + (size_t)128 * DD + o);
            p3 = *(const f16x8*)(Wp + (size_t)192 * DD + o);
        }
        f16x8 a = *(const f16x8*)&Ast[buf][c][g << 3];
        #pragma unroll
        for (int f = 0; f < 4; f++) {
            f16x8 bfr = *(const f16x8*)&Bst[buf][(w << 6) + (f << 4) + c][g << 3];
            acc[f] = __builtin_amdgcn_mfma_f32_16x16x32_f16(a, bfr, acc[f], 0, 0, 0);
        }
        buf ^= 1;
    }

    float vals[4][4];
    float s1[4] = {0.f,0.f,0.f,0.f}, s2[4] = {0.f,0.f,0.f,0.f};
    #pragma unroll
    for (int f = 0; f < 4; f++) {
        int col = (w << 6) + (f << 4) + c;
        float bv = bias[col];
        #pragma unroll
        for (int r = 0; r < 4; r++) {
            int row = bm + (g << 2) + r;
            float v = acc[f][r] + bv + Z[(size_t)row * DD + col];
            vals[f][r] = v; s1[r] += v; s2[r] += v * v;
        }
    }
    #pragma unroll
    for (int off = 1; off < 16; off <<= 1) {
        #pragma unroll
        for (int r = 0; r < 4; r++) {
            s1[r] += __shfl_xor(s1[r], off, 64);
            s2[r] += __shfl_xor(s2[r], off, 64);
        }
    }
    if (c == 0) {
        #pragma unroll
        for (int r = 0; r < 4; r++) {
            lred[w][(g << 2) + r][0] = s1[r];
            lred[w][(g << 2) + r][1] = s2[r];
        }
    }
    __syncthreads();
    float mu_r[4], rs_r[4];
    #pragma unroll
    for (int r = 0; r < 4; r++) {
        int lr_ = (g << 2) + r;
        float S1 = lred[0][lr_][0] + lred[1][lr_][0] + lred[2][lr_][0] + lred[3][lr_][0];
        float S2 = lred[0][lr_][1] + lred[1][lr_][1] + lred[2][lr_][1] + lred[3][lr_][1];
        float mu = S1 * (1.0f / 256.0f);
        float var = S2 * (1.0f / 256.0f) - mu * mu;
        mu_r[r] = mu; rs_r[r] = rsqrtf(var + 1e-5f);
    }
    #pragma unroll
    for (int f = 0; f < 4; f++) {
        int col = (w << 6) + (f << 4) + c;
        float swv = sw[col], bwv = bw[col];
        #pragma unroll
        for (int r = 0; r < 4; r++) {
            int row = bm + (g << 2) + r;
            float o = (vals[f][r] - mu_r[r]) * rs_r[r] * swv + bwv;
            Z[(size_t)row * DD + col] = o;
            Zh[(size_t)row * DD + col] = (_Float16)o;
        }
    }
}

// ---------------- Residual + LN, one WAVE per row (no LDS, no barrier) ----------------
__global__ __launch_bounds__(256) void ln4_k(
    float* __restrict__ Z, const float* __restrict__ Y,
    const float* __restrict__ sw, const float* __restrict__ bw,
    _Float16* __restrict__ Zh)
{
    const int w = threadIdx.x >> 6, lane = threadIdx.x & 63;
    const int row = (blockIdx.x << 2) + w;
    float4 z = ((const float4*)(Z + (size_t)row * DD))[lane];
    float4 y = ((const float4*)(Y + (size_t)row * DD))[lane];
    float x0 = z.x + y.x, x1 = z.y + y.y, x2 = z.z + y.z, x3 = z.w + y.w;
    float s1 = (x0 + x1) + (x2 + x3);
    float s2 = (x0 * x0 + x1 * x1) + (x2 * x2 + x3 * x3);
    #pragma unroll
    for (int off = 1; off < 64; off <<= 1) {
        s1 += __shfl_xor(s1, off, 64);
        s2 += __shfl_xor(s2, off, 64);
    }
    float mu = s1 * (1.0f / 256.0f);
    float var = s2 * (1.0f / 256.0f) - mu * mu;
    float rs = rsqrtf(var + 1e-5f);
    float4 sv = ((const float4*)sw)[lane];
    float4 bv = ((const float4*)bw)[lane];
    float o0 = (x0 - mu) * rs * sv.x + bv.x;
    float o1 = (x1 - mu) * rs * sv.y + bv.y;
    float o2 = (x2 - mu) * rs * sv.z + bv.z;
    float o3 = (x3 - mu) * rs * sv.w + bv.w;
    ((float4*)(Z + (size_t)row * DD))[lane] = make_float4(o0, o1, o2, o3);
    f16x4 oh = {(_Float16)o0, (_Float16)o1, (_Float16)o2, (_Float16)o3};
    ((f16x4*)(Zh + (size_t)row * DD))[lane] = oh;
}

// ---------------- MFMA flash attention (r14 config: 1024 thr, 2wg x 8qt) ----------------
__global__ __launch_bounds__(1024, 4) void attn_k(
    const _Float16* __restrict__ Qf, const _Float16* __restrict__ Kf,
    const _Float16* __restrict__ Vf, const float* __restrict__ tf_all,
    const float* __restrict__ alpha, _Float16* __restrict__ O)
{
    const int bh = blockIdx.x >> 4;           // /(S/128)=16
    const int itile = blockIdx.x & 15;
    const int b = bh >> 3, h = bh & 7;
    const int tid = threadIdx.x;
    const int w16 = tid >> 6;                 // 0..15
    const int wg = w16 >> 3;                  // key-split 0/1
    const int wq = w16 & 7;                   // query tile 0..7
    const int ltid = tid & 511;               // within wave-group
    const int lane = tid & 63;
    const int c = lane & 15, g = lane >> 4;
    const int i0 = (itile << 7) + (wq << 4);
    const int jbase = wg * KHALF;

    __shared__ __align__(16) char smem[38912];
    _Float16 (*Kl)[2][64][40] = (_Float16(*)[2][64][40])smem;
    _Float16 (*Vl)[2][32][72] = (_Float16(*)[2][32][72])(smem + 20480);
    float (*sacc)[16][36] = (float(*)[16][36])smem;
    float (*sml)[2][16] = (float(*)[2][16])(smem + 36864);

    const float LOG2E = 1.44269504088896f;
    const float sc2 = 0.17677669529663687f * LOG2E;
    const float ah2 = alpha[h] * LOG2E;

    const _Float16* Qbh = Qf + (size_t)bh * S_LEN * DH;
    const _Float16* Kbh = Kf + (size_t)bh * S_LEN * DH;
    const _Float16* Vbh = Vf + (size_t)bh * DH * S_LEN;
    const float* tb = tf_all + b * S_LEN;

    f16x8 qfrag = *(const f16x8*)(Qbh + (size_t)(i0 + c) * DH + (g << 3));
    const float ti = tb[i0 + c];

    const int lh = ltid & 255;
    const int kr = lh >> 2, kc = (lh & 3) << 3;
    const int vr = lh >> 3, vc = (lh & 7) << 3;
    const bool doK = (ltid < 256);

    float m2 = -3.0e38f, l = 0.0f;
    f32x4 acc0 = {0.f, 0.f, 0.f, 0.f};
    f32x4 acc1 = {0.f, 0.f, 0.f, 0.f};
    const f32x4 zero = {0.f, 0.f, 0.f, 0.f};

    f16x8 pre;
    if (doK) pre = *(const f16x8*)(Kbh + (size_t)(jbase + kr) * DH + kc);
    else     pre = *(const f16x8*)(Vbh + (size_t)vr * S_LEN + jbase + vc);
    int buf = 0;

    for (int kt = 0; kt < KHALF; kt += 64) {
        if (doK) *(f16x8*)&Kl[wg][buf][kr][kc] = pre;
        else     *(f16x8*)&Vl[wg][buf][vr][vc] = pre;
        __syncthreads();
        if (kt + 64 < KHALF) {
            if (doK) pre = *(const f16x8*)(Kbh + (size_t)(jbase + kt + 64 + kr) * DH + kc);
            else     pre = *(const f16x8*)(Vbh + (size_t)vr * S_LEN + jbase + kt + 64 + vc);
        }
        #pragma unroll
        for (int jj = 0; jj < 64; jj += 32) {
            const int j0 = jbase + kt + jj;
            f16x8 kf0 = *(const f16x8*)&Kl[wg][buf][jj + c][g << 3];
            f16x8 kf1 = *(const f16x8*)&Kl[wg][buf][jj + 16 + c][g << 3];
            f32x4 dA = __builtin_amdgcn_mfma_f32_16x16x32_f16(kf0, qfrag, zero, 0, 0, 0);
            f32x4 dB = __builtin_amdgcn_mfma_f32_16x16x32_f16(kf1, qfrag, zero, 0, 0, 0);
            float4 tjA = *(const float4*)(tb + j0 + (g << 2));
            float4 tjB = *(const float4*)(tb + j0 + 16 + (g << 2));
            float eA0 = ti - tjA.x, eA1 = ti - tjA.y, eA2 = ti - tjA.z, eA3 = ti - tjA.w;
            float eB0 = ti - tjB.x, eB1 = ti - tjB.y, eB2 = ti - tjB.z, eB3 = ti - tjB.w;
            float sA0 = (eA0 >= 0.f) ? dA[0] * sc2 - ah2 * eA0 : -1e9f;
            float sA1 = (eA1 >= 0.f) ? dA[1] * sc2 - ah2 * eA1 : -1e9f;
            float sA2 = (eA2 >= 0.f) ? dA[2] * sc2 - ah2 * eA2 : -1e9f;
            float sA3 = (eA3 >= 0.f) ? dA[3] * sc2 - ah2 * eA3 : -1e9f;
            float sB0 = (eB0 >= 0.f) ? dB[0] * sc2 - ah2 * eB0 : -1e9f;
            float sB1 = (eB1 >= 0.f) ? dB[1] * sc2 - ah2 * eB1 : -1e9f;
            float sB2 = (eB2 >= 0.f) ? dB[2] * sc2 - ah2 * eB2 : -1e9f;
            float sB3 = (eB3 >= 0.f) ? dB[3] * sc2 - ah2 * eB3 : -1e9f;
            float pmaxl = fmaxf(fmaxf(fmaxf(sA0, sA1), fmaxf(sA2, sA3)),
                                fmaxf(fmaxf(sB0, sB1), fmaxf(sB2, sB3)));
            if (__any(pmaxl > m2 + 8.0f)) {
                float pm = fmaxf(pmaxl, __shfl_xor(pmaxl, 16, 64));
                pm = fmaxf(pm, __shfl_xor(pm, 32, 64));
                float mnew = fmaxf(m2, pm);
                float fsc = __builtin_amdgcn_exp2f(m2 - mnew);
                m2 = mnew;
                l *= fsc; acc0 *= fsc; acc1 *= fsc;
            }
            float pA0 = __builtin_amdgcn_exp2f(sA0 - m2);
            float pA1 = __builtin_amdgcn_exp2f(sA1 - m2);
            float pA2 = __builtin_amdgcn_exp2f(sA2 - m2);
            float pA3 = __builtin_amdgcn_exp2f(sA3 - m2);
            float pB0 = __builtin_amdgcn_exp2f(sB0 - m2);
            float pB1 = __builtin_amdgcn_exp2f(sB1 - m2);
            float pB2 = __builtin_amdgcn_exp2f(sB2 - m2);
            float pB3 = __builtin_amdgcn_exp2f(sB3 - m2);
            l += ((pA0 + pA1) + (pA2 + pA3)) + ((pB0 + pB1) + (pB2 + pB3));
            f16x4 pfA = {(_Float16)pA0, (_Float16)pA1, (_Float16)pA2, (_Float16)pA3};
            f16x4 pfB = {(_Float16)pB0, (_Float16)pB1, (_Float16)pB2, (_Float16)pB3};
            f16x4 vA0 = *(const f16x4*)&Vl[wg][buf][c][jj + (g << 2)];
            f16x4 vA1 = *(const f16x4*)&Vl[wg][buf][16 + c][jj + (g << 2)];
            f16x4 vB0 = *(const f16x4*)&Vl[wg][buf][c][jj + 16 + (g << 2)];
            f16x4 vB1 = *(const f16x4*)&Vl[wg][buf][16 + c][jj + 16 + (g << 2)];
            acc0 = __builtin_amdgcn_mfma_f32_16x16x16f16(vA0, pfA, acc0, 0, 0, 0);
            acc0 = __builtin_amdgcn_mfma_f32_16x16x16f16(vB0, pfB, acc0, 0, 0, 0);
            acc1 = __builtin_amdgcn_mfma_f32_16x16x16f16(vA1, pfA, acc1, 0, 0, 0);
            acc1 = __builtin_amdgcn_mfma_f32_16x16x16f16(vB1, pfB, acc1, 0, 0, 0);
        }
        buf ^= 1;
    }

    l += __shfl_xor(l, 16, 64);
    l += __shfl_xor(l, 32, 64);

    __syncthreads();
    *(f32x4*)&sacc[w16][c][g << 2] = acc0;
    *(f32x4*)&sacc[w16][c][16 + (g << 2)] = acc1;
    if (g == 0) { sml[w16][0][c] = m2; sml[w16][1][c] = l; }
    __syncthreads();

    {
        const int qt = tid >> 7;
        const int q = (tid >> 3) & 15;
        const int dh0 = (tid & 7) << 2;
        float m0 = sml[qt][0][q], m1 = sml[qt + 8][0][q];
        float M = fmaxf(m0, m1);
        float f0 = __builtin_amdgcn_exp2f(m0 - M);
        float f1 = __builtin_amdgcn_exp2f(m1 - M);
        float L = sml[qt][1][q] * f0 + sml[qt + 8][1][q] * f1;
        float a0 = sacc[qt][q][dh0 + 0] * f0 + sacc[qt + 8][q][dh0 + 0] * f1;
        float a1 = sacc[qt][q][dh0 + 1] * f0 + sacc[qt + 8][q][dh0 + 1] * f1;
        float a2 = sacc[qt][q][dh0 + 2] * f0 + sacc[qt + 8][q][dh0 + 2] * f1;
        float a3 = sacc[qt][q][dh0 + 3] * f0 + sacc[qt + 8][q][dh0 + 3] * f1;
        if (M < -4.9e8f) {
            float vs0 = 0.f, vs1 = 0.f, vs2 = 0.f, vs3 = 0.f;
            const _Float16* vp = Vbh + (size_t)dh0 * S_LEN + CTX;
            for (int j = 0; j < QQ; j += 8) {
                f16x8 x0 = *(const f16x8*)(vp + j);
                f16x8 x1 = *(const f16x8*)(vp + S_LEN + j);
                f16x8 x2 = *(const f16x8*)(vp + 2 * S_LEN + j);
                f16x8 x3 = *(const f16x8*)(vp + 3 * S_LEN + j);
                #pragma unroll
                for (int e = 0; e < 8; e++) {
                    vs0 += (float)x0[e]; vs1 += (float)x1[e];
                    vs2 += (float)x2[e]; vs3 += (float)x3[e];
                }
            }
            a0 += vs0; a1 += vs1; a2 += vs2; a3 += vs3;
            L += (float)QQ;
        }
        float inv = 1.0f / L;
        int row = b * S_LEN + (itile << 7) + (qt << 4) + q;
        f16x4 o = {(_Float16)(a0 * inv), (_Float16)(a1 * inv),
                   (_Float16)(a2 * inv), (_Float16)(a3 * inv)};
        *(f16x4*)(O + (size_t)row * DD + h * DH + dh0) = o;
    }
}

// ---------------- Output head ----------------
__global__ __launch_bounds__(256) void outhead_k(
    const float* __restrict__ Z, const float* __restrict__ Wout,
    const float* __restrict__ bout, float* __restrict__ out)
{
    int tid = threadIdx.x;
    int rloc = tid >> 4, ho = tid & 15;
    int qrow = blockIdx.x * 16 + rloc;
    int b = qrow >> 9, qi = qrow & (QQ - 1);
    if (ho < HOUTD) {
        const float* z = Z + (size_t)(b * S_LEN + CTX + qi) * DD;
        const float* wr = Wout + (size_t)ho * DD;
        float s = 0.0f;
        for (int d = 0; d < DD; d += 4) {
            float4 zv = *(const float4*)(z + d);
            float4 wv = *(const float4*)(wr + d);
            s += zv.x * wv.x + zv.y * wv.y + zv.z * wv.z + zv.w * wv.w;
        }
        out[(size_t)(b * QQ + qi) * HOUTD + ho] = s + bout[ho];
    }
}

extern "C" void kernel_launch(void* const* d_in, const int* in_sizes, int n_in,
                              void* d_out, int out_size, void* d_ws, size_t ws_size,
                              hipStream_t stream) {
    (void)in_sizes; (void)n_in; (void)out_size; (void)ws_size;
    const float* ctx_x = (const float*)d_in[0];
    const float* ctx_z = (const float*)d_in[1];
    const float* qry_x = (const float*)d_in[2];
    const int* t_ctx = (const int*)d_in[3];
    const int* t_qry = (const int*)d_in[4];
    const float* W_ctx = (const float*)d_in[5];
    const float* b_ctx = (const float*)d_in[6];
    const float* W_qry = (const float*)d_in[7];
    const float* b_qry = (const float*)d_in[8];
    const float* alpha = (const float*)d_in[9];
    const float* Wqkv = (const float*)d_in[10];
    const float* bqkv = (const float*)d_in[11];
    const float* Wo = (const float*)d_in[12];
    const float* bo = (const float*)d_in[13];
    const float* ln1_s = (const float*)d_in[14];
    const float* ln1_b = (const float*)d_in[15];
    const float* W1 = (const float*)d_in[16];
    const float* b1 = (const float*)d_in[17];
    const float* W2 = (const float*)d_in[18];
    const float* b2 = (const float*)d_in[19];
    const float* ln2_s = (const float*)d_in[20];
    const float* ln2_b = (const float*)d_in[21];
    const float* W_out = (const float*)d_in[22];
    const float* b_out = (const float*)d_in[23];

    float* ws = (float*)d_ws;
    const size_t MTOT = (size_t)BB * S_LEN;       // 4096
    const size_t ZSZ = MTOT * DD;                 // 1M floats
    float* Z   = ws;                              // [0, 1M) f32
    float* Yb  = ws + ZSZ;                        // [1M, 2M) f32
    _Float16* Zh   = (_Float16*)(ws + 2 * ZSZ);          // 1M halfs
    _Float16* AYh  = (_Float16*)(ws + 2 * ZSZ + ZSZ / 2);
    _Float16* FF1h = (_Float16*)(ws + 3 * ZSZ);          // 4M halfs -> [3M,5M)
    _Float16* Qh   = (_Float16*)(ws + 5 * ZSZ);
    _Float16* Kh   = (_Float16*)(ws + 5 * ZSZ + ZSZ / 2);
    _Float16* Vh   = (_Float16*)(ws + 6 * ZSZ);
    float* tf_all  = ws + 6 * ZSZ + ZSZ / 2;             // 4096 floats
    _Float16* Whqkv = (_Float16*)(ws + 6 * ZSZ + ZSZ / 2 + 4096);
    _Float16* Who   = Whqkv + (size_t)NL * 3 * DD * DD;
    _Float16* Wh1   = Who   + (size_t)NL * DD * DD;
    _Float16* Wh2   = Wh1   + (size_t)NL * DFF * DD;

    {
        int n4tot = N4_QKV + N4_WO + N4_W1 + N4_W2;
        cvtall_k<<<(n4tot + 255) / 256, 256, 0, stream>>>(
            Wqkv, Wo, W1, W2, Whqkv, Who, Wh1, Wh2);
    }

    embed_k<<<MTOT, 256, 0, stream>>>(ctx_x, ctx_z, qry_x, W_ctx, b_ctx, W_qry, b_qry,
                                      t_ctx, t_qry, Z, Zh, tf_all);

    for (int l = 0; l < NL; l++) {
        hgemm128_k<<<dim3(MTOT / 128, (3 * DD) / 128), 256, 0, stream>>>(
            Zh, Whqkv + (size_t)l * 3 * DD * DD, bqkv + (size_t)l * 3 * DD,
            nullptr, (int)MTOT, 3 * DD, DD, 2, Qh, Kh, Vh);
        attn_k<<<BB * NH * (S_LEN / 128), 1024, 0, stream>>>(
            Qh, Kh, Vh, tf_all, alpha, AYh);
        gemmln_k<<<MTOT / 16, 256, 0, stream>>>(
            AYh, Who + (size_t)l * DD * DD, bo + (size_t)l * DD,
            Z, Zh, ln1_s + (size_t)l * DD, ln1_b + (size_t)l * DD);
        hgemm128_k<<<dim3(MTOT / 128, DFF / 128), 256, 0, stream>>>(
            Zh, Wh1 + (size_t)l * DFF * DD, b1 + (size_t)l * DFF,
            FF1h, (int)MTOT, DFF, DD, 1, nullptr, nullptr, nullptr);
        hgemm_k<<<dim3(MTOT / 64, DD / 64), 256, 0, stream>>>(
            FF1h, Wh2 + (size_t)l * DD * DFF, b2 + (size_t)l * DD,
            Yb, (int)MTOT, DD, DFF);
        ln4_k<<<MTOT / 4, 256, 0, stream>>>(
            Z, Yb, ln2_s + (size_t)l * DD, ln2_b + (size_t)l * DD, Zh);
    }

    outhead_k<<<(BB * QQ) / 16, 256, 0, stream>>>(Z, W_out, b_out, (float*)d_out);
}

// Round 16
// 439.060 us; speedup vs baseline: 1.1323x; 1.1323x over previous
//
#include <hip/hip_runtime.h>
#include <hip/hip_bf16.h>
#include <cstddef>

#define BB   2
#define CTX  1536
#define QQ   512
#define S_LEN 2048
#define DD   256
#define NH   8
#define DH   32
#define DFF  1024
#define NL   6
#define LIN  20
#define HOUTD 10
#define KHALF (CTX / 2)      // 768 keys per wave-group

typedef _Float16 f16x2 __attribute__((ext_vector_type(2)));
typedef _Float16 f16x4 __attribute__((ext_vector_type(4)));
typedef _Float16 f16x8 __attribute__((ext_vector_type(8)));
typedef float f32x4 __attribute__((ext_vector_type(4)));

#define N4_QKV (NL * 3 * DD * DD / 4)
#define N4_WO  (NL * DD * DD / 4)
#define N4_W1  (NL * DFF * DD / 4)
#define N4_W2  (NL * DD * DFF / 4)

// ---------------- fp32 -> f16 convert (all weights, one launch) ----------------
__global__ __launch_bounds__(256) void cvtall_k(
    const float* __restrict__ wqkv, const float* __restrict__ wo,
    const float* __restrict__ w1, const float* __restrict__ w2,
    _Float16* __restrict__ hqkv, _Float16* __restrict__ ho,
    _Float16* __restrict__ h1, _Float16* __restrict__ h2)
{
    int i = blockIdx.x * 256 + threadIdx.x;
    const float* s; _Float16* t; int j = i;
    if (j < N4_QKV) { s = wqkv; t = hqkv; }
    else if ((j -= N4_QKV) < N4_WO) { s = wo; t = ho; }
    else if ((j -= N4_WO) < N4_W1) { s = w1; t = h1; }
    else if ((j -= N4_W1) < N4_W2) { s = w2; t = h2; }
    else return;
    float4 v = ((const float4*)s)[j];
    f16x4 h = {(_Float16)v.x, (_Float16)v.y, (_Float16)v.z, (_Float16)v.w};
    ((f16x4*)t)[j] = h;
}

// ---------------- Embed: Z[b*S+s][d] (+f16 copy, +t_all float) ----------------
__global__ __launch_bounds__(256) void embed_k(
    const float* __restrict__ ctx_x, const float* __restrict__ ctx_z,
    const float* __restrict__ qry_x,
    const float* __restrict__ W_ctx, const float* __restrict__ b_ctx,
    const float* __restrict__ W_qry, const float* __restrict__ b_qry,
    const int* __restrict__ t_ctx, const int* __restrict__ t_qry,
    float* __restrict__ Z, _Float16* __restrict__ Zh, float* __restrict__ tf)
{
    int row = blockIdx.x;            // 0..4095
    int d = threadIdx.x;             // 0..255
    int b = row >> 11, s = row & (S_LEN - 1);
    float acc;
    if (s < CTX) {
        const float* x1 = ctx_x + (size_t)(b * CTX + s) * LIN;
        const float* x2 = ctx_z + (size_t)(b * CTX + s) * HOUTD;
        const float* w = W_ctx + (size_t)d * (LIN + HOUTD);
        acc = b_ctx[d];
        #pragma unroll
        for (int i = 0; i < LIN; i++) acc += x1[i] * w[i];
        #pragma unroll
        for (int i = 0; i < HOUTD; i++) acc += x2[i] * w[LIN + i];
        if (d == 0) tf[row] = (float)t_ctx[b * CTX + s];
    } else {
        int qi = s - CTX;
        const float* x1 = qry_x + (size_t)(b * QQ + qi) * LIN;
        const float* w = W_qry + (size_t)d * (LIN + HOUTD);
        acc = b_qry[d];
        #pragma unroll
        for (int i = 0; i < LIN; i++) acc += x1[i] * w[i];
        if (d == 0) tf[row] = (float)t_qry[b * QQ + qi];
    }
    Z[(size_t)row * DD + d] = acc;
    Zh[(size_t)row * DD + d] = (_Float16)acc;
}

// ---------------- MFMA f16 GEMM 64x64 (dbuf LDS, pad-40, split-K capable) ----------------
// mode 0: fp32 out (Y / Ysplit per blockIdx.z; bias only on z==0)
// mode 1: relu -> f16 Yh   mode 2: f16 Q,K:[B,NH,S,DH] V:[B,NH,DH,S]
// lda = row stride of X and W; K = depth per z-split; kbase = z*K.
__global__ __launch_bounds__(256) void hgemm_k(
    const _Float16* __restrict__ X, const _Float16* __restrict__ W,
    const float* __restrict__ bias, float* __restrict__ Y,
    float* __restrict__ Ysplit, _Float16* __restrict__ Yh,
    int M, int N, int K, int lda, int mode,
    _Float16* __restrict__ Qh, _Float16* __restrict__ Kh, _Float16* __restrict__ Vh)
{
    __shared__ _Float16 Ah[2][64][40];
    __shared__ _Float16 Bh[2][64][40];
    const int tid = threadIdx.x;
    const int bm = blockIdx.x << 6, bn = blockIdx.y << 6;
    const int kbase = blockIdx.z * K;
    const int lr = tid >> 2;
    const int lk = (tid & 3) << 3;
    const int w = tid >> 6, lane = tid & 63;
    const int c = lane & 15, g = lane >> 4;
    const int wm = (w >> 1) << 5, wn = (w & 1) << 5;

    f32x4 acc00 = {0.f,0.f,0.f,0.f}, acc01 = {0.f,0.f,0.f,0.f};
    f32x4 acc10 = {0.f,0.f,0.f,0.f}, acc11 = {0.f,0.f,0.f,0.f};

    const _Float16* Xp = X + (size_t)(bm + lr) * lda + kbase + lk;
    const _Float16* Wp = W + (size_t)(bn + lr) * lda + kbase + lk;

    f16x8 xa = *(const f16x8*)Xp;
    f16x8 wb = *(const f16x8*)Wp;
    const int nt = K >> 5;
    int buf = 0;
    for (int t = 0; t < nt; t++) {
        *(f16x8*)&Ah[buf][lr][lk] = xa;
        *(f16x8*)&Bh[buf][lr][lk] = wb;
        __syncthreads();
        if (t + 1 < nt) {
            xa = *(const f16x8*)(Xp + ((size_t)(t + 1) << 5));
            wb = *(const f16x8*)(Wp + ((size_t)(t + 1) << 5));
        }
        f16x8 a0 = *(const f16x8*)&Ah[buf][wm + c][g << 3];
        f16x8 a1 = *(const f16x8*)&Ah[buf][wm + 16 + c][g << 3];
        f16x8 b0 = *(const f16x8*)&Bh[buf][wn + c][g << 3];
        f16x8 b1 = *(const f16x8*)&Bh[buf][wn + 16 + c][g << 3];
        acc00 = __builtin_amdgcn_mfma_f32_16x16x32_f16(a0, b0, acc00, 0, 0, 0);
        acc01 = __builtin_amdgcn_mfma_f32_16x16x32_f16(a0, b1, acc01, 0, 0, 0);
        acc10 = __builtin_amdgcn_mfma_f32_16x16x32_f16(a1, b0, acc10, 0, 0, 0);
        acc11 = __builtin_amdgcn_mfma_f32_16x16x32_f16(a1, b1, acc11, 0, 0, 0);
        buf ^= 1;
    }

    float* Yt = blockIdx.z ? Ysplit : Y;
    f32x4 accs[2][2] = {{acc00, acc01}, {acc10, acc11}};
    #pragma unroll
    for (int fm = 0; fm < 2; fm++) {
        #pragma unroll
        for (int fn = 0; fn < 2; fn++) {
            int colb = bn + wn + (fn << 4) + c;
            float bv = (blockIdx.z == 0) ? bias[colb] : 0.0f;
            #pragma unroll
            for (int r = 0; r < 4; r++) {
                int row = bm + wm + (fm << 4) + (g << 2) + r;
                float v = accs[fm][fn][r] + bv;
                if (mode == 0) {
                    Yt[(size_t)row * N + colb] = v;
                } else if (mode == 1) {
                    Yh[(size_t)row * N + colb] = (_Float16)fmaxf(v, 0.0f);
                } else {
                    int which = colb >> 8, h = (colb >> 5) & 7, d = colb & 31;
                    int bb2 = row >> 11, ss = row & (S_LEN - 1);
                    int bhi = (bb2 << 3) + h;
                    _Float16 hv = (_Float16)v;
                    if (which == 0)      Qh[((size_t)bhi * S_LEN + ss) * DH + d] = hv;
                    else if (which == 1) Kh[((size_t)bhi * S_LEN + ss) * DH + d] = hv;
                    else                 Vh[((size_t)bhi * DH + d) * S_LEN + ss] = hv;
                }
            }
        }
    }
}

// ---------------- fused Wo GEMM + residual + LayerNorm (BM=16, grid 256) ----------------
__global__ __launch_bounds__(256) void gemmln_k(
    const _Float16* __restrict__ X, const _Float16* __restrict__ W,
    const float* __restrict__ bias, float* __restrict__ Z,
    _Float16* __restrict__ Zh, const float* __restrict__ sw,
    const float* __restrict__ bw)
{
    __shared__ _Float16 Ast[2][16][40];
    __shared__ _Float16 Bst[2][256][40];
    __shared__ float lred[4][16][2];
    const int tid = threadIdx.x;
    const int bm = blockIdx.x << 4;
    const int w = tid >> 6, lane = tid & 63;
    const int c = lane & 15, g = lane >> 4;
    const int br = tid >> 2, bk = (tid & 3) << 3;

    f32x4 acc[4] = {};
    const _Float16* Wp = W + (size_t)br * DD + bk;
    f16x8 p0 = *(const f16x8*)Wp;
    f16x8 p1 = *(const f16x8*)(Wp + (size_t)64 * DD);
    f16x8 p2 = *(const f16x8*)(Wp + (size_t)128 * DD);
    f16x8 p3 = *(const f16x8*)(Wp + (size_t)192 * DD);
    f16x8 xa;
    if (tid < 64) xa = *(const f16x8*)(X + (size_t)(bm + br) * DD + bk);
    int buf = 0;
    #pragma unroll
    for (int t = 0; t < 8; t++) {
        if (tid < 64) *(f16x8*)&Ast[buf][br][bk] = xa;
        *(f16x8*)&Bst[buf][br][bk] = p0;
        *(f16x8*)&Bst[buf][br + 64][bk] = p1;
        *(f16x8*)&Bst[buf][br + 128][bk] = p2;
        *(f16x8*)&Bst[buf][br + 192][bk] = p3;
        __syncthreads();
        if (t < 7) {
            int o = (t + 1) << 5;
            if (tid < 64) xa = *(const f16x8*)(X + (size_t)(bm + br) * DD + o + bk);
            p0 = *(const f16x8*)(Wp + o);
            p1 = *(const f16x8*)(Wp + (size_t)64 * DD + o);
            p2 = *(const f16x8*)(Wp + (size_t)128 * DD + o);
            p3 = *(const f16x8*)(Wp + (size_t)192 * DD + o);
        }
        f16x8 a = *(const f16x8*)&Ast[buf][c][g << 3];
        #pragma unroll
        for (int f = 0; f < 4; f++) {
            f16x8 bfr = *(const f16x8*)&Bst[buf][(w << 6) + (f << 4) + c][g << 3];
            acc[f] = __builtin_amdgcn_mfma_f32_16x16x32_f16(a, bfr, acc[f], 0, 0, 0);
        }
        buf ^= 1;
    }

    float vals[4][4];
    float s1[4] = {0.f,0.f,0.f,0.f}, s2[4] = {0.f,0.f,0.f,0.f};
    #pragma unroll
    for (int f = 0; f < 4; f++) {
        int col = (w << 6) + (f << 4) + c;
        float bv = bias[col];
        #pragma unroll
        for (int r = 0; r < 4; r++) {
            int row = bm + (g << 2) + r;
            float v = acc[f][r] + bv + Z[(size_t)row * DD + col];
            vals[f][r] = v; s1[r] += v; s2[r] += v * v;
        }
    }
    #pragma unroll
    for (int off = 1; off < 16; off <<= 1) {
        #pragma unroll
        for (int r = 0; r < 4; r++) {
            s1[r] += __shfl_xor(s1[r], off, 64);
            s2[r] += __shfl_xor(s2[r], off, 64);
        }
    }
    if (c == 0) {
        #pragma unroll
        for (int r = 0; r < 4; r++) {
            lred[w][(g << 2) + r][0] = s1[r];
            lred[w][(g << 2) + r][1] = s2[r];
        }
    }
    __syncthreads();
    float mu_r[4], rs_r[4];
    #pragma unroll
    for (int r = 0; r < 4; r++) {
        int lr_ = (g << 2) + r;
        float S1 = lred[0][lr_][0] + lred[1][lr_][0] + lred[2][lr_][0] + lred[3][lr_][0];
        float S2 = lred[0][lr_][1] + lred[1][lr_][1] + lred[2][lr_][1] + lred[3][lr_][1];
        float mu = S1 * (1.0f / 256.0f);
        float var = S2 * (1.0f / 256.0f) - mu * mu;
        mu_r[r] = mu; rs_r[r] = rsqrtf(var + 1e-5f);
    }
    #pragma unroll
    for (int f = 0; f < 4; f++) {
        int col = (w << 6) + (f << 4) + c;
        float swv = sw[col], bwv = bw[col];
        #pragma unroll
        for (int r = 0; r < 4; r++) {
            int row = bm + (g << 2) + r;
            float o = (vals[f][r] - mu_r[r]) * rs_r[r] * swv + bwv;
            Z[(size_t)row * DD + col] = o;
            Zh[(size_t)row * DD + col] = (_Float16)o;
        }
    }
}

// ---------------- Residual + LN (3-input: Z + Y0 + Y1), one WAVE per row ----------------
__global__ __launch_bounds__(256) void ln4_k(
    float* __restrict__ Z, const float* __restrict__ Y0,
    const float* __restrict__ Y1,
    const float* __restrict__ sw, const float* __restrict__ bw,
    _Float16* __restrict__ Zh)
{
    const int w = threadIdx.x >> 6, lane = threadIdx.x & 63;
    const int row = (blockIdx.x << 2) + w;
    float4 z = ((const float4*)(Z + (size_t)row * DD))[lane];
    float4 y = ((const float4*)(Y0 + (size_t)row * DD))[lane];
    float4 y2 = ((const float4*)(Y1 + (size_t)row * DD))[lane];
    float x0 = z.x + y.x + y2.x, x1 = z.y + y.y + y2.y;
    float x2 = z.z + y.z + y2.z, x3 = z.w + y.w + y2.w;
    float s1 = (x0 + x1) + (x2 + x3);
    float s2 = (x0 * x0 + x1 * x1) + (x2 * x2 + x3 * x3);
    #pragma unroll
    for (int off = 1; off < 64; off <<= 1) {
        s1 += __shfl_xor(s1, off, 64);
        s2 += __shfl_xor(s2, off, 64);
    }
    float mu = s1 * (1.0f / 256.0f);
    float var = s2 * (1.0f / 256.0f) - mu * mu;
    float rs = rsqrtf(var + 1e-5f);
    float4 sv = ((const float4*)sw)[lane];
    float4 bv = ((const float4*)bw)[lane];
    float o0 = (x0 - mu) * rs * sv.x + bv.x;
    float o1 = (x1 - mu) * rs * sv.y + bv.y;
    float o2 = (x2 - mu) * rs * sv.z + bv.z;
    float o3 = (x3 - mu) * rs * sv.w + bv.w;
    ((float4*)(Z + (size_t)row * DD))[lane] = make_float4(o0, o1, o2, o3);
    f16x4 oh = {(_Float16)o0, (_Float16)o1, (_Float16)o2, (_Float16)o3};
    ((f16x4*)(Zh + (size_t)row * DD))[lane] = oh;
}

// ---------------- MFMA flash attention (r14 config: 1024 thr, 2wg x 8qt) ----------------
__global__ __launch_bounds__(1024, 4) void attn_k(
    const _Float16* __restrict__ Qf, const _Float16* __restrict__ Kf,
    const _Float16* __restrict__ Vf, const float* __restrict__ tf_all,
    const float* __restrict__ alpha, _Float16* __restrict__ O)
{
    const int bh = blockIdx.x >> 4;           // /(S/128)=16
    const int itile = blockIdx.x & 15;
    const int b = bh >> 3, h = bh & 7;
    const int tid = threadIdx.x;
    const int w16 = tid >> 6;                 // 0..15
    const int wg = w16 >> 3;                  // key-split 0/1
    const int wq = w16 & 7;                   // query tile 0..7
    const int ltid = tid & 511;               // within wave-group
    const int lane = tid & 63;
    const int c = lane & 15, g = lane >> 4;
    const int i0 = (itile << 7) + (wq << 4);
    const int jbase = wg * KHALF;

    __shared__ __align__(16) char smem[38912];
    _Float16 (*Kl)[2][64][40] = (_Float16(*)[2][64][40])smem;
    _Float16 (*Vl)[2][32][72] = (_Float16(*)[2][32][72])(smem + 20480);
    float (*sacc)[16][36] = (float(*)[16][36])smem;
    float (*sml)[2][16] = (float(*)[2][16])(smem + 36864);

    const float LOG2E = 1.44269504088896f;
    const float sc2 = 0.17677669529663687f * LOG2E;
    const float ah2 = alpha[h] * LOG2E;

    const _Float16* Qbh = Qf + (size_t)bh * S_LEN * DH;
    const _Float16* Kbh = Kf + (size_t)bh * S_LEN * DH;
    const _Float16* Vbh = Vf + (size_t)bh * DH * S_LEN;
    const float* tb = tf_all + b * S_LEN;

    f16x8 qfrag = *(const f16x8*)(Qbh + (size_t)(i0 + c) * DH + (g << 3));
    const float ti = tb[i0 + c];

    const int lh = ltid & 255;
    const int kr = lh >> 2, kc = (lh & 3) << 3;
    const int vr = lh >> 3, vc = (lh & 7) << 3;
    const bool doK = (ltid < 256);

    float m2 = -3.0e38f, l = 0.0f;
    f32x4 acc0 = {0.f, 0.f, 0.f, 0.f};
    f32x4 acc1 = {0.f, 0.f, 0.f, 0.f};
    const f32x4 zero = {0.f, 0.f, 0.f, 0.f};

    f16x8 pre;
    if (doK) pre = *(const f16x8*)(Kbh + (size_t)(jbase + kr) * DH + kc);
    else     pre = *(const f16x8*)(Vbh + (size_t)vr * S_LEN + jbase + vc);
    int buf = 0;

    for (int kt = 0; kt < KHALF; kt += 64) {
        if (doK) *(f16x8*)&Kl[wg][buf][kr][kc] = pre;
        else     *(f16x8*)&Vl[wg][buf][vr][vc] = pre;
        __syncthreads();
        if (kt + 64 < KHALF) {
            if (doK) pre = *(const f16x8*)(Kbh + (size_t)(jbase + kt + 64 + kr) * DH + kc);
            else     pre = *(const f16x8*)(Vbh + (size_t)vr * S_LEN + jbase + kt + 64 + vc);
        }
        #pragma unroll
        for (int jj = 0; jj < 64; jj += 32) {
            const int j0 = jbase + kt + jj;
            f16x8 kf0 = *(const f16x8*)&Kl[wg][buf][jj + c][g << 3];
            f16x8 kf1 = *(const f16x8*)&Kl[wg][buf][jj + 16 + c][g << 3];
            f32x4 dA = __builtin_amdgcn_mfma_f32_16x16x32_f16(kf0, qfrag, zero, 0, 0, 0);
            f32x4 dB = __builtin_amdgcn_mfma_f32_16x16x32_f16(kf1, qfrag, zero, 0, 0, 0);
            float4 tjA = *(const float4*)(tb + j0 + (g << 2));
            float4 tjB = *(const float4*)(tb + j0 + 16 + (g << 2));
            float eA0 = ti - tjA.x, eA1 = ti - tjA.y, eA2 = ti - tjA.z, eA3 = ti - tjA.w;
            float eB0 = ti - tjB.x, eB1 = ti - tjB.y, eB2 = ti - tjB.z, eB3 = ti - tjB.w;
            float sA0 = (eA0 >= 0.f) ? dA[0] * sc2 - ah2 * eA0 : -1e9f;
            float sA1 = (eA1 >= 0.f) ? dA[1] * sc2 - ah2 * eA1 : -1e9f;
            float sA2 = (eA2 >= 0.f) ? dA[2] * sc2 - ah2 * eA2 : -1e9f;
            float sA3 = (eA3 >= 0.f) ? dA[3] * sc2 - ah2 * eA3 : -1e9f;
            float sB0 = (eB0 >= 0.f) ? dB[0] * sc2 - ah2 * eB0 : -1e9f;
            float sB1 = (eB1 >= 0.f) ? dB[1] * sc2 - ah2 * eB1 : -1e9f;
            float sB2 = (eB2 >= 0.f) ? dB[2] * sc2 - ah2 * eB2 : -1e9f;
            float sB3 = (eB3 >= 0.f) ? dB[3] * sc2 - ah2 * eB3 : -1e9f;
            float pmaxl = fmaxf(fmaxf(fmaxf(sA0, sA1), fmaxf(sA2, sA3)),
                                fmaxf(fmaxf(sB0, sB1), fmaxf(sB2, sB3)));
            if (__any(pmaxl > m2 + 8.0f)) {
                float pm = fmaxf(pmaxl, __shfl_xor(pmaxl, 16, 64));
                pm = fmaxf(pm, __shfl_xor(pm, 32, 64));
                float mnew = fmaxf(m2, pm);
                float fsc = __builtin_amdgcn_exp2f(m2 - mnew);
                m2 = mnew;
                l *= fsc; acc0 *= fsc; acc1 *= fsc;
            }
            float pA0 = __builtin_amdgcn_exp2f(sA0 - m2);
            float pA1 = __builtin_amdgcn_exp2f(sA1 - m2);
            float pA2 = __builtin_amdgcn_exp2f(sA2 - m2);
            float pA3 = __builtin_amdgcn_exp2f(sA3 - m2);
            float pB0 = __builtin_amdgcn_exp2f(sB0 - m2);
            float pB1 = __builtin_amdgcn_exp2f(sB1 - m2);
            float pB2 = __builtin_amdgcn_exp2f(sB2 - m2);
            float pB3 = __builtin_amdgcn_exp2f(sB3 - m2);
            l += ((pA0 + pA1) + (pA2 + pA3)) + ((pB0 + pB1) + (pB2 + pB3));
            f16x4 pfA = {(_Float16)pA0, (_Float16)pA1, (_Float16)pA2, (_Float16)pA3};
            f16x4 pfB = {(_Float16)pB0, (_Float16)pB1, (_Float16)pB2, (_Float16)pB3};
            f16x4 vA0 = *(const f16x4*)&Vl[wg][buf][c][jj + (g << 2)];
            f16x4 vA1 = *(const f16x4*)&Vl[wg][buf][16 + c][jj + (g << 2)];
            f16x4 vB0 = *(const f16x4*)&Vl[wg][buf][c][jj + 16 + (g << 2)];
            f16x4 vB1 = *(const f16x4*)&Vl[wg][buf][16 + c][jj + 16 + (g << 2)];
            acc0 = __builtin_amdgcn_mfma_f32_16x16x16f16(vA0, pfA, acc0, 0, 0, 0);
            acc0 = __builtin_amdgcn_mfma_f32_16x16x16f16(vB0, pfB, acc0, 0, 0, 0);
            acc1 = __builtin_amdgcn_mfma_f32_16x16x16f16(vA1, pfA, acc1, 0, 0, 0);
            acc1 = __builtin_amdgcn_mfma_f32_16x16x16f16(vB1, pfB, acc1, 0, 0, 0);
        }
        buf ^= 1;
    }

    l += __shfl_xor(l, 16, 64);
    l += __shfl_xor(l, 32, 64);

    __syncthreads();
    *(f32x4*)&sacc[w16][c][g << 2] = acc0;
    *(f32x4*)&sacc[w16][c][16 + (g << 2)] = acc1;
    if (g == 0) { sml[w16][0][c] = m2; sml[w16][1][c] = l; }
    __syncthreads();

    {
        const int qt = tid >> 7;
        const int q = (tid >> 3) & 15;
        const int dh0 = (tid & 7) << 2;
        float m0 = sml[qt][0][q], m1 = sml[qt + 8][0][q];
        float M = fmaxf(m0, m1);
        float f0 = __builtin_amdgcn_exp2f(m0 - M);
        float f1 = __builtin_amdgcn_exp2f(m1 - M);
        float L = sml[qt][1][q] * f0 + sml[qt + 8][1][q] * f1;
        float a0 = sacc[qt][q][dh0 + 0] * f0 + sacc[qt + 8][q][dh0 + 0] * f1;
        float a1 = sacc[qt][q][dh0 + 1] * f0 + sacc[qt + 8][q][dh0 + 1] * f1;
        float a2 = sacc[qt][q][dh0 + 2] * f0 + sacc[qt + 8][q][dh0 + 2] * f1;
        float a3 = sacc[qt][q][dh0 + 3] * f0 + sacc[qt + 8][q][dh0 + 3] * f1;
        if (M < -4.9e8f) {
            float vs0 = 0.f, vs1 = 0.f, vs2 = 0.f, vs3 = 0.f;
            const _Float16* vp = Vbh + (size_t)dh0 * S_LEN + CTX;
            for (int j = 0; j < QQ; j += 8) {
                f16x8 x0 = *(const f16x8*)(vp + j);
                f16x8 x1 = *(const f16x8*)(vp + S_LEN + j);
                f16x8 x2 = *(const f16x8*)(vp + 2 * S_LEN + j);
                f16x8 x3 = *(const f16x8*)(vp + 3 * S_LEN + j);
                #pragma unroll
                for (int e = 0; e < 8; e++) {
                    vs0 += (float)x0[e]; vs1 += (float)x1[e];
                    vs2 += (float)x2[e]; vs3 += (float)x3[e];
                }
            }
            a0 += vs0; a1 += vs1; a2 += vs2; a3 += vs3;
            L += (float)QQ;
        }
        float inv = 1.0f / L;
        int row = b * S_LEN + (itile << 7) + (qt << 4) + q;
        f16x4 o = {(_Float16)(a0 * inv), (_Float16)(a1 * inv),
                   (_Float16)(a2 * inv), (_Float16)(a3 * inv)};
        *(f16x4*)(O + (size_t)row * DD + h * DH + dh0) = o;
    }
}

// ---------------- Output head ----------------
__global__ __launch_bounds__(256) void outhead_k(
    const float* __restrict__ Z, const float* __restrict__ Wout,
    const float* __restrict__ bout, float* __restrict__ out)
{
    int tid = threadIdx.x;
    int rloc = tid >> 4, ho = tid & 15;
    int qrow = blockIdx.x * 16 + rloc;
    int b = qrow >> 9, qi = qrow & (QQ - 1);
    if (ho < HOUTD) {
        const float* z = Z + (size_t)(b * S_LEN + CTX + qi) * DD;
        const float* wr = Wout + (size_t)ho * DD;
        float s = 0.0f;
        for (int d = 0; d < DD; d += 4) {
            float4 zv = *(const float4*)(z + d);
            float4 wv = *(const float4*)(wr + d);
            s += zv.x * wv.x + zv.y * wv.y + zv.z * wv.z + zv.w * wv.w;
        }
        out[(size_t)(b * QQ + qi) * HOUTD + ho] = s + bout[ho];
    }
}

extern "C" void kernel_launch(void* const* d_in, const int* in_sizes, int n_in,
                              void* d_out, int out_size, void* d_ws, size_t ws_size,
                              hipStream_t stream) {
    (void)in_sizes; (void)n_in; (void)out_size; (void)ws_size;
    const float* ctx_x = (const float*)d_in[0];
    const float* ctx_z = (const float*)d_in[1];
    const float* qry_x = (const float*)d_in[2];
    const int* t_ctx = (const int*)d_in[3];
    const int* t_qry = (const int*)d_in[4];
    const float* W_ctx = (const float*)d_in[5];
    const float* b_ctx = (const float*)d_in[6];
    const float* W_qry = (const float*)d_in[7];
    const float* b_qry = (const float*)d_in[8];
    const float* alpha = (const float*)d_in[9];
    const float* Wqkv = (const float*)d_in[10];
    const float* bqkv = (const float*)d_in[11];
    const float* Wo = (const float*)d_in[12];
    const float* bo = (const float*)d_in[13];
    const float* ln1_s = (const float*)d_in[14];
    const float* ln1_b = (const float*)d_in[15];
    const float* W1 = (const float*)d_in[16];
    const float* b1 = (const float*)d_in[17];
    const float* W2 = (const float*)d_in[18];
    const float* b2 = (const float*)d_in[19];
    const float* ln2_s = (const float*)d_in[20];
    const float* ln2_b = (const float*)d_in[21];
    const float* W_out = (const float*)d_in[22];
    const float* b_out = (const float*)d_in[23];

    float* ws = (float*)d_ws;
    const size_t MTOT = (size_t)BB * S_LEN;       // 4096
    const size_t ZSZ = MTOT * DD;                 // 1M floats
    float* Z   = ws;                              // [0, 1M) f32
    float* Yb  = ws + ZSZ;                        // [1M, 2M) f32
    _Float16* Zh   = (_Float16*)(ws + 2 * ZSZ);          // 1M halfs
    _Float16* AYh  = (_Float16*)(ws + 2 * ZSZ + ZSZ / 2);
    _Float16* FF1h = (_Float16*)(ws + 3 * ZSZ);          // 4M halfs -> [3M,5M)
    _Float16* Qh   = (_Float16*)(ws + 5 * ZSZ);
    _Float16* Kh   = (_Float16*)(ws + 5 * ZSZ + ZSZ / 2);
    _Float16* Vh   = (_Float16*)(ws + 6 * ZSZ);
    // w2 split-K partial buffer: aliases Qh+Kh (dead during the FFN tail,
    // rewritten by the next layer's qkv AFTER ln4 has consumed Yb1).
    float* Yb1 = ws + 5 * ZSZ;                           // [5M, 6M) f32
    float* tf_all  = ws + 6 * ZSZ + ZSZ / 2;             // 4096 floats
    _Float16* Whqkv = (_Float16*)(ws + 6 * ZSZ + ZSZ / 2 + 4096);
    _Float16* Who   = Whqkv + (size_t)NL * 3 * DD * DD;
    _Float16* Wh1   = Who   + (size_t)NL * DD * DD;
    _Float16* Wh2   = Wh1   + (size_t)NL * DFF * DD;

    {
        int n4tot = N4_QKV + N4_WO + N4_W1 + N4_W2;
        cvtall_k<<<(n4tot + 255) / 256, 256, 0, stream>>>(
            Wqkv, Wo, W1, W2, Whqkv, Who, Wh1, Wh2);
    }

    embed_k<<<MTOT, 256, 0, stream>>>(ctx_x, ctx_z, qry_x, W_ctx, b_ctx, W_qry, b_qry,
                                      t_ctx, t_qry, Z, Zh, tf_all);

    for (int l = 0; l < NL; l++) {
        hgemm_k<<<dim3(MTOT / 64, (3 * DD) / 64, 1), 256, 0, stream>>>(
            Zh, Whqkv + (size_t)l * 3 * DD * DD, bqkv + (size_t)l * 3 * DD,
            nullptr, nullptr, nullptr, (int)MTOT, 3 * DD, DD, DD, 2, Qh, Kh, Vh);
        attn_k<<<BB * NH * (S_LEN / 128), 1024, 0, stream>>>(
            Qh, Kh, Vh, tf_all, alpha, AYh);
        gemmln_k<<<MTOT / 16, 256, 0, stream>>>(
            AYh, Who + (size_t)l * DD * DD, bo + (size_t)l * DD,
            Z, Zh, ln1_s + (size_t)l * DD, ln1_b + (size_t)l * DD);
        hgemm_k<<<dim3(MTOT / 64, DFF / 64, 1), 256, 0, stream>>>(
            Zh, Wh1 + (size_t)l * DFF * DD, b1 + (size_t)l * DFF,
            nullptr, nullptr, FF1h, (int)MTOT, DFF, DD, DD, 1,
            nullptr, nullptr, nullptr);
        hgemm_k<<<dim3(MTOT / 64, DD / 64, 2), 256, 0, stream>>>(
            FF1h, Wh2 + (size_t)l * DD * DFF, b2 + (size_t)l * DD,
            Yb, Yb1, nullptr, (int)MTOT, DD, DFF / 2, DFF, 0,
            nullptr, nullptr, nullptr);
        ln4_k<<<MTOT / 4, 256, 0, stream>>>(
            Z, Yb, Yb1, ln2_s + (size_t)l * DD, ln2_b + (size_t)l * DD, Zh);
    }

    outhead_k<<<(BB * QQ) / 16, 256, 0, stream>>>(Z, W_out, b_out, (float*)d_out);
}

// Round 17
// 423.307 us; speedup vs baseline: 1.1745x; 1.0372x over previous
//
#include <hip/hip_runtime.h>
#include <hip/hip_bf16.h>
#include <cstddef>

#define BB   2
#define CTX  1536
#define QQ   512
#define S_LEN 2048
#define DD   256
#define NH   8
#define DH   32
#define DFF  1024
#define NL   6
#define LIN  20
#define HOUTD 10
#define KHALF (CTX / 2)      // 768 keys per wave-group

typedef _Float16 f16x2 __attribute__((ext_vector_type(2)));
typedef _Float16 f16x4 __attribute__((ext_vector_type(4)));
typedef _Float16 f16x8 __attribute__((ext_vector_type(8)));
typedef float f32x4 __attribute__((ext_vector_type(4)));

#define N4_QKV (NL * 3 * DD * DD / 4)
#define N4_WO  (NL * DD * DD / 4)
#define N4_W1  (NL * DFF * DD / 4)
#define N4_W2  (NL * DD * DFF / 4)

// ---------------- fp32 -> f16 convert (all weights, one launch) ----------------
__global__ __launch_bounds__(256) void cvtall_k(
    const float* __restrict__ wqkv, const float* __restrict__ wo,
    const float* __restrict__ w1, const float* __restrict__ w2,
    _Float16* __restrict__ hqkv, _Float16* __restrict__ ho,
    _Float16* __restrict__ h1, _Float16* __restrict__ h2)
{
    int i = blockIdx.x * 256 + threadIdx.x;
    const float* s; _Float16* t; int j = i;
    if (j < N4_QKV) { s = wqkv; t = hqkv; }
    else if ((j -= N4_QKV) < N4_WO) { s = wo; t = ho; }
    else if ((j -= N4_WO) < N4_W1) { s = w1; t = h1; }
    else if ((j -= N4_W1) < N4_W2) { s = w2; t = h2; }
    else return;
    float4 v = ((const float4*)s)[j];
    f16x4 h = {(_Float16)v.x, (_Float16)v.y, (_Float16)v.z, (_Float16)v.w};
    ((f16x4*)t)[j] = h;
}

// ---------------- Embed: Z[b*S+s][d] (+f16 copy, +t_all float) ----------------
__global__ __launch_bounds__(256) void embed_k(
    const float* __restrict__ ctx_x, const float* __restrict__ ctx_z,
    const float* __restrict__ qry_x,
    const float* __restrict__ W_ctx, const float* __restrict__ b_ctx,
    const float* __restrict__ W_qry, const float* __restrict__ b_qry,
    const int* __restrict__ t_ctx, const int* __restrict__ t_qry,
    float* __restrict__ Z, _Float16* __restrict__ Zh, float* __restrict__ tf)
{
    int row = blockIdx.x;            // 0..4095
    int d = threadIdx.x;             // 0..255
    int b = row >> 11, s = row & (S_LEN - 1);
    float acc;
    if (s < CTX) {
        const float* x1 = ctx_x + (size_t)(b * CTX + s) * LIN;
        const float* x2 = ctx_z + (size_t)(b * CTX + s) * HOUTD;
        const float* w = W_ctx + (size_t)d * (LIN + HOUTD);
        acc = b_ctx[d];
        #pragma unroll
        for (int i = 0; i < LIN; i++) acc += x1[i] * w[i];
        #pragma unroll
        for (int i = 0; i < HOUTD; i++) acc += x2[i] * w[LIN + i];
        if (d == 0) tf[row] = (float)t_ctx[b * CTX + s];
    } else {
        int qi = s - CTX;
        const float* x1 = qry_x + (size_t)(b * QQ + qi) * LIN;
        const float* w = W_qry + (size_t)d * (LIN + HOUTD);
        acc = b_qry[d];
        #pragma unroll
        for (int i = 0; i < LIN; i++) acc += x1[i] * w[i];
        if (d == 0) tf[row] = (float)t_qry[b * QQ + qi];
    }
    Z[(size_t)row * DD + d] = acc;
    Zh[(size_t)row * DD + d] = (_Float16)acc;
}

// ---------------- MFMA f16 GEMM 64x64 (dbuf LDS, pad-40, split-K capable) ----------------
// mode 0: fp32 out (Y0..Y3 per blockIdx.z; bias only on z==0)
// mode 1: relu -> f16 Yh   mode 2: f16 Q,K:[B,NH,S,DH] V:[B,NH,DH,S]
// lda = row stride of X and W; K = depth per z-split; kbase = z*K.
__global__ __launch_bounds__(256) void hgemm_k(
    const _Float16* __restrict__ X, const _Float16* __restrict__ W,
    const float* __restrict__ bias, float* __restrict__ Y0,
    float* __restrict__ Y1, float* __restrict__ Y2, float* __restrict__ Y3,
    _Float16* __restrict__ Yh,
    int M, int N, int K, int lda, int mode,
    _Float16* __restrict__ Qh, _Float16* __restrict__ Kh, _Float16* __restrict__ Vh)
{
    __shared__ _Float16 Ah[2][64][40];
    __shared__ _Float16 Bh[2][64][40];
    const int tid = threadIdx.x;
    const int bm = blockIdx.x << 6, bn = blockIdx.y << 6;
    const int kbase = blockIdx.z * K;
    const int lr = tid >> 2;
    const int lk = (tid & 3) << 3;
    const int w = tid >> 6, lane = tid & 63;
    const int c = lane & 15, g = lane >> 4;
    const int wm = (w >> 1) << 5, wn = (w & 1) << 5;

    f32x4 acc00 = {0.f,0.f,0.f,0.f}, acc01 = {0.f,0.f,0.f,0.f};
    f32x4 acc10 = {0.f,0.f,0.f,0.f}, acc11 = {0.f,0.f,0.f,0.f};

    const _Float16* Xp = X + (size_t)(bm + lr) * lda + kbase + lk;
    const _Float16* Wp = W + (size_t)(bn + lr) * lda + kbase + lk;

    f16x8 xa = *(const f16x8*)Xp;
    f16x8 wb = *(const f16x8*)Wp;
    const int nt = K >> 5;
    int buf = 0;
    for (int t = 0; t < nt; t++) {
        *(f16x8*)&Ah[buf][lr][lk] = xa;
        *(f16x8*)&Bh[buf][lr][lk] = wb;
        __syncthreads();
        if (t + 1 < nt) {
            xa = *(const f16x8*)(Xp + ((size_t)(t + 1) << 5));
            wb = *(const f16x8*)(Wp + ((size_t)(t + 1) << 5));
        }
        f16x8 a0 = *(const f16x8*)&Ah[buf][wm + c][g << 3];
        f16x8 a1 = *(const f16x8*)&Ah[buf][wm + 16 + c][g << 3];
        f16x8 b0 = *(const f16x8*)&Bh[buf][wn + c][g << 3];
        f16x8 b1 = *(const f16x8*)&Bh[buf][wn + 16 + c][g << 3];
        acc00 = __builtin_amdgcn_mfma_f32_16x16x32_f16(a0, b0, acc00, 0, 0, 0);
        acc01 = __builtin_amdgcn_mfma_f32_16x16x32_f16(a0, b1, acc01, 0, 0, 0);
        acc10 = __builtin_amdgcn_mfma_f32_16x16x32_f16(a1, b0, acc10, 0, 0, 0);
        acc11 = __builtin_amdgcn_mfma_f32_16x16x32_f16(a1, b1, acc11, 0, 0, 0);
        buf ^= 1;
    }

    float* Yt = (blockIdx.z == 0) ? Y0 : (blockIdx.z == 1) ? Y1
              : (blockIdx.z == 2) ? Y2 : Y3;
    f32x4 accs[2][2] = {{acc00, acc01}, {acc10, acc11}};
    #pragma unroll
    for (int fm = 0; fm < 2; fm++) {
        #pragma unroll
        for (int fn = 0; fn < 2; fn++) {
            int colb = bn + wn + (fn << 4) + c;
            float bv = (blockIdx.z == 0) ? bias[colb] : 0.0f;
            #pragma unroll
            for (int r = 0; r < 4; r++) {
                int row = bm + wm + (fm << 4) + (g << 2) + r;
                float v = accs[fm][fn][r] + bv;
                if (mode == 0) {
                    Yt[(size_t)row * N + colb] = v;
                } else if (mode == 1) {
                    Yh[(size_t)row * N + colb] = (_Float16)fmaxf(v, 0.0f);
                } else {
                    int which = colb >> 8, h = (colb >> 5) & 7, d = colb & 31;
                    int bb2 = row >> 11, ss = row & (S_LEN - 1);
                    int bhi = (bb2 << 3) + h;
                    _Float16 hv = (_Float16)v;
                    if (which == 0)      Qh[((size_t)bhi * S_LEN + ss) * DH + d] = hv;
                    else if (which == 1) Kh[((size_t)bhi * S_LEN + ss) * DH + d] = hv;
                    else                 Vh[((size_t)bhi * DH + d) * S_LEN + ss] = hv;
                }
            }
        }
    }
}

// ---------------- fused Wo GEMM + residual + LayerNorm (BM=16, grid 256) ----------------
__global__ __launch_bounds__(256) void gemmln_k(
    const _Float16* __restrict__ X, const _Float16* __restrict__ W,
    const float* __restrict__ bias, float* __restrict__ Z,
    _Float16* __restrict__ Zh, const float* __restrict__ sw,
    const float* __restrict__ bw)
{
    __shared__ _Float16 Ast[2][16][40];
    __shared__ _Float16 Bst[2][256][40];
    __shared__ float lred[4][16][2];
    const int tid = threadIdx.x;
    const int bm = blockIdx.x << 4;
    const int w = tid >> 6, lane = tid & 63;
    const int c = lane & 15, g = lane >> 4;
    const int br = tid >> 2, bk = (tid & 3) << 3;

    f32x4 acc[4] = {};
    const _Float16* Wp = W + (size_t)br * DD + bk;
    f16x8 p0 = *(const f16x8*)Wp;
    f16x8 p1 = *(const f16x8*)(Wp + (size_t)64 * DD);
    f16x8 p2 = *(const f16x8*)(Wp + (size_t)128 * DD);
    f16x8 p3 = *(const f16x8*)(Wp + (size_t)192 * DD);
    f16x8 xa;
    if (tid < 64) xa = *(const f16x8*)(X + (size_t)(bm + br) * DD + bk);
    int buf = 0;
    #pragma unroll
    for (int t = 0; t < 8; t++) {
        if (tid < 64) *(f16x8*)&Ast[buf][br][bk] = xa;
        *(f16x8*)&Bst[buf][br][bk] = p0;
        *(f16x8*)&Bst[buf][br + 64][bk] = p1;
        *(f16x8*)&Bst[buf][br + 128][bk] = p2;
        *(f16x8*)&Bst[buf][br + 192][bk] = p3;
        __syncthreads();
        if (t < 7) {
            int o = (t + 1) << 5;
            if (tid < 64) xa = *(const f16x8*)(X + (size_t)(bm + br) * DD + o + bk);
            p0 = *(const f16x8*)(Wp + o);
            p1 = *(const f16x8*)(Wp + (size_t)64 * DD + o);
            p2 = *(const f16x8*)(Wp + (size_t)128 * DD + o);
            p3 = *(const f16x8*)(Wp + (size_t)192 * DD + o);
        }
        f16x8 a = *(const f16x8*)&Ast[buf][c][g << 3];
        #pragma unroll
        for (int f = 0; f < 4; f++) {
            f16x8 bfr = *(const f16x8*)&Bst[buf][(w << 6) + (f << 4) + c][g << 3];
            acc[f] = __builtin_amdgcn_mfma_f32_16x16x32_f16(a, bfr, acc[f], 0, 0, 0);
        }
        buf ^= 1;
    }

    float vals[4][4];
    float s1[4] = {0.f,0.f,0.f,0.f}, s2[4] = {0.f,0.f,0.f,0.f};
    #pragma unroll
    for (int f = 0; f < 4; f++) {
        int col = (w << 6) + (f << 4) + c;
        float bv = bias[col];
        #pragma unroll
        for (int r = 0; r < 4; r++) {
            int row = bm + (g << 2) + r;
            float v = acc[f][r] + bv + Z[(size_t)row * DD + col];
            vals[f][r] = v; s1[r] += v; s2[r] += v * v;
        }
    }
    #pragma unroll
    for (int off = 1; off < 16; off <<= 1) {
        #pragma unroll
        for (int r = 0; r < 4; r++) {
            s1[r] += __shfl_xor(s1[r], off, 64);
            s2[r] += __shfl_xor(s2[r], off, 64);
        }
    }
    if (c == 0) {
        #pragma unroll
        for (int r = 0; r < 4; r++) {
            lred[w][(g << 2) + r][0] = s1[r];
            lred[w][(g << 2) + r][1] = s2[r];
        }
    }
    __syncthreads();
    float mu_r[4], rs_r[4];
    #pragma unroll
    for (int r = 0; r < 4; r++) {
        int lr_ = (g << 2) + r;
        float S1 = lred[0][lr_][0] + lred[1][lr_][0] + lred[2][lr_][0] + lred[3][lr_][0];
        float S2 = lred[0][lr_][1] + lred[1][lr_][1] + lred[2][lr_][1] + lred[3][lr_][1];
        float mu = S1 * (1.0f / 256.0f);
        float var = S2 * (1.0f / 256.0f) - mu * mu;
        mu_r[r] = mu; rs_r[r] = rsqrtf(var + 1e-5f);
    }
    #pragma unroll
    for (int f = 0; f < 4; f++) {
        int col = (w << 6) + (f << 4) + c;
        float swv = sw[col], bwv = bw[col];
        #pragma unroll
        for (int r = 0; r < 4; r++) {
            int row = bm + (g << 2) + r;
            float o = (vals[f][r] - mu_r[r]) * rs_r[r] * swv + bwv;
            Z[(size_t)row * DD + col] = o;
            Zh[(size_t)row * DD + col] = (_Float16)o;
        }
    }
}

// ---------------- Residual + LN (Z + Y0..Y3), one WAVE per row ----------------
__global__ __launch_bounds__(256) void ln4_k(
    float* __restrict__ Z, const float* __restrict__ Y0,
    const float* __restrict__ Y1, const float* __restrict__ Y2,
    const float* __restrict__ Y3,
    const float* __restrict__ sw, const float* __restrict__ bw,
    _Float16* __restrict__ Zh)
{
    const int w = threadIdx.x >> 6, lane = threadIdx.x & 63;
    const int row = (blockIdx.x << 2) + w;
    float4 z = ((const float4*)(Z + (size_t)row * DD))[lane];
    float4 y0 = ((const float4*)(Y0 + (size_t)row * DD))[lane];
    float4 y1 = ((const float4*)(Y1 + (size_t)row * DD))[lane];
    float4 y2 = ((const float4*)(Y2 + (size_t)row * DD))[lane];
    float4 y3 = ((const float4*)(Y3 + (size_t)row * DD))[lane];
    float x0 = z.x + (y0.x + y1.x) + (y2.x + y3.x);
    float x1 = z.y + (y0.y + y1.y) + (y2.y + y3.y);
    float x2 = z.z + (y0.z + y1.z) + (y2.z + y3.z);
    float x3 = z.w + (y0.w + y1.w) + (y2.w + y3.w);
    float s1 = (x0 + x1) + (x2 + x3);
    float s2 = (x0 * x0 + x1 * x1) + (x2 * x2 + x3 * x3);
    #pragma unroll
    for (int off = 1; off < 64; off <<= 1) {
        s1 += __shfl_xor(s1, off, 64);
        s2 += __shfl_xor(s2, off, 64);
    }
    float mu = s1 * (1.0f / 256.0f);
    float var = s2 * (1.0f / 256.0f) - mu * mu;
    float rs = rsqrtf(var + 1e-5f);
    float4 sv = ((const float4*)sw)[lane];
    float4 bv = ((const float4*)bw)[lane];
    float o0 = (x0 - mu) * rs * sv.x + bv.x;
    float o1 = (x1 - mu) * rs * sv.y + bv.y;
    float o2 = (x2 - mu) * rs * sv.z + bv.z;
    float o3 = (x3 - mu) * rs * sv.w + bv.w;
    ((float4*)(Z + (size_t)row * DD))[lane] = make_float4(o0, o1, o2, o3);
    f16x4 oh = {(_Float16)o0, (_Float16)o1, (_Float16)o2, (_Float16)o3};
    ((f16x4*)(Zh + (size_t)row * DD))[lane] = oh;
}

// ---------------- MFMA flash attention ----------------
// 1024 thr = 16 waves = 2 key-split wg x 8 query tiles (128 q/block).
// 128-key tiles (6 staging barriers), dbuf; t_all staged in LDS once.
__global__ __launch_bounds__(1024, 4) void attn_k(
    const _Float16* __restrict__ Qf, const _Float16* __restrict__ Kf,
    const _Float16* __restrict__ Vf, const float* __restrict__ tf_all,
    const float* __restrict__ alpha, _Float16* __restrict__ O)
{
    const int bh = blockIdx.x >> 4;           // /(S/128)=16
    const int itile = blockIdx.x & 15;
    const int b = bh >> 3, h = bh & 7;
    const int tid = threadIdx.x;
    const int w16 = tid >> 6;                 // 0..15
    const int wg = w16 >> 3;                  // key-split 0/1
    const int wq = w16 & 7;                   // query tile 0..7
    const int ltid = tid & 511;               // within wave-group
    const int lane = tid & 63;
    const int c = lane & 15, g = lane >> 4;
    const int i0 = (itile << 7) + (wq << 4);
    const int jbase = wg * KHALF;

    // K: [2][2][128][40]=40960  V: [2][2][32][136]=34816  tb: 2048 f32 = 8192
    // merge aliases sacc(36864)+sml(2048) over [0, 38912)
    __shared__ __align__(16) char smem[83968];
    _Float16 (*Kl)[2][128][40] = (_Float16(*)[2][128][40])smem;
    _Float16 (*Vl)[2][32][136] = (_Float16(*)[2][32][136])(smem + 40960);
    float* tbl = (float*)(smem + 75776);
    float (*sacc)[16][36] = (float(*)[16][36])smem;
    float (*sml)[2][16] = (float(*)[2][16])(smem + 36864);

    const float LOG2E = 1.44269504088896f;
    const float sc2 = 0.17677669529663687f * LOG2E;
    const float ah2 = alpha[h] * LOG2E;

    const _Float16* Qbh = Qf + (size_t)bh * S_LEN * DH;
    const _Float16* Kbh = Kf + (size_t)bh * S_LEN * DH;
    const _Float16* Vbh = Vf + (size_t)bh * DH * S_LEN;
    const float* tb = tf_all + b * S_LEN;

    f16x8 qfrag = *(const f16x8*)(Qbh + (size_t)(i0 + c) * DH + (g << 3));
    const float ti = tb[i0 + c];

    // staging maps (per wave-group of 512 threads; each thread 1 K + 1 V store)
    const int kr = ltid >> 2, kc = (ltid & 3) << 3;     // K: 128 x 32
    const int vr = ltid >> 4, vc = (ltid & 15) << 3;    // V: 32 x 128

    // stage t_all (whole sequence) once
    tbl[tid] = tb[tid];
    tbl[tid + 1024] = tb[tid + 1024];

    float m2 = -3.0e38f, l = 0.0f;
    f32x4 acc0 = {0.f, 0.f, 0.f, 0.f};
    f32x4 acc1 = {0.f, 0.f, 0.f, 0.f};
    const f32x4 zero = {0.f, 0.f, 0.f, 0.f};

    f16x8 kpre = *(const f16x8*)(Kbh + (size_t)(jbase + kr) * DH + kc);
    f16x8 vpre = *(const f16x8*)(Vbh + (size_t)vr * S_LEN + jbase + vc);
    int buf = 0;

    for (int kt = 0; kt < KHALF; kt += 128) {
        *(f16x8*)&Kl[wg][buf][kr][kc] = kpre;
        *(f16x8*)&Vl[wg][buf][vr][vc] = vpre;
        __syncthreads();
        if (kt + 128 < KHALF) {
            kpre = *(const f16x8*)(Kbh + (size_t)(jbase + kt + 128 + kr) * DH + kc);
            vpre = *(const f16x8*)(Vbh + (size_t)vr * S_LEN + jbase + kt + 128 + vc);
        }
        #pragma unroll
        for (int jj = 0; jj < 128; jj += 32) {
            const int j0 = jbase + kt + jj;
            f16x8 kf0 = *(const f16x8*)&Kl[wg][buf][jj + c][g << 3];
            f16x8 kf1 = *(const f16x8*)&Kl[wg][buf][jj + 16 + c][g << 3];
            f32x4 dA = __builtin_amdgcn_mfma_f32_16x16x32_f16(kf0, qfrag, zero, 0, 0, 0);
            f32x4 dB = __builtin_amdgcn_mfma_f32_16x16x32_f16(kf1, qfrag, zero, 0, 0, 0);
            float4 tjA = *(const float4*)&tbl[j0 + (g << 2)];
            float4 tjB = *(const float4*)&tbl[j0 + 16 + (g << 2)];
            float eA0 = ti - tjA.x, eA1 = ti - tjA.y, eA2 = ti - tjA.z, eA3 = ti - tjA.w;
            float eB0 = ti - tjB.x, eB1 = ti - tjB.y, eB2 = ti - tjB.z, eB3 = ti - tjB.w;
            float sA0 = (eA0 >= 0.f) ? dA[0] * sc2 - ah2 * eA0 : -1e9f;
            float sA1 = (eA1 >= 0.f) ? dA[1] * sc2 - ah2 * eA1 : -1e9f;
            float sA2 = (eA2 >= 0.f) ? dA[2] * sc2 - ah2 * eA2 : -1e9f;
            float sA3 = (eA3 >= 0.f) ? dA[3] * sc2 - ah2 * eA3 : -1e9f;
            float sB0 = (eB0 >= 0.f) ? dB[0] * sc2 - ah2 * eB0 : -1e9f;
            float sB1 = (eB1 >= 0.f) ? dB[1] * sc2 - ah2 * eB1 : -1e9f;
            float sB2 = (eB2 >= 0.f) ? dB[2] * sc2 - ah2 * eB2 : -1e9f;
            float sB3 = (eB3 >= 0.f) ? dB[3] * sc2 - ah2 * eB3 : -1e9f;
            float pmaxl = fmaxf(fmaxf(fmaxf(sA0, sA1), fmaxf(sA2, sA3)),
                                fmaxf(fmaxf(sB0, sB1), fmaxf(sB2, sB3)));
            if (__any(pmaxl > m2 + 8.0f)) {
                float pm = fmaxf(pmaxl, __shfl_xor(pmaxl, 16, 64));
                pm = fmaxf(pm, __shfl_xor(pm, 32, 64));
                float mnew = fmaxf(m2, pm);
                float fsc = __builtin_amdgcn_exp2f(m2 - mnew);
                m2 = mnew;
                l *= fsc; acc0 *= fsc; acc1 *= fsc;
            }
            float pA0 = __builtin_amdgcn_exp2f(sA0 - m2);
            float pA1 = __builtin_amdgcn_exp2f(sA1 - m2);
            float pA2 = __builtin_amdgcn_exp2f(sA2 - m2);
            float pA3 = __builtin_amdgcn_exp2f(sA3 - m2);
            float pB0 = __builtin_amdgcn_exp2f(sB0 - m2);
            float pB1 = __builtin_amdgcn_exp2f(sB1 - m2);
            float pB2 = __builtin_amdgcn_exp2f(sB2 - m2);
            float pB3 = __builtin_amdgcn_exp2f(sB3 - m2);
            l += ((pA0 + pA1) + (pA2 + pA3)) + ((pB0 + pB1) + (pB2 + pB3));
            f16x4 pfA = {(_Float16)pA0, (_Float16)pA1, (_Float16)pA2, (_Float16)pA3};
            f16x4 pfB = {(_Float16)pB0, (_Float16)pB1, (_Float16)pB2, (_Float16)pB3};
            f16x4 vA0 = *(const f16x4*)&Vl[wg][buf][c][jj + (g << 2)];
            f16x4 vA1 = *(const f16x4*)&Vl[wg][buf][16 + c][jj + (g << 2)];
            f16x4 vB0 = *(const f16x4*)&Vl[wg][buf][c][jj + 16 + (g << 2)];
            f16x4 vB1 = *(const f16x4*)&Vl[wg][buf][16 + c][jj + 16 + (g << 2)];
            acc0 = __builtin_amdgcn_mfma_f32_16x16x16f16(vA0, pfA, acc0, 0, 0, 0);
            acc0 = __builtin_amdgcn_mfma_f32_16x16x16f16(vB0, pfB, acc0, 0, 0, 0);
            acc1 = __builtin_amdgcn_mfma_f32_16x16x16f16(vA1, pfA, acc1, 0, 0, 0);
            acc1 = __builtin_amdgcn_mfma_f32_16x16x16f16(vB1, pfB, acc1, 0, 0, 0);
        }
        buf ^= 1;
    }

    l += __shfl_xor(l, 16, 64);
    l += __shfl_xor(l, 32, 64);

    // all waves done reading K/V/t LDS -> safe to alias as merge scratch
    __syncthreads();
    *(f32x4*)&sacc[w16][c][g << 2] = acc0;
    *(f32x4*)&sacc[w16][c][16 + (g << 2)] = acc1;
    if (g == 0) { sml[w16][0][c] = m2; sml[w16][1][c] = l; }
    __syncthreads();

    {
        const int qt = tid >> 7;
        const int q = (tid >> 3) & 15;
        const int dh0 = (tid & 7) << 2;
        float m0 = sml[qt][0][q], m1 = sml[qt + 8][0][q];
        float M = fmaxf(m0, m1);
        float f0 = __builtin_amdgcn_exp2f(m0 - M);
        float f1 = __builtin_amdgcn_exp2f(m1 - M);
        float L = sml[qt][1][q] * f0 + sml[qt + 8][1][q] * f1;
        float a0 = sacc[qt][q][dh0 + 0] * f0 + sacc[qt + 8][q][dh0 + 0] * f1;
        float a1 = sacc[qt][q][dh0 + 1] * f0 + sacc[qt + 8][q][dh0 + 1] * f1;
        float a2 = sacc[qt][q][dh0 + 2] * f0 + sacc[qt + 8][q][dh0 + 2] * f1;
        float a3 = sacc[qt][q][dh0 + 3] * f0 + sacc[qt + 8][q][dh0 + 3] * f1;
        if (M < -4.9e8f) {
            // fully-masked row: reference = uniform softmax over ALL 2048 keys.
            float vs0 = 0.f, vs1 = 0.f, vs2 = 0.f, vs3 = 0.f;
            const _Float16* vp = Vbh + (size_t)dh0 * S_LEN + CTX;
            for (int j = 0; j < QQ; j += 8) {
                f16x8 x0 = *(const f16x8*)(vp + j);
                f16x8 x1 = *(const f16x8*)(vp + S_LEN + j);
                f16x8 x2 = *(const f16x8*)(vp + 2 * S_LEN + j);
                f16x8 x3 = *(const f16x8*)(vp + 3 * S_LEN + j);
                #pragma unroll
                for (int e = 0; e < 8; e++) {
                    vs0 += (float)x0[e]; vs1 += (float)x1[e];
                    vs2 += (float)x2[e]; vs3 += (float)x3[e];
                }
            }
            a0 += vs0; a1 += vs1; a2 += vs2; a3 += vs3;
            L += (float)QQ;
        }
        float inv = 1.0f / L;
        int row = b * S_LEN + (itile << 7) + (qt << 4) + q;
        f16x4 o = {(_Float16)(a0 * inv), (_Float16)(a1 * inv),
                   (_Float16)(a2 * inv), (_Float16)(a3 * inv)};
        *(f16x4*)(O + (size_t)row * DD + h * DH + dh0) = o;
    }
}

// ---------------- Output head ----------------
__global__ __launch_bounds__(256) void outhead_k(
    const float* __restrict__ Z, const float* __restrict__ Wout,
    const float* __restrict__ bout, float* __restrict__ out)
{
    int tid = threadIdx.x;
    int rloc = tid >> 4, ho = tid & 15;
    int qrow = blockIdx.x * 16 + rloc;
    int b = qrow >> 9, qi = qrow & (QQ - 1);
    if (ho < HOUTD) {
        const float* z = Z + (size_t)(b * S_LEN + CTX + qi) * DD;
        const float* wr = Wout + (size_t)ho * DD;
        float s = 0.0f;
        for (int d = 0; d < DD; d += 4) {
            float4 zv = *(const float4*)(z + d);
            float4 wv = *(const float4*)(wr + d);
            s += zv.x * wv.x + zv.y * wv.y + zv.z * wv.z + zv.w * wv.w;
        }
        out[(size_t)(b * QQ + qi) * HOUTD + ho] = s + bout[ho];
    }
}

extern "C" void kernel_launch(void* const* d_in, const int* in_sizes, int n_in,
                              void* d_out, int out_size, void* d_ws, size_t ws_size,
                              hipStream_t stream) {
    (void)in_sizes; (void)n_in; (void)out_size; (void)ws_size;
    const float* ctx_x = (const float*)d_in[0];
    const float* ctx_z = (const float*)d_in[1];
    const float* qry_x = (const float*)d_in[2];
    const int* t_ctx = (const int*)d_in[3];
    const int* t_qry = (const int*)d_in[4];
    const float* W_ctx = (const float*)d_in[5];
    const float* b_ctx = (const float*)d_in[6];
    const float* W_qry = (const float*)d_in[7];
    const float* b_qry = (const float*)d_in[8];
    const float* alpha = (const float*)d_in[9];
    const float* Wqkv = (const float*)d_in[10];
    const float* bqkv = (const float*)d_in[11];
    const float* Wo = (const float*)d_in[12];
    const float* bo = (const float*)d_in[13];
    const float* ln1_s = (const float*)d_in[14];
    const float* ln1_b = (const float*)d_in[15];
    const float* W1 = (const float*)d_in[16];
    const float* b1 = (const float*)d_in[17];
    const float* W2 = (const float*)d_in[18];
    const float* b2 = (const float*)d_in[19];
    const float* ln2_s = (const float*)d_in[20];
    const float* ln2_b = (const float*)d_in[21];
    const float* W_out = (const float*)d_in[22];
    const float* b_out = (const float*)d_in[23];

    float* ws = (float*)d_ws;
    const size_t MTOT = (size_t)BB * S_LEN;       // 4096
    const size_t ZSZ = MTOT * DD;                 // 1M floats
    float* Z   = ws;                              // [0, 1M) f32
    float* Yb  = ws + ZSZ;                        // [1M, 2M) f32
    _Float16* Zh   = (_Float16*)(ws + 2 * ZSZ);          // 1M halfs
    _Float16* AYh  = (_Float16*)(ws + 2 * ZSZ + ZSZ / 2);
    _Float16* FF1h = (_Float16*)(ws + 3 * ZSZ);          // 4M halfs -> [3M,5M)
    _Float16* Qh   = (_Float16*)(ws + 5 * ZSZ);
    _Float16* Kh   = (_Float16*)(ws + 5 * ZSZ + ZSZ / 2);
    _Float16* Vh   = (_Float16*)(ws + 6 * ZSZ);
    float* tf_all  = ws + 6 * ZSZ + ZSZ / 2;             // 4096 floats
    _Float16* Whqkv = (_Float16*)(ws + 6 * ZSZ + ZSZ / 2 + 4096);
    _Float16* Who   = Whqkv + (size_t)NL * 3 * DD * DD;
    _Float16* Wh1   = Who   + (size_t)NL * DD * DD;
    _Float16* Wh2   = Wh1   + (size_t)NL * DFF * DD;
    // split-K partial buffers (fresh space; ws is ~268 MB, weights end < 9M floats)
    float* Yb1 = ws + 9 * ZSZ;
    float* Yb2 = ws + 10 * ZSZ;
    float* Yb3 = ws + 11 * ZSZ;

    {
        int n4tot = N4_QKV + N4_WO + N4_W1 + N4_W2;
        cvtall_k<<<(n4tot + 255) / 256, 256, 0, stream>>>(
            Wqkv, Wo, W1, W2, Whqkv, Who, Wh1, Wh2);
    }

    embed_k<<<MTOT, 256, 0, stream>>>(ctx_x, ctx_z, qry_x, W_ctx, b_ctx, W_qry, b_qry,
                                      t_ctx, t_qry, Z, Zh, tf_all);

    for (int l = 0; l < NL; l++) {
        hgemm_k<<<dim3(MTOT / 64, (3 * DD) / 64, 1), 256, 0, stream>>>(
            Zh, Whqkv + (size_t)l * 3 * DD * DD, bqkv + (size_t)l * 3 * DD,
            nullptr, nullptr, nullptr, nullptr, nullptr,
            (int)MTOT, 3 * DD, DD, DD, 2, Qh, Kh, Vh);
        attn_k<<<BB * NH * (S_LEN / 128), 1024, 0, stream>>>(
            Qh, Kh, Vh, tf_all, alpha, AYh);
        gemmln_k<<<MTOT / 16, 256, 0, stream>>>(
            AYh, Who + (size_t)l * DD * DD, bo + (size_t)l * DD,
            Z, Zh, ln1_s + (size_t)l * DD, ln1_b + (size_t)l * DD);
        hgemm_k<<<dim3(MTOT / 64, DFF / 64, 1), 256, 0, stream>>>(
            Zh, Wh1 + (size_t)l * DFF * DD, b1 + (size_t)l * DFF,
            nullptr, nullptr, nullptr, nullptr, FF1h,
            (int)MTOT, DFF, DD, DD, 1, nullptr, nullptr, nullptr);
        hgemm_k<<<dim3(MTOT / 64, DD / 64, 4), 256, 0, stream>>>(
            FF1h, Wh2 + (size_t)l * DD * DFF, b2 + (size_t)l * DD,
            Yb, Yb1, Yb2, Yb3, nullptr,
            (int)MTOT, DD, DFF / 4, DFF, 0, nullptr, nullptr, nullptr);
        ln4_k<<<MTOT / 4, 256, 0, stream>>>(
            Z, Yb, Yb1, Yb2, Yb3,
            ln2_s + (size_t)l * DD, ln2_b + (size_t)l * DD, Zh);
    }

    outhead_k<<<(BB * QQ) / 16, 256, 0, stream>>>(Z, W_out, b_out, (float*)d_out);
}

// Round 18
// 391.195 us; speedup vs baseline: 1.2709x; 1.0821x over previous
//
#include <hip/hip_runtime.h>
#include <hip/hip_bf16.h>
#include <cstddef>

#define BB   2
#define CTX  1536
#define QQ   512
#define S_LEN 2048
#define DD   256
#define NH   8
#define DH   32
#define DFF  1024
#define NL   6
#define LIN  20
#define HOUTD 10
#define KHALF (CTX / 2)      // 768 keys per wave-group

typedef _Float16 f16x2 __attribute__((ext_vector_type(2)));
typedef _Float16 f16x4 __attribute__((ext_vector_type(4)));
typedef _Float16 f16x8 __attribute__((ext_vector_type(8)));
typedef float f32x4 __attribute__((ext_vector_type(4)));

#define N4_QKV (NL * 3 * DD * DD / 4)
#define N4_WO  (NL * DD * DD / 4)
#define N4_W1  (NL * DFF * DD / 4)
#define N4_W2  (NL * DD * DFF / 4)

// Q pre-scale: (1/sqrt(32)) * log2(e), folded into the qkv epilogue.
#define QSCALE (0.17677669529663687f * 1.44269504088896f)

// ---------------- fp32 -> f16 convert (all weights, one launch) ----------------
__global__ __launch_bounds__(256) void cvtall_k(
    const float* __restrict__ wqkv, const float* __restrict__ wo,
    const float* __restrict__ w1, const float* __restrict__ w2,
    _Float16* __restrict__ hqkv, _Float16* __restrict__ ho,
    _Float16* __restrict__ h1, _Float16* __restrict__ h2)
{
    int i = blockIdx.x * 256 + threadIdx.x;
    const float* s; _Float16* t; int j = i;
    if (j < N4_QKV) { s = wqkv; t = hqkv; }
    else if ((j -= N4_QKV) < N4_WO) { s = wo; t = ho; }
    else if ((j -= N4_WO) < N4_W1) { s = w1; t = h1; }
    else if ((j -= N4_W1) < N4_W2) { s = w2; t = h2; }
    else return;
    float4 v = ((const float4*)s)[j];
    f16x4 h = {(_Float16)v.x, (_Float16)v.y, (_Float16)v.z, (_Float16)v.w};
    ((f16x4*)t)[j] = h;
}

// ---------------- Embed: Z[b*S+s][d] (+f16 copy, +t_all float) ----------------
__global__ __launch_bounds__(256) void embed_k(
    const float* __restrict__ ctx_x, const float* __restrict__ ctx_z,
    const float* __restrict__ qry_x,
    const float* __restrict__ W_ctx, const float* __restrict__ b_ctx,
    const float* __restrict__ W_qry, const float* __restrict__ b_qry,
    const int* __restrict__ t_ctx, const int* __restrict__ t_qry,
    float* __restrict__ Z, _Float16* __restrict__ Zh, float* __restrict__ tf)
{
    int row = blockIdx.x;            // 0..4095
    int d = threadIdx.x;             // 0..255
    int b = row >> 11, s = row & (S_LEN - 1);
    float acc;
    if (s < CTX) {
        const float* x1 = ctx_x + (size_t)(b * CTX + s) * LIN;
        const float* x2 = ctx_z + (size_t)(b * CTX + s) * HOUTD;
        const float* w = W_ctx + (size_t)d * (LIN + HOUTD);
        acc = b_ctx[d];
        #pragma unroll
        for (int i = 0; i < LIN; i++) acc += x1[i] * w[i];
        #pragma unroll
        for (int i = 0; i < HOUTD; i++) acc += x2[i] * w[LIN + i];
        if (d == 0) tf[row] = (float)t_ctx[b * CTX + s];
    } else {
        int qi = s - CTX;
        const float* x1 = qry_x + (size_t)(b * QQ + qi) * LIN;
        const float* w = W_qry + (size_t)d * (LIN + HOUTD);
        acc = b_qry[d];
        #pragma unroll
        for (int i = 0; i < LIN; i++) acc += x1[i] * w[i];
        if (d == 0) tf[row] = (float)t_qry[b * QQ + qi];
    }
    Z[(size_t)row * DD + d] = acc;
    Zh[(size_t)row * DD + d] = (_Float16)acc;
}

// ---------------- MFMA f16 GEMM 64x64 (dbuf LDS, pad-40, split-K capable) ----------------
// mode 0: fp32 out (Y0..Y3 per blockIdx.z; bias only on z==0)
// mode 1: relu -> f16 Yh   mode 2: f16 Q(prescaled),K:[B,NH,S,DH] V:[B,NH,DH,S]
__global__ __launch_bounds__(256) void hgemm_k(
    const _Float16* __restrict__ X, const _Float16* __restrict__ W,
    const float* __restrict__ bias, float* __restrict__ Y0,
    float* __restrict__ Y1, float* __restrict__ Y2, float* __restrict__ Y3,
    _Float16* __restrict__ Yh,
    int M, int N, int K, int lda, int mode,
    _Float16* __restrict__ Qh, _Float16* __restrict__ Kh, _Float16* __restrict__ Vh)
{
    __shared__ _Float16 Ah[2][64][40];
    __shared__ _Float16 Bh[2][64][40];
    const int tid = threadIdx.x;
    const int bm = blockIdx.x << 6, bn = blockIdx.y << 6;
    const int kbase = blockIdx.z * K;
    const int lr = tid >> 2;
    const int lk = (tid & 3) << 3;
    const int w = tid >> 6, lane = tid & 63;
    const int c = lane & 15, g = lane >> 4;
    const int wm = (w >> 1) << 5, wn = (w & 1) << 5;

    f32x4 acc00 = {0.f,0.f,0.f,0.f}, acc01 = {0.f,0.f,0.f,0.f};
    f32x4 acc10 = {0.f,0.f,0.f,0.f}, acc11 = {0.f,0.f,0.f,0.f};

    const _Float16* Xp = X + (size_t)(bm + lr) * lda + kbase + lk;
    const _Float16* Wp = W + (size_t)(bn + lr) * lda + kbase + lk;

    f16x8 xa = *(const f16x8*)Xp;
    f16x8 wb = *(const f16x8*)Wp;
    const int nt = K >> 5;
    int buf = 0;
    for (int t = 0; t < nt; t++) {
        *(f16x8*)&Ah[buf][lr][lk] = xa;
        *(f16x8*)&Bh[buf][lr][lk] = wb;
        __syncthreads();
        if (t + 1 < nt) {
            xa = *(const f16x8*)(Xp + ((size_t)(t + 1) << 5));
            wb = *(const f16x8*)(Wp + ((size_t)(t + 1) << 5));
        }
        f16x8 a0 = *(const f16x8*)&Ah[buf][wm + c][g << 3];
        f16x8 a1 = *(const f16x8*)&Ah[buf][wm + 16 + c][g << 3];
        f16x8 b0 = *(const f16x8*)&Bh[buf][wn + c][g << 3];
        f16x8 b1 = *(const f16x8*)&Bh[buf][wn + 16 + c][g << 3];
        acc00 = __builtin_amdgcn_mfma_f32_16x16x32_f16(a0, b0, acc00, 0, 0, 0);
        acc01 = __builtin_amdgcn_mfma_f32_16x16x32_f16(a0, b1, acc01, 0, 0, 0);
        acc10 = __builtin_amdgcn_mfma_f32_16x16x32_f16(a1, b0, acc10, 0, 0, 0);
        acc11 = __builtin_amdgcn_mfma_f32_16x16x32_f16(a1, b1, acc11, 0, 0, 0);
        buf ^= 1;
    }

    float* Yt = (blockIdx.z == 0) ? Y0 : (blockIdx.z == 1) ? Y1
              : (blockIdx.z == 2) ? Y2 : Y3;
    f32x4 accs[2][2] = {{acc00, acc01}, {acc10, acc11}};
    #pragma unroll
    for (int fm = 0; fm < 2; fm++) {
        #pragma unroll
        for (int fn = 0; fn < 2; fn++) {
            int colb = bn + wn + (fn << 4) + c;
            float bv = (blockIdx.z == 0) ? bias[colb] : 0.0f;
            #pragma unroll
            for (int r = 0; r < 4; r++) {
                int row = bm + wm + (fm << 4) + (g << 2) + r;
                float v = accs[fm][fn][r] + bv;
                if (mode == 0) {
                    Yt[(size_t)row * N + colb] = v;
                } else if (mode == 1) {
                    Yh[(size_t)row * N + colb] = (_Float16)fmaxf(v, 0.0f);
                } else {
                    int which = colb >> 8, h = (colb >> 5) & 7, d = colb & 31;
                    int bb2 = row >> 11, ss = row & (S_LEN - 1);
                    int bhi = (bb2 << 3) + h;
                    if (which == 0)
                        Qh[((size_t)bhi * S_LEN + ss) * DH + d] = (_Float16)(v * QSCALE);
                    else if (which == 1)
                        Kh[((size_t)bhi * S_LEN + ss) * DH + d] = (_Float16)v;
                    else
                        Vh[((size_t)bhi * DH + d) * S_LEN + ss] = (_Float16)v;
                }
            }
        }
    }
}

// ---------------- fused Wo GEMM + residual + LayerNorm (BM=16, grid 256) ----------------
__global__ __launch_bounds__(256) void gemmln_k(
    const _Float16* __restrict__ X, const _Float16* __restrict__ W,
    const float* __restrict__ bias, float* __restrict__ Z,
    _Float16* __restrict__ Zh, const float* __restrict__ sw,
    const float* __restrict__ bw)
{
    __shared__ _Float16 Ast[2][16][40];
    __shared__ _Float16 Bst[2][256][40];
    __shared__ float lred[4][16][2];
    const int tid = threadIdx.x;
    const int bm = blockIdx.x << 4;
    const int w = tid >> 6, lane = tid & 63;
    const int c = lane & 15, g = lane >> 4;
    const int br = tid >> 2, bk = (tid & 3) << 3;

    f32x4 acc[4] = {};
    const _Float16* Wp = W + (size_t)br * DD + bk;
    f16x8 p0 = *(const f16x8*)Wp;
    f16x8 p1 = *(const f16x8*)(Wp + (size_t)64 * DD);
    f16x8 p2 = *(const f16x8*)(Wp + (size_t)128 * DD);
    f16x8 p3 = *(const f16x8*)(Wp + (size_t)192 * DD);
    f16x8 xa;
    if (tid < 64) xa = *(const f16x8*)(X + (size_t)(bm + br) * DD + bk);
    int buf = 0;
    #pragma unroll
    for (int t = 0; t < 8; t++) {
        if (tid < 64) *(f16x8*)&Ast[buf][br][bk] = xa;
        *(f16x8*)&Bst[buf][br][bk] = p0;
        *(f16x8*)&Bst[buf][br + 64][bk] = p1;
        *(f16x8*)&Bst[buf][br + 128][bk] = p2;
        *(f16x8*)&Bst[buf][br + 192][bk] = p3;
        __syncthreads();
        if (t < 7) {
            int o = (t + 1) << 5;
            if (tid < 64) xa = *(const f16x8*)(X + (size_t)(bm + br) * DD + o + bk);
            p0 = *(const f16x8*)(Wp + o);
            p1 = *(const f16x8*)(Wp + (size_t)64 * DD + o);
            p2 = *(const f16x8*)(Wp + (size_t)128 * DD + o);
            p3 = *(const f16x8*)(Wp + (size_t)192 * DD + o);
        }
        f16x8 a = *(const f16x8*)&Ast[buf][c][g << 3];
        #pragma unroll
        for (int f = 0; f < 4; f++) {
            f16x8 bfr = *(const f16x8*)&Bst[buf][(w << 6) + (f << 4) + c][g << 3];
            acc[f] = __builtin_amdgcn_mfma_f32_16x16x32_f16(a, bfr, acc[f], 0, 0, 0);
        }
        buf ^= 1;
    }

    float vals[4][4];
    float s1[4] = {0.f,0.f,0.f,0.f}, s2[4] = {0.f,0.f,0.f,0.f};
    #pragma unroll
    for (int f = 0; f < 4; f++) {
        int col = (w << 6) + (f << 4) + c;
        float bv = bias[col];
        #pragma unroll
        for (int r = 0; r < 4; r++) {
            int row = bm + (g << 2) + r;
            float v = acc[f][r] + bv + Z[(size_t)row * DD + col];
            vals[f][r] = v; s1[r] += v; s2[r] += v * v;
        }
    }
    #pragma unroll
    for (int off = 1; off < 16; off <<= 1) {
        #pragma unroll
        for (int r = 0; r < 4; r++) {
            s1[r] += __shfl_xor(s1[r], off, 64);
            s2[r] += __shfl_xor(s2[r], off, 64);
        }
    }
    if (c == 0) {
        #pragma unroll
        for (int r = 0; r < 4; r++) {
            lred[w][(g << 2) + r][0] = s1[r];
            lred[w][(g << 2) + r][1] = s2[r];
        }
    }
    __syncthreads();
    float mu_r[4], rs_r[4];
    #pragma unroll
    for (int r = 0; r < 4; r++) {
        int lr_ = (g << 2) + r;
        float S1 = lred[0][lr_][0] + lred[1][lr_][0] + lred[2][lr_][0] + lred[3][lr_][0];
        float S2 = lred[0][lr_][1] + lred[1][lr_][1] + lred[2][lr_][1] + lred[3][lr_][1];
        float mu = S1 * (1.0f / 256.0f);
        float var = S2 * (1.0f / 256.0f) - mu * mu;
        mu_r[r] = mu; rs_r[r] = rsqrtf(var + 1e-5f);
    }
    #pragma unroll
    for (int f = 0; f < 4; f++) {
        int col = (w << 6) + (f << 4) + c;
        float swv = sw[col], bwv = bw[col];
        #pragma unroll
        for (int r = 0; r < 4; r++) {
            int row = bm + (g << 2) + r;
            float o = (vals[f][r] - mu_r[r]) * rs_r[r] * swv + bwv;
            Z[(size_t)row * DD + col] = o;
            Zh[(size_t)row * DD + col] = (_Float16)o;
        }
    }
}

// ---------------- Residual + LN (Z + Y0..Y3), one WAVE per row ----------------
__global__ __launch_bounds__(256) void ln4_k(
    float* __restrict__ Z, const float* __restrict__ Y0,
    const float* __restrict__ Y1, const float* __restrict__ Y2,
    const float* __restrict__ Y3,
    const float* __restrict__ sw, const float* __restrict__ bw,
    _Float16* __restrict__ Zh)
{
    const int w = threadIdx.x >> 6, lane = threadIdx.x & 63;
    const int row = (blockIdx.x << 2) + w;
    float4 z = ((const float4*)(Z + (size_t)row * DD))[lane];
    float4 y0 = ((const float4*)(Y0 + (size_t)row * DD))[lane];
    float4 y1 = ((const float4*)(Y1 + (size_t)row * DD))[lane];
    float4 y2 = ((const float4*)(Y2 + (size_t)row * DD))[lane];
    float4 y3 = ((const float4*)(Y3 + (size_t)row * DD))[lane];
    float x0 = z.x + (y0.x + y1.x) + (y2.x + y3.x);
    float x1 = z.y + (y0.y + y1.y) + (y2.y + y3.y);
    float x2 = z.z + (y0.z + y1.z) + (y2.z + y3.z);
    float x3 = z.w + (y0.w + y1.w) + (y2.w + y3.w);
    float s1 = (x0 + x1) + (x2 + x3);
    float s2 = (x0 * x0 + x1 * x1) + (x2 * x2 + x3 * x3);
    #pragma unroll
    for (int off = 1; off < 64; off <<= 1) {
        s1 += __shfl_xor(s1, off, 64);
        s2 += __shfl_xor(s2, off, 64);
    }
    float mu = s1 * (1.0f / 256.0f);
    float var = s2 * (1.0f / 256.0f) - mu * mu;
    float rs = rsqrtf(var + 1e-5f);
    float4 sv = ((const float4*)sw)[lane];
    float4 bv = ((const float4*)bw)[lane];
    float o0 = (x0 - mu) * rs * sv.x + bv.x;
    float o1 = (x1 - mu) * rs * sv.y + bv.y;
    float o2 = (x2 - mu) * rs * sv.z + bv.z;
    float o3 = (x3 - mu) * rs * sv.w + bv.w;
    ((float4*)(Z + (size_t)row * DD))[lane] = make_float4(o0, o1, o2, o3);
    f16x4 oh = {(_Float16)o0, (_Float16)o1, (_Float16)o2, (_Float16)o3};
    ((f16x4*)(Zh + (size_t)row * DD))[lane] = oh;
}

// ---------------- Final-layer LN: query rows only, f32 Z only ----------------
__global__ __launch_bounds__(256) void ln4q_k(
    float* __restrict__ Z, const float* __restrict__ Y0,
    const float* __restrict__ Y1, const float* __restrict__ Y2,
    const float* __restrict__ Y3,
    const float* __restrict__ sw, const float* __restrict__ bw)
{
    const int w = threadIdx.x >> 6, lane = threadIdx.x & 63;
    const int qrow = (blockIdx.x << 2) + w;           // 0..1023
    const int b = qrow >> 9;
    const int row = b * S_LEN + CTX + (qrow & (QQ - 1));
    float4 z = ((const float4*)(Z + (size_t)row * DD))[lane];
    float4 y0 = ((const float4*)(Y0 + (size_t)row * DD))[lane];
    float4 y1 = ((const float4*)(Y1 + (size_t)row * DD))[lane];
    float4 y2 = ((const float4*)(Y2 + (size_t)row * DD))[lane];
    float4 y3 = ((const float4*)(Y3 + (size_t)row * DD))[lane];
    float x0 = z.x + (y0.x + y1.x) + (y2.x + y3.x);
    float x1 = z.y + (y0.y + y1.y) + (y2.y + y3.y);
    float x2 = z.z + (y0.z + y1.z) + (y2.z + y3.z);
    float x3 = z.w + (y0.w + y1.w) + (y2.w + y3.w);
    float s1 = (x0 + x1) + (x2 + x3);
    float s2 = (x0 * x0 + x1 * x1) + (x2 * x2 + x3 * x3);
    #pragma unroll
    for (int off = 1; off < 64; off <<= 1) {
        s1 += __shfl_xor(s1, off, 64);
        s2 += __shfl_xor(s2, off, 64);
    }
    float mu = s1 * (1.0f / 256.0f);
    float var = s2 * (1.0f / 256.0f) - mu * mu;
    float rs = rsqrtf(var + 1e-5f);
    float4 sv = ((const float4*)sw)[lane];
    float4 bv = ((const float4*)bw)[lane];
    float o0 = (x0 - mu) * rs * sv.x + bv.x;
    float o1 = (x1 - mu) * rs * sv.y + bv.y;
    float o2 = (x2 - mu) * rs * sv.z + bv.z;
    float o3 = (x3 - mu) * rs * sv.w + bv.w;
    ((float4*)(Z + (size_t)row * DD))[lane] = make_float4(o0, o1, o2, o3);
}

// ---------------- MFMA flash attention ----------------
// 1024 thr = 16 waves = 2 key-split wg x 8 query tiles (128 q/block).
// 128-key tiles, dbuf; t and alpha-scaled t staged in LDS; scores in shifted
// log2 domain (Q pre-scaled by QSCALE, per-query shift cancels in softmax).
__global__ __launch_bounds__(1024, 4) void attn_k(
    const _Float16* __restrict__ Qf, const _Float16* __restrict__ Kf,
    const _Float16* __restrict__ Vf, const float* __restrict__ tf_all,
    const float* __restrict__ alpha, _Float16* __restrict__ O)
{
    const int bh = blockIdx.x >> 4;           // /(S/128)=16
    const int itile = blockIdx.x & 15;
    const int b = bh >> 3, h = bh & 7;
    const int tid = threadIdx.x;
    const int w16 = tid >> 6;                 // 0..15
    const int wg = w16 >> 3;                  // key-split 0/1
    const int wq = w16 & 7;                   // query tile 0..7
    const int ltid = tid & 511;               // within wave-group
    const int lane = tid & 63;
    const int c = lane & 15, g = lane >> 4;
    const int i0 = (itile << 7) + (wq << 4);
    const int jbase = wg * KHALF;

    // K: 40960  V: 34816 (=75776)  tbl: 8192 (=83968)  ptl: 8192 -> 92160
    // merge aliases sacc(36864)+sml(2048) over [0, 38912)
    __shared__ __align__(16) char smem[92160];
    _Float16 (*Kl)[2][128][40] = (_Float16(*)[2][128][40])smem;
    _Float16 (*Vl)[2][32][136] = (_Float16(*)[2][32][136])(smem + 40960);
    float* tbl = (float*)(smem + 75776);
    float* ptl = (float*)(smem + 83968);
    float (*sacc)[16][36] = (float(*)[16][36])smem;
    float (*sml)[2][16] = (float(*)[2][16])(smem + 36864);

    const float LOG2E = 1.44269504088896f;
    const float ah2 = alpha[h] * LOG2E;

    const _Float16* Qbh = Qf + (size_t)bh * S_LEN * DH;
    const _Float16* Kbh = Kf + (size_t)bh * S_LEN * DH;
    const _Float16* Vbh = Vf + (size_t)bh * DH * S_LEN;
    const float* tb = tf_all + b * S_LEN;

    f16x8 qfrag = *(const f16x8*)(Qbh + (size_t)(i0 + c) * DH + (g << 3));
    const float ti = tb[i0 + c];

    const int kr = ltid >> 2, kc = (ltid & 3) << 3;     // K: 128 x 32
    const int vr = ltid >> 4, vc = (ltid & 15) << 3;    // V: 32 x 128

    // stage t (compare) and ah2*t (bias) once
    {
        float t0 = tb[tid], t1 = tb[tid + 1024];
        tbl[tid] = t0; tbl[tid + 1024] = t1;
        ptl[tid] = ah2 * t0; ptl[tid + 1024] = ah2 * t1;
    }

    float m2 = -3.0e38f, l = 0.0f;
    f32x4 acc0 = {0.f, 0.f, 0.f, 0.f};
    f32x4 acc1 = {0.f, 0.f, 0.f, 0.f};
    const f32x4 zero = {0.f, 0.f, 0.f, 0.f};

    f16x8 kpre = *(const f16x8*)(Kbh + (size_t)(jbase + kr) * DH + kc);
    f16x8 vpre = *(const f16x8*)(Vbh + (size_t)vr * S_LEN + jbase + vc);
    int buf = 0;

    for (int kt = 0; kt < KHALF; kt += 128) {
        *(f16x8*)&Kl[wg][buf][kr][kc] = kpre;
        *(f16x8*)&Vl[wg][buf][vr][vc] = vpre;
        __syncthreads();
        if (kt + 128 < KHALF) {
            kpre = *(const f16x8*)(Kbh + (size_t)(jbase + kt + 128 + kr) * DH + kc);
            vpre = *(const f16x8*)(Vbh + (size_t)vr * S_LEN + jbase + kt + 128 + vc);
        }
        #pragma unroll
        for (int jj = 0; jj < 128; jj += 32) {
            const int j0 = jbase + kt + jj;
            f16x8 kf0 = *(const f16x8*)&Kl[wg][buf][jj + c][g << 3];
            f16x8 kf1 = *(const f16x8*)&Kl[wg][buf][jj + 16 + c][g << 3];
            __builtin_amdgcn_s_setprio(1);
            f32x4 dA = __builtin_amdgcn_mfma_f32_16x16x32_f16(kf0, qfrag, zero, 0, 0, 0);
            f32x4 dB = __builtin_amdgcn_mfma_f32_16x16x32_f16(kf1, qfrag, zero, 0, 0, 0);
            __builtin_amdgcn_s_setprio(0);
            float4 tjA = *(const float4*)&tbl[j0 + (g << 2)];
            float4 tjB = *(const float4*)&tbl[j0 + 16 + (g << 2)];
            float4 ptA = *(const float4*)&ptl[j0 + (g << 2)];
            float4 ptB = *(const float4*)&ptl[j0 + 16 + (g << 2)];
            // shifted score: s' = d + ah2*tj   (true s = s' - ah2*ti, shift
            // cancels in softmax). mask on raw t.
            float sA0 = (tjA.x <= ti) ? dA[0] + ptA.x : -1e9f;
            float sA1 = (tjA.y <= ti) ? dA[1] + ptA.y : -1e9f;
            float sA2 = (tjA.z <= ti) ? dA[2] + ptA.z : -1e9f;
            float sA3 = (tjA.w <= ti) ? dA[3] + ptA.w : -1e9f;
            float sB0 = (tjB.x <= ti) ? dB[0] + ptB.x : -1e9f;
            float sB1 = (tjB.y <= ti) ? dB[1] + ptB.y : -1e9f;
            float sB2 = (tjB.z <= ti) ? dB[2] + ptB.z : -1e9f;
            float sB3 = (tjB.w <= ti) ? dB[3] + ptB.w : -1e9f;
            float pmaxl = fmaxf(fmaxf(fmaxf(sA0, sA1), fmaxf(sA2, sA3)),
                                fmaxf(fmaxf(sB0, sB1), fmaxf(sB2, sB3)));
            if (__any(pmaxl > m2 + 8.0f)) {
                float pm = fmaxf(pmaxl, __shfl_xor(pmaxl, 16, 64));
                pm = fmaxf(pm, __shfl_xor(pm, 32, 64));
                float mnew = fmaxf(m2, pm);
                float fsc = __builtin_amdgcn_exp2f(m2 - mnew);
                m2 = mnew;
                l *= fsc; acc0 *= fsc; acc1 *= fsc;
            }
            float pA0 = __builtin_amdgcn_exp2f(sA0 - m2);
            float pA1 = __builtin_amdgcn_exp2f(sA1 - m2);
            float pA2 = __builtin_amdgcn_exp2f(sA2 - m2);
            float pA3 = __builtin_amdgcn_exp2f(sA3 - m2);
            float pB0 = __builtin_amdgcn_exp2f(sB0 - m2);
            float pB1 = __builtin_amdgcn_exp2f(sB1 - m2);
            float pB2 = __builtin_amdgcn_exp2f(sB2 - m2);
            float pB3 = __builtin_amdgcn_exp2f(sB3 - m2);
            l += ((pA0 + pA1) + (pA2 + pA3)) + ((pB0 + pB1) + (pB2 + pB3));
            f16x4 pfA = {(_Float16)pA0, (_Float16)pA1, (_Float16)pA2, (_Float16)pA3};
            f16x4 pfB = {(_Float16)pB0, (_Float16)pB1, (_Float16)pB2, (_Float16)pB3};
            f16x4 vA0 = *(const f16x4*)&Vl[wg][buf][c][jj + (g << 2)];
            f16x4 vA1 = *(const f16x4*)&Vl[wg][buf][16 + c][jj + (g << 2)];
            f16x4 vB0 = *(const f16x4*)&Vl[wg][buf][c][jj + 16 + (g << 2)];
            f16x4 vB1 = *(const f16x4*)&Vl[wg][buf][16 + c][jj + 16 + (g << 2)];
            __builtin_amdgcn_s_setprio(1);
            acc0 = __builtin_amdgcn_mfma_f32_16x16x16f16(vA0, pfA, acc0, 0, 0, 0);
            acc0 = __builtin_amdgcn_mfma_f32_16x16x16f16(vB0, pfB, acc0, 0, 0, 0);
            acc1 = __builtin_amdgcn_mfma_f32_16x16x16f16(vA1, pfA, acc1, 0, 0, 0);
            acc1 = __builtin_amdgcn_mfma_f32_16x16x16f16(vB1, pfB, acc1, 0, 0, 0);
            __builtin_amdgcn_s_setprio(0);
        }
        buf ^= 1;
    }

    l += __shfl_xor(l, 16, 64);
    l += __shfl_xor(l, 32, 64);

    // all waves done reading K/V/t LDS -> safe to alias as merge scratch
    __syncthreads();
    *(f32x4*)&sacc[w16][c][g << 2] = acc0;
    *(f32x4*)&sacc[w16][c][16 + (g << 2)] = acc1;
    if (g == 0) { sml[w16][0][c] = m2; sml[w16][1][c] = l; }
    __syncthreads();

    {
        const int qt = tid >> 7;
        const int q = (tid >> 3) & 15;
        const int dh0 = (tid & 7) << 2;
        float m0 = sml[qt][0][q], m1 = sml[qt + 8][0][q];
        float M = fmaxf(m0, m1);
        float f0 = __builtin_amdgcn_exp2f(m0 - M);
        float f1 = __builtin_amdgcn_exp2f(m1 - M);
        float L = sml[qt][1][q] * f0 + sml[qt + 8][1][q] * f1;
        float a0 = sacc[qt][q][dh0 + 0] * f0 + sacc[qt + 8][q][dh0 + 0] * f1;
        float a1 = sacc[qt][q][dh0 + 1] * f0 + sacc[qt + 8][q][dh0 + 1] * f1;
        float a2 = sacc[qt][q][dh0 + 2] * f0 + sacc[qt + 8][q][dh0 + 2] * f1;
        float a3 = sacc[qt][q][dh0 + 3] * f0 + sacc[qt + 8][q][dh0 + 3] * f1;
        if (M < -4.9e8f) {
            // fully-masked row: reference = uniform softmax over ALL 2048 keys.
            float vs0 = 0.f, vs1 = 0.f, vs2 = 0.f, vs3 = 0.f;
            const _Float16* vp = Vbh + (size_t)dh0 * S_LEN + CTX;
            for (int j = 0; j < QQ; j += 8) {
                f16x8 x0 = *(const f16x8*)(vp + j);
                f16x8 x1 = *(const f16x8*)(vp + S_LEN + j);
                f16x8 x2 = *(const f16x8*)(vp + 2 * S_LEN + j);
                f16x8 x3 = *(const f16x8*)(vp + 3 * S_LEN + j);
                #pragma unroll
                for (int e = 0; e < 8; e++) {
                    vs0 += (float)x0[e]; vs1 += (float)x1[e];
                    vs2 += (float)x2[e]; vs3 += (float)x3[e];
                }
            }
            a0 += vs0; a1 += vs1; a2 += vs2; a3 += vs3;
            L += (float)QQ;
        }
        float inv = 1.0f / L;
        int row = b * S_LEN + (itile << 7) + (qt << 4) + q;
        f16x4 o = {(_Float16)(a0 * inv), (_Float16)(a1 * inv),
                   (_Float16)(a2 * inv), (_Float16)(a3 * inv)};
        *(f16x4*)(O + (size_t)row * DD + h * DH + dh0) = o;
    }
}

// ---------------- Output head ----------------
__global__ __launch_bounds__(256) void outhead_k(
    const float* __restrict__ Z, const float* __restrict__ Wout,
    const float* __restrict__ bout, float* __restrict__ out)
{
    int tid = threadIdx.x;
    int rloc = tid >> 4, ho = tid & 15;
    int qrow = blockIdx.x * 16 + rloc;
    int b = qrow >> 9, qi = qrow & (QQ - 1);
    if (ho < HOUTD) {
        const float* z = Z + (size_t)(b * S_LEN + CTX + qi) * DD;
        const float* wr = Wout + (size_t)ho * DD;
        float s = 0.0f;
        for (int d = 0; d < DD; d += 4) {
            float4 zv = *(const float4*)(z + d);
            float4 wv = *(const float4*)(wr + d);
            s += zv.x * wv.x + zv.y * wv.y + zv.z * wv.z + zv.w * wv.w;
        }
        out[(size_t)(b * QQ + qi) * HOUTD + ho] = s + bout[ho];
    }
}

extern "C" void kernel_launch(void* const* d_in, const int* in_sizes, int n_in,
                              void* d_out, int out_size, void* d_ws, size_t ws_size,
                              hipStream_t stream) {
    (void)in_sizes; (void)n_in; (void)out_size; (void)ws_size;
    const float* ctx_x = (const float*)d_in[0];
    const float* ctx_z = (const float*)d_in[1];
    const float* qry_x = (const float*)d_in[2];
    const int* t_ctx = (const int*)d_in[3];
    const int* t_qry = (const int*)d_in[4];
    const float* W_ctx = (const float*)d_in[5];
    const float* b_ctx = (const float*)d_in[6];
    const float* W_qry = (const float*)d_in[7];
    const float* b_qry = (const float*)d_in[8];
    const float* alpha = (const float*)d_in[9];
    const float* Wqkv = (const float*)d_in[10];
    const float* bqkv = (const float*)d_in[11];
    const float* Wo = (const float*)d_in[12];
    const float* bo = (const float*)d_in[13];
    const float* ln1_s = (const float*)d_in[14];
    const float* ln1_b = (const float*)d_in[15];
    const float* W1 = (const float*)d_in[16];
    const float* b1 = (const float*)d_in[17];
    const float* W2 = (const float*)d_in[18];
    const float* b2 = (const float*)d_in[19];
    const float* ln2_s = (const float*)d_in[20];
    const float* ln2_b = (const float*)d_in[21];
    const float* W_out = (const float*)d_in[22];
    const float* b_out = (const float*)d_in[23];

    float* ws = (float*)d_ws;
    const size_t MTOT = (size_t)BB * S_LEN;       // 4096
    const size_t ZSZ = MTOT * DD;                 // 1M floats
    float* Z   = ws;                              // [0, 1M) f32
    float* Yb  = ws + ZSZ;                        // [1M, 2M) f32
    _Float16* Zh   = (_Float16*)(ws + 2 * ZSZ);          // 1M halfs
    _Float16* AYh  = (_Float16*)(ws + 2 * ZSZ + ZSZ / 2);
    _Float16* FF1h = (_Float16*)(ws + 3 * ZSZ);          // 4M halfs -> [3M,5M)
    _Float16* Qh   = (_Float16*)(ws + 5 * ZSZ);
    _Float16* Kh   = (_Float16*)(ws + 5 * ZSZ + ZSZ / 2);
    _Float16* Vh   = (_Float16*)(ws + 6 * ZSZ);
    float* tf_all  = ws + 6 * ZSZ + ZSZ / 2;             // 4096 floats
    _Float16* Whqkv = (_Float16*)(ws + 6 * ZSZ + ZSZ / 2 + 4096);
    _Float16* Who   = Whqkv + (size_t)NL * 3 * DD * DD;
    _Float16* Wh1   = Who   + (size_t)NL * DD * DD;
    _Float16* Wh2   = Wh1   + (size_t)NL * DFF * DD;
    float* Yb1 = ws + 9 * ZSZ;
    float* Yb2 = ws + 10 * ZSZ;
    float* Yb3 = ws + 11 * ZSZ;

    {
        int n4tot = N4_QKV + N4_WO + N4_W1 + N4_W2;
        cvtall_k<<<(n4tot + 255) / 256, 256, 0, stream>>>(
            Wqkv, Wo, W1, W2, Whqkv, Who, Wh1, Wh2);
    }

    embed_k<<<MTOT, 256, 0, stream>>>(ctx_x, ctx_z, qry_x, W_ctx, b_ctx, W_qry, b_qry,
                                      t_ctx, t_qry, Z, Zh, tf_all);

    for (int l = 0; l < NL; l++) {
        hgemm_k<<<dim3(MTOT / 64, (3 * DD) / 64, 1), 256, 0, stream>>>(
            Zh, Whqkv + (size_t)l * 3 * DD * DD, bqkv + (size_t)l * 3 * DD,
            nullptr, nullptr, nullptr, nullptr, nullptr,
            (int)MTOT, 3 * DD, DD, DD, 2, Qh, Kh, Vh);
        attn_k<<<BB * NH * (S_LEN / 128), 1024, 0, stream>>>(
            Qh, Kh, Vh, tf_all, alpha, AYh);
        gemmln_k<<<MTOT / 16, 256, 0, stream>>>(
            AYh, Who + (size_t)l * DD * DD, bo + (size_t)l * DD,
            Z, Zh, ln1_s + (size_t)l * DD, ln1_b + (size_t)l * DD);
        hgemm_k<<<dim3(MTOT / 64, DFF / 64, 1), 256, 0, stream>>>(
            Zh, Wh1 + (size_t)l * DFF * DD, b1 + (size_t)l * DFF,
            nullptr, nullptr, nullptr, nullptr, FF1h,
            (int)MTOT, DFF, DD, DD, 1, nullptr, nullptr, nullptr);
        hgemm_k<<<dim3(MTOT / 64, DD / 64, 4), 256, 0, stream>>>(
            FF1h, Wh2 + (size_t)l * DD * DFF, b2 + (size_t)l * DD,
            Yb, Yb1, Yb2, Yb3, nullptr,
            (int)MTOT, DD, DFF / 4, DFF, 0, nullptr, nullptr, nullptr);
        if (l < NL - 1) {
            ln4_k<<<MTOT / 4, 256, 0, stream>>>(
                Z, Yb, Yb1, Yb2, Yb3,
                ln2_s + (size_t)l * DD, ln2_b + (size_t)l * DD, Zh);
        } else {
            ln4q_k<<<(BB * QQ) / 4, 256, 0, stream>>>(
                Z, Yb, Yb1, Yb2, Yb3,
                ln2_s + (size_t)l * DD, ln2_b + (size_t)l * DD);
        }
    }

    outhead_k<<<(BB * QQ) / 16, 256, 0, stream>>>(Z, W_out, b_out, (float*)d_out);
}

// Round 19
// 368.522 us; speedup vs baseline: 1.3490x; 1.0615x over previous
//
#include <hip/hip_runtime.h>
#include <hip/hip_bf16.h>
#include <cstddef>

#define BB   2
#define CTX  1536
#define QQ   512
#define S_LEN 2048
#define DD   256
#define NH   8
#define DH   32
#define DFF  1024
#define NL   6
#define LIN  20
#define HOUTD 10
#define KHALF (CTX / 2)      // 768 keys per wave-group

typedef _Float16 f16x2 __attribute__((ext_vector_type(2)));
typedef _Float16 f16x4 __attribute__((ext_vector_type(4)));
typedef _Float16 f16x8 __attribute__((ext_vector_type(8)));
typedef float f32x4 __attribute__((ext_vector_type(4)));

#define N4_QKV (NL * 3 * DD * DD / 4)
#define N4_WO  (NL * DD * DD / 4)
#define N4_W1  (NL * DFF * DD / 4)
#define N4_W2  (NL * DD * DFF / 4)

// Q pre-scale: (1/sqrt(32)) * log2(e), folded into the qkv epilogue.
#define QSCALE (0.17677669529663687f * 1.44269504088896f)

// ---------------- fp32 -> f16 convert (all weights, one launch) ----------------
__global__ __launch_bounds__(256) void cvtall_k(
    const float* __restrict__ wqkv, const float* __restrict__ wo,
    const float* __restrict__ w1, const float* __restrict__ w2,
    _Float16* __restrict__ hqkv, _Float16* __restrict__ ho,
    _Float16* __restrict__ h1, _Float16* __restrict__ h2)
{
    int i = blockIdx.x * 256 + threadIdx.x;
    const float* s; _Float16* t; int j = i;
    if (j < N4_QKV) { s = wqkv; t = hqkv; }
    else if ((j -= N4_QKV) < N4_WO) { s = wo; t = ho; }
    else if ((j -= N4_WO) < N4_W1) { s = w1; t = h1; }
    else if ((j -= N4_W1) < N4_W2) { s = w2; t = h2; }
    else return;
    float4 v = ((const float4*)s)[j];
    f16x4 h = {(_Float16)v.x, (_Float16)v.y, (_Float16)v.z, (_Float16)v.w};
    ((f16x4*)t)[j] = h;
}

// ---------------- Embed: Z[b*S+s][d] (+f16 copy, +t_all float) ----------------
__global__ __launch_bounds__(256) void embed_k(
    const float* __restrict__ ctx_x, const float* __restrict__ ctx_z,
    const float* __restrict__ qry_x,
    const float* __restrict__ W_ctx, const float* __restrict__ b_ctx,
    const float* __restrict__ W_qry, const float* __restrict__ b_qry,
    const int* __restrict__ t_ctx, const int* __restrict__ t_qry,
    float* __restrict__ Z, _Float16* __restrict__ Zh, float* __restrict__ tf)
{
    int row = blockIdx.x;            // 0..4095
    int d = threadIdx.x;             // 0..255
    int b = row >> 11, s = row & (S_LEN - 1);
    float acc;
    if (s < CTX) {
        const float* x1 = ctx_x + (size_t)(b * CTX + s) * LIN;
        const float* x2 = ctx_z + (size_t)(b * CTX + s) * HOUTD;
        const float* w = W_ctx + (size_t)d * (LIN + HOUTD);
        acc = b_ctx[d];
        #pragma unroll
        for (int i = 0; i < LIN; i++) acc += x1[i] * w[i];
        #pragma unroll
        for (int i = 0; i < HOUTD; i++) acc += x2[i] * w[LIN + i];
        if (d == 0) tf[row] = (float)t_ctx[b * CTX + s];
    } else {
        int qi = s - CTX;
        const float* x1 = qry_x + (size_t)(b * QQ + qi) * LIN;
        const float* w = W_qry + (size_t)d * (LIN + HOUTD);
        acc = b_qry[d];
        #pragma unroll
        for (int i = 0; i < LIN; i++) acc += x1[i] * w[i];
        if (d == 0) tf[row] = (float)t_qry[b * QQ + qi];
    }
    Z[(size_t)row * DD + d] = acc;
    Zh[(size_t)row * DD + d] = (_Float16)acc;
}

// ---------------- MFMA f16 GEMM 64x64 (dbuf LDS, pad-40, split-K capable) ----------------
// mode 0: fp32 out (Y0..Y3 per blockIdx.z; bias only on z==0)
// mode 1: relu -> f16 Yh   mode 2: f16 Q(prescaled),K:[B,NH,S,DH] V:[B,NH,DH,S]
__global__ __launch_bounds__(256) void hgemm_k(
    const _Float16* __restrict__ X, const _Float16* __restrict__ W,
    const float* __restrict__ bias, float* __restrict__ Y0,
    float* __restrict__ Y1, float* __restrict__ Y2, float* __restrict__ Y3,
    _Float16* __restrict__ Yh,
    int M, int N, int K, int lda, int mode,
    _Float16* __restrict__ Qh, _Float16* __restrict__ Kh, _Float16* __restrict__ Vh)
{
    __shared__ _Float16 Ah[2][64][40];
    __shared__ _Float16 Bh[2][64][40];
    const int tid = threadIdx.x;
    const int bm = blockIdx.x << 6, bn = blockIdx.y << 6;
    const int kbase = blockIdx.z * K;
    const int lr = tid >> 2;
    const int lk = (tid & 3) << 3;
    const int w = tid >> 6, lane = tid & 63;
    const int c = lane & 15, g = lane >> 4;
    const int wm = (w >> 1) << 5, wn = (w & 1) << 5;

    f32x4 acc00 = {0.f,0.f,0.f,0.f}, acc01 = {0.f,0.f,0.f,0.f};
    f32x4 acc10 = {0.f,0.f,0.f,0.f}, acc11 = {0.f,0.f,0.f,0.f};

    const _Float16* Xp = X + (size_t)(bm + lr) * lda + kbase + lk;
    const _Float16* Wp = W + (size_t)(bn + lr) * lda + kbase + lk;

    f16x8 xa = *(const f16x8*)Xp;
    f16x8 wb = *(const f16x8*)Wp;
    const int nt = K >> 5;
    int buf = 0;
    for (int t = 0; t < nt; t++) {
        *(f16x8*)&Ah[buf][lr][lk] = xa;
        *(f16x8*)&Bh[buf][lr][lk] = wb;
        __syncthreads();
        if (t + 1 < nt) {
            xa = *(const f16x8*)(Xp + ((size_t)(t + 1) << 5));
            wb = *(const f16x8*)(Wp + ((size_t)(t + 1) << 5));
        }
        f16x8 a0 = *(const f16x8*)&Ah[buf][wm + c][g << 3];
        f16x8 a1 = *(const f16x8*)&Ah[buf][wm + 16 + c][g << 3];
        f16x8 b0 = *(const f16x8*)&Bh[buf][wn + c][g << 3];
        f16x8 b1 = *(const f16x8*)&Bh[buf][wn + 16 + c][g << 3];
        acc00 = __builtin_amdgcn_mfma_f32_16x16x32_f16(a0, b0, acc00, 0, 0, 0);
        acc01 = __builtin_amdgcn_mfma_f32_16x16x32_f16(a0, b1, acc01, 0, 0, 0);
        acc10 = __builtin_amdgcn_mfma_f32_16x16x32_f16(a1, b0, acc10, 0, 0, 0);
        acc11 = __builtin_amdgcn_mfma_f32_16x16x32_f16(a1, b1, acc11, 0, 0, 0);
        buf ^= 1;
    }

    float* Yt = (blockIdx.z == 0) ? Y0 : (blockIdx.z == 1) ? Y1
              : (blockIdx.z == 2) ? Y2 : Y3;
    f32x4 accs[2][2] = {{acc00, acc01}, {acc10, acc11}};
    #pragma unroll
    for (int fm = 0; fm < 2; fm++) {
        #pragma unroll
        for (int fn = 0; fn < 2; fn++) {
            int colb = bn + wn + (fn << 4) + c;
            float bv = (blockIdx.z == 0) ? bias[colb] : 0.0f;
            if (mode == 2) {
                int which = colb >> 8, h = (colb >> 5) & 7, d = colb & 31;
                int row0 = bm + wm + (fm << 4) + (g << 2);
                int bb2 = row0 >> 11, ss0 = row0 & (S_LEN - 1);
                int bhi = (bb2 << 3) + h;
                if (which == 2) {
                    // V: 4 consecutive ss at fixed d -> one 8B store
                    f16x4 v4 = {(_Float16)(accs[fm][fn][0] + bv),
                                (_Float16)(accs[fm][fn][1] + bv),
                                (_Float16)(accs[fm][fn][2] + bv),
                                (_Float16)(accs[fm][fn][3] + bv)};
                    *(f16x4*)(Vh + ((size_t)bhi * DH + d) * S_LEN + ss0) = v4;
                } else {
                    #pragma unroll
                    for (int r = 0; r < 4; r++) {
                        float v = accs[fm][fn][r] + bv;
                        if (which == 0)
                            Qh[((size_t)bhi * S_LEN + ss0 + r) * DH + d] = (_Float16)(v * QSCALE);
                        else
                            Kh[((size_t)bhi * S_LEN + ss0 + r) * DH + d] = (_Float16)v;
                    }
                }
            } else {
                #pragma unroll
                for (int r = 0; r < 4; r++) {
                    int row = bm + wm + (fm << 4) + (g << 2) + r;
                    float v = accs[fm][fn][r] + bv;
                    if (mode == 0) {
                        Yt[(size_t)row * N + colb] = v;
                    } else {
                        Yh[(size_t)row * N + colb] = (_Float16)fmaxf(v, 0.0f);
                    }
                }
            }
        }
    }
}

// ---------------- fused Wo GEMM + residual + LayerNorm (BM=16, grid 256) ----------------
__global__ __launch_bounds__(256) void gemmln_k(
    const _Float16* __restrict__ X, const _Float16* __restrict__ W,
    const float* __restrict__ bias, float* __restrict__ Z,
    _Float16* __restrict__ Zh, const float* __restrict__ sw,
    const float* __restrict__ bw)
{
    __shared__ _Float16 Ast[2][16][40];
    __shared__ _Float16 Bst[2][256][40];
    __shared__ float lred[4][16][2];
    const int tid = threadIdx.x;
    const int bm = blockIdx.x << 4;
    const int w = tid >> 6, lane = tid & 63;
    const int c = lane & 15, g = lane >> 4;
    const int br = tid >> 2, bk = (tid & 3) << 3;

    f32x4 acc[4] = {};
    const _Float16* Wp = W + (size_t)br * DD + bk;
    f16x8 p0 = *(const f16x8*)Wp;
    f16x8 p1 = *(const f16x8*)(Wp + (size_t)64 * DD);
    f16x8 p2 = *(const f16x8*)(Wp + (size_t)128 * DD);
    f16x8 p3 = *(const f16x8*)(Wp + (size_t)192 * DD);
    f16x8 xa;
    if (tid < 64) xa = *(const f16x8*)(X + (size_t)(bm + br) * DD + bk);
    int buf = 0;
    #pragma unroll
    for (int t = 0; t < 8; t++) {
        if (tid < 64) *(f16x8*)&Ast[buf][br][bk] = xa;
        *(f16x8*)&Bst[buf][br][bk] = p0;
        *(f16x8*)&Bst[buf][br + 64][bk] = p1;
        *(f16x8*)&Bst[buf][br + 128][bk] = p2;
        *(f16x8*)&Bst[buf][br + 192][bk] = p3;
        __syncthreads();
        if (t < 7) {
            int o = (t + 1) << 5;
            if (tid < 64) xa = *(const f16x8*)(X + (size_t)(bm + br) * DD + o + bk);
            p0 = *(const f16x8*)(Wp + o);
            p1 = *(const f16x8*)(Wp + (size_t)64 * DD + o);
            p2 = *(const f16x8*)(Wp + (size_t)128 * DD + o);
            p3 = *(const f16x8*)(Wp + (size_t)192 * DD + o);
        }
        f16x8 a = *(const f16x8*)&Ast[buf][c][g << 3];
        #pragma unroll
        for (int f = 0; f < 4; f++) {
            f16x8 bfr = *(const f16x8*)&Bst[buf][(w << 6) + (f << 4) + c][g << 3];
            acc[f] = __builtin_amdgcn_mfma_f32_16x16x32_f16(a, bfr, acc[f], 0, 0, 0);
        }
        buf ^= 1;
    }

    float vals[4][4];
    float s1[4] = {0.f,0.f,0.f,0.f}, s2[4] = {0.f,0.f,0.f,0.f};
    #pragma unroll
    for (int f = 0; f < 4; f++) {
        int col = (w << 6) + (f << 4) + c;
        float bv = bias[col];
        #pragma unroll
        for (int r = 0; r < 4; r++) {
            int row = bm + (g << 2) + r;
            float v = acc[f][r] + bv + Z[(size_t)row * DD + col];
            vals[f][r] = v; s1[r] += v; s2[r] += v * v;
        }
    }
    #pragma unroll
    for (int off = 1; off < 16; off <<= 1) {
        #pragma unroll
        for (int r = 0; r < 4; r++) {
            s1[r] += __shfl_xor(s1[r], off, 64);
            s2[r] += __shfl_xor(s2[r], off, 64);
        }
    }
    if (c == 0) {
        #pragma unroll
        for (int r = 0; r < 4; r++) {
            lred[w][(g << 2) + r][0] = s1[r];
            lred[w][(g << 2) + r][1] = s2[r];
        }
    }
    __syncthreads();
    float mu_r[4], rs_r[4];
    #pragma unroll
    for (int r = 0; r < 4; r++) {
        int lr_ = (g << 2) + r;
        float S1 = lred[0][lr_][0] + lred[1][lr_][0] + lred[2][lr_][0] + lred[3][lr_][0];
        float S2 = lred[0][lr_][1] + lred[1][lr_][1] + lred[2][lr_][1] + lred[3][lr_][1];
        float mu = S1 * (1.0f / 256.0f);
        float var = S2 * (1.0f / 256.0f) - mu * mu;
        mu_r[r] = mu; rs_r[r] = rsqrtf(var + 1e-5f);
    }
    #pragma unroll
    for (int f = 0; f < 4; f++) {
        int col = (w << 6) + (f << 4) + c;
        float swv = sw[col], bwv = bw[col];
        #pragma unroll
        for (int r = 0; r < 4; r++) {
            int row = bm + (g << 2) + r;
            float o = (vals[f][r] - mu_r[r]) * rs_r[r] * swv + bwv;
            Z[(size_t)row * DD + col] = o;
            Zh[(size_t)row * DD + col] = (_Float16)o;
        }
    }
}

// ---------------- Residual + LN (Z + Y0..Y3), one WAVE per row ----------------
__global__ __launch_bounds__(256) void ln4_k(
    float* __restrict__ Z, const float* __restrict__ Y0,
    const float* __restrict__ Y1, const float* __restrict__ Y2,
    const float* __restrict__ Y3,
    const float* __restrict__ sw, const float* __restrict__ bw,
    _Float16* __restrict__ Zh)
{
    const int w = threadIdx.x >> 6, lane = threadIdx.x & 63;
    const int row = (blockIdx.x << 2) + w;
    float4 z = ((const float4*)(Z + (size_t)row * DD))[lane];
    float4 y0 = ((const float4*)(Y0 + (size_t)row * DD))[lane];
    float4 y1 = ((const float4*)(Y1 + (size_t)row * DD))[lane];
    float4 y2 = ((const float4*)(Y2 + (size_t)row * DD))[lane];
    float4 y3 = ((const float4*)(Y3 + (size_t)row * DD))[lane];
    float x0 = z.x + (y0.x + y1.x) + (y2.x + y3.x);
    float x1 = z.y + (y0.y + y1.y) + (y2.y + y3.y);
    float x2 = z.z + (y0.z + y1.z) + (y2.z + y3.z);
    float x3 = z.w + (y0.w + y1.w) + (y2.w + y3.w);
    float s1 = (x0 + x1) + (x2 + x3);
    float s2 = (x0 * x0 + x1 * x1) + (x2 * x2 + x3 * x3);
    #pragma unroll
    for (int off = 1; off < 64; off <<= 1) {
        s1 += __shfl_xor(s1, off, 64);
        s2 += __shfl_xor(s2, off, 64);
    }
    float mu = s1 * (1.0f / 256.0f);
    float var = s2 * (1.0f / 256.0f) - mu * mu;
    float rs = rsqrtf(var + 1e-5f);
    float4 sv = ((const float4*)sw)[lane];
    float4 bv = ((const float4*)bw)[lane];
    float o0 = (x0 - mu) * rs * sv.x + bv.x;
    float o1 = (x1 - mu) * rs * sv.y + bv.y;
    float o2 = (x2 - mu) * rs * sv.z + bv.z;
    float o3 = (x3 - mu) * rs * sv.w + bv.w;
    ((float4*)(Z + (size_t)row * DD))[lane] = make_float4(o0, o1, o2, o3);
    f16x4 oh = {(_Float16)o0, (_Float16)o1, (_Float16)o2, (_Float16)o3};
    ((f16x4*)(Zh + (size_t)row * DD))[lane] = oh;
}

// ---------------- Final layer: LN (query rows) + output head, fused ----------------
// One wave per query row; head dot-products via butterfly reduce; writes out only.
__global__ __launch_bounds__(256) void ln4qo_k(
    const float* __restrict__ Z, const float* __restrict__ Y0,
    const float* __restrict__ Y1, const float* __restrict__ Y2,
    const float* __restrict__ Y3,
    const float* __restrict__ sw, const float* __restrict__ bw,
    const float* __restrict__ Wout, const float* __restrict__ bout,
    float* __restrict__ out)
{
    const int w = threadIdx.x >> 6, lane = threadIdx.x & 63;
    const int qrow = (blockIdx.x << 2) + w;           // 0..1023
    const int b = qrow >> 9;
    const int row = b * S_LEN + CTX + (qrow & (QQ - 1));
    float4 z = ((const float4*)(Z + (size_t)row * DD))[lane];
    float4 y0 = ((const float4*)(Y0 + (size_t)row * DD))[lane];
    float4 y1 = ((const float4*)(Y1 + (size_t)row * DD))[lane];
    float4 y2 = ((const float4*)(Y2 + (size_t)row * DD))[lane];
    float4 y3 = ((const float4*)(Y3 + (size_t)row * DD))[lane];
    float x0 = z.x + (y0.x + y1.x) + (y2.x + y3.x);
    float x1 = z.y + (y0.y + y1.y) + (y2.y + y3.y);
    float x2 = z.z + (y0.z + y1.z) + (y2.z + y3.z);
    float x3 = z.w + (y0.w + y1.w) + (y2.w + y3.w);
    float s1 = (x0 + x1) + (x2 + x3);
    float s2 = (x0 * x0 + x1 * x1) + (x2 * x2 + x3 * x3);
    #pragma unroll
    for (int off = 1; off < 64; off <<= 1) {
        s1 += __shfl_xor(s1, off, 64);
        s2 += __shfl_xor(s2, off, 64);
    }
    float mu = s1 * (1.0f / 256.0f);
    float var = s2 * (1.0f / 256.0f) - mu * mu;
    float rs = rsqrtf(var + 1e-5f);
    float4 sv = ((const float4*)sw)[lane];
    float4 bv = ((const float4*)bw)[lane];
    float o0 = (x0 - mu) * rs * sv.x + bv.x;
    float o1 = (x1 - mu) * rs * sv.y + bv.y;
    float o2 = (x2 - mu) * rs * sv.z + bv.z;
    float o3 = (x3 - mu) * rs * sv.w + bv.w;
    // head: out[qrow][ho] = dot(o_row, Wout[ho]) + bout[ho]
    #pragma unroll
    for (int ho = 0; ho < HOUTD; ho++) {
        float4 wv = ((const float4*)(Wout + (size_t)ho * DD))[lane];
        float s = (o0 * wv.x + o1 * wv.y) + (o2 * wv.z + o3 * wv.w);
        #pragma unroll
        for (int off = 1; off < 64; off <<= 1) s += __shfl_xor(s, off, 64);
        if (lane == ho) out[(size_t)qrow * HOUTD + ho] = s + bout[ho];
    }
}

// ---------------- MFMA flash attention ----------------
// 1024 thr = 16 waves = 2 key-split wg x 8 query tiles (128 q/block).
// 128-key tiles, dbuf; t and alpha-scaled t staged in LDS; scores in shifted
// log2 domain (Q pre-scaled by QSCALE, per-query shift cancels in softmax).
__global__ __launch_bounds__(1024, 4) void attn_k(
    const _Float16* __restrict__ Qf, const _Float16* __restrict__ Kf,
    const _Float16* __restrict__ Vf, const float* __restrict__ tf_all,
    const float* __restrict__ alpha, _Float16* __restrict__ O)
{
    const int bh = blockIdx.x >> 4;           // /(S/128)=16
    const int itile = blockIdx.x & 15;
    const int b = bh >> 3, h = bh & 7;
    const int tid = threadIdx.x;
    const int w16 = tid >> 6;                 // 0..15
    const int wg = w16 >> 3;                  // key-split 0/1
    const int wq = w16 & 7;                   // query tile 0..7
    const int ltid = tid & 511;               // within wave-group
    const int lane = tid & 63;
    const int c = lane & 15, g = lane >> 4;
    const int i0 = (itile << 7) + (wq << 4);
    const int jbase = wg * KHALF;

    // K: 40960  V: 34816 (=75776)  tbl: 8192 (=83968)  ptl: 8192 -> 92160
    // merge aliases sacc(36864)+sml(2048) over [0, 38912)
    __shared__ __align__(16) char smem[92160];
    _Float16 (*Kl)[2][128][40] = (_Float16(*)[2][128][40])smem;
    _Float16 (*Vl)[2][32][136] = (_Float16(*)[2][32][136])(smem + 40960);
    float* tbl = (float*)(smem + 75776);
    float* ptl = (float*)(smem + 83968);
    float (*sacc)[16][36] = (float(*)[16][36])smem;
    float (*sml)[2][16] = (float(*)[2][16])(smem + 36864);

    const float LOG2E = 1.44269504088896f;
    const float ah2 = alpha[h] * LOG2E;

    const _Float16* Qbh = Qf + (size_t)bh * S_LEN * DH;
    const _Float16* Kbh = Kf + (size_t)bh * S_LEN * DH;
    const _Float16* Vbh = Vf + (size_t)bh * DH * S_LEN;
    const float* tb = tf_all + b * S_LEN;

    f16x8 qfrag = *(const f16x8*)(Qbh + (size_t)(i0 + c) * DH + (g << 3));
    const float ti = tb[i0 + c];

    const int kr = ltid >> 2, kc = (ltid & 3) << 3;     // K: 128 x 32
    const int vr = ltid >> 4, vc = (ltid & 15) << 3;    // V: 32 x 128

    // stage t (compare) and ah2*t (bias) once
    {
        float t0 = tb[tid], t1 = tb[tid + 1024];
        tbl[tid] = t0; tbl[tid + 1024] = t1;
        ptl[tid] = ah2 * t0; ptl[tid + 1024] = ah2 * t1;
    }

    float m2 = -3.0e38f, l = 0.0f;
    f32x4 acc0 = {0.f, 0.f, 0.f, 0.f};
    f32x4 acc1 = {0.f, 0.f, 0.f, 0.f};
    const f32x4 zero = {0.f, 0.f, 0.f, 0.f};

    f16x8 kpre = *(const f16x8*)(Kbh + (size_t)(jbase + kr) * DH + kc);
    f16x8 vpre = *(const f16x8*)(Vbh + (size_t)vr * S_LEN + jbase + vc);
    int buf = 0;

    for (int kt = 0; kt < KHALF; kt += 128) {
        *(f16x8*)&Kl[wg][buf][kr][kc] = kpre;
        *(f16x8*)&Vl[wg][buf][vr][vc] = vpre;
        __syncthreads();
        if (kt + 128 < KHALF) {
            kpre = *(const f16x8*)(Kbh + (size_t)(jbase + kt + 128 + kr) * DH + kc);
            vpre = *(const f16x8*)(Vbh + (size_t)vr * S_LEN + jbase + kt + 128 + vc);
        }
        #pragma unroll
        for (int jj = 0; jj < 128; jj += 32) {
            const int j0 = jbase + kt + jj;
            f16x8 kf0 = *(const f16x8*)&Kl[wg][buf][jj + c][g << 3];
            f16x8 kf1 = *(const f16x8*)&Kl[wg][buf][jj + 16 + c][g << 3];
            __builtin_amdgcn_s_setprio(1);
            f32x4 dA = __builtin_amdgcn_mfma_f32_16x16x32_f16(kf0, qfrag, zero, 0, 0, 0);
            f32x4 dB = __builtin_amdgcn_mfma_f32_16x16x32_f16(kf1, qfrag, zero, 0, 0, 0);
            __builtin_amdgcn_s_setprio(0);
            float4 tjA = *(const float4*)&tbl[j0 + (g << 2)];
            float4 tjB = *(const float4*)&tbl[j0 + 16 + (g << 2)];
            float4 ptA = *(const float4*)&ptl[j0 + (g << 2)];
            float4 ptB = *(const float4*)&ptl[j0 + 16 + (g << 2)];
            // shifted score: s' = d + ah2*tj   (true s = s' - ah2*ti, shift
            // cancels in softmax). mask on raw t.
            float sA0 = (tjA.x <= ti) ? dA[0] + ptA.x : -1e9f;
            float sA1 = (tjA.y <= ti) ? dA[1] + ptA.y : -1e9f;
            float sA2 = (tjA.z <= ti) ? dA[2] + ptA.z : -1e9f;
            float sA3 = (tjA.w <= ti) ? dA[3] + ptA.w : -1e9f;
            float sB0 = (tjB.x <= ti) ? dB[0] + ptB.x : -1e9f;
            float sB1 = (tjB.y <= ti) ? dB[1] + ptB.y : -1e9f;
            float sB2 = (tjB.z <= ti) ? dB[2] + ptB.z : -1e9f;
            float sB3 = (tjB.w <= ti) ? dB[3] + ptB.w : -1e9f;
            float pmaxl = fmaxf(fmaxf(fmaxf(sA0, sA1), fmaxf(sA2, sA3)),
                                fmaxf(fmaxf(sB0, sB1), fmaxf(sB2, sB3)));
            if (__any(pmaxl > m2 + 8.0f)) {
                float pm = fmaxf(pmaxl, __shfl_xor(pmaxl, 16, 64));
                pm = fmaxf(pm, __shfl_xor(pm, 32, 64));
                float mnew = fmaxf(m2, pm);
                float fsc = __builtin_amdgcn_exp2f(m2 - mnew);
                m2 = mnew;
                l *= fsc; acc0 *= fsc; acc1 *= fsc;
            }
            float pA0 = __builtin_amdgcn_exp2f(sA0 - m2);
            float pA1 = __builtin_amdgcn_exp2f(sA1 - m2);
            float pA2 = __builtin_amdgcn_exp2f(sA2 - m2);
            float pA3 = __builtin_amdgcn_exp2f(sA3 - m2);
            float pB0 = __builtin_amdgcn_exp2f(sB0 - m2);
            float pB1 = __builtin_amdgcn_exp2f(sB1 - m2);
            float pB2 = __builtin_amdgcn_exp2f(sB2 - m2);
            float pB3 = __builtin_amdgcn_exp2f(sB3 - m2);
            l += ((pA0 + pA1) + (pA2 + pA3)) + ((pB0 + pB1) + (pB2 + pB3));
            f16x4 pfA = {(_Float16)pA0, (_Float16)pA1, (_Float16)pA2, (_Float16)pA3};
            f16x4 pfB = {(_Float16)pB0, (_Float16)pB1, (_Float16)pB2, (_Float16)pB3};
            f16x4 vA0 = *(const f16x4*)&Vl[wg][buf][c][jj + (g << 2)];
            f16x4 vA1 = *(const f16x4*)&Vl[wg][buf][16 + c][jj + (g << 2)];
            f16x4 vB0 = *(const f16x4*)&Vl[wg][buf][c][jj + 16 + (g << 2)];
            f16x4 vB1 = *(const f16x4*)&Vl[wg][buf][16 + c][jj + 16 + (g << 2)];
            __builtin_amdgcn_s_setprio(1);
            acc0 = __builtin_amdgcn_mfma_f32_16x16x16f16(vA0, pfA, acc0, 0, 0, 0);
            acc0 = __builtin_amdgcn_mfma_f32_16x16x16f16(vB0, pfB, acc0, 0, 0, 0);
            acc1 = __builtin_amdgcn_mfma_f32_16x16x16f16(vA1, pfA, acc1, 0, 0, 0);
            acc1 = __builtin_amdgcn_mfma_f32_16x16x16f16(vB1, pfB, acc1, 0, 0, 0);
            __builtin_amdgcn_s_setprio(0);
        }
        buf ^= 1;
    }

    l += __shfl_xor(l, 16, 64);
    l += __shfl_xor(l, 32, 64);

    // all waves done reading K/V/t LDS -> safe to alias as merge scratch
    __syncthreads();
    *(f32x4*)&sacc[w16][c][g << 2] = acc0;
    *(f32x4*)&sacc[w16][c][16 + (g << 2)] = acc1;
    if (g == 0) { sml[w16][0][c] = m2; sml[w16][1][c] = l; }
    __syncthreads();

    {
        const int qt = tid >> 7;
        const int q = (tid >> 3) & 15;
        const int dh0 = (tid & 7) << 2;
        float m0 = sml[qt][0][q], m1 = sml[qt + 8][0][q];
        float M = fmaxf(m0, m1);
        float f0 = __builtin_amdgcn_exp2f(m0 - M);
        float f1 = __builtin_amdgcn_exp2f(m1 - M);
        float L = sml[qt][1][q] * f0 + sml[qt + 8][1][q] * f1;
        float a0 = sacc[qt][q][dh0 + 0] * f0 + sacc[qt + 8][q][dh0 + 0] * f1;
        float a1 = sacc[qt][q][dh0 + 1] * f0 + sacc[qt + 8][q][dh0 + 1] * f1;
        float a2 = sacc[qt][q][dh0 + 2] * f0 + sacc[qt + 8][q][dh0 + 2] * f1;
        float a3 = sacc[qt][q][dh0 + 3] * f0 + sacc[qt + 8][q][dh0 + 3] * f1;
        if (M < -4.9e8f) {
            // fully-masked row: reference = uniform softmax over ALL 2048 keys.
            float vs0 = 0.f, vs1 = 0.f, vs2 = 0.f, vs3 = 0.f;
            const _Float16* vp = Vbh + (size_t)dh0 * S_LEN + CTX;
            for (int j = 0; j < QQ; j += 8) {
                f16x8 x0 = *(const f16x8*)(vp + j);
                f16x8 x1 = *(const f16x8*)(vp + S_LEN + j);
                f16x8 x2 = *(const f16x8*)(vp + 2 * S_LEN + j);
                f16x8 x3 = *(const f16x8*)(vp + 3 * S_LEN + j);
                #pragma unroll
                for (int e = 0; e < 8; e++) {
                    vs0 += (float)x0[e]; vs1 += (float)x1[e];
                    vs2 += (float)x2[e]; vs3 += (float)x3[e];
                }
            }
            a0 += vs0; a1 += vs1; a2 += vs2; a3 += vs3;
            L += (float)QQ;
        }
        float inv = 1.0f / L;
        int row = b * S_LEN + (itile << 7) + (qt << 4) + q;
        f16x4 o = {(_Float16)(a0 * inv), (_Float16)(a1 * inv),
                   (_Float16)(a2 * inv), (_Float16)(a3 * inv)};
        *(f16x4*)(O + (size_t)row * DD + h * DH + dh0) = o;
    }
}

extern "C" void kernel_launch(void* const* d_in, const int* in_sizes, int n_in,
                              void* d_out, int out_size, void* d_ws, size_t ws_size,
                              hipStream_t stream) {
    (void)in_sizes; (void)n_in; (void)out_size; (void)ws_size;
    const float* ctx_x = (const float*)d_in[0];
    const float* ctx_z = (const float*)d_in[1];
    const float* qry_x = (const float*)d_in[2];
    const int* t_ctx = (const int*)d_in[3];
    const int* t_qry = (const int*)d_in[4];
    const float* W_ctx = (const float*)d_in[5];
    const float* b_ctx = (const float*)d_in[6];
    const float* W_qry = (const float*)d_in[7];
    const float* b_qry = (const float*)d_in[8];
    const float* alpha = (const float*)d_in[9];
    const float* Wqkv = (const float*)d_in[10];
    const float* bqkv = (const float*)d_in[11];
    const float* Wo = (const float*)d_in[12];
    const float* bo = (const float*)d_in[13];
    const float* ln1_s = (const float*)d_in[14];
    const float* ln1_b = (const float*)d_in[15];
    const float* W1 = (const float*)d_in[16];
    const float* b1 = (const float*)d_in[17];
    const float* W2 = (const float*)d_in[18];
    const float* b2 = (const float*)d_in[19];
    const float* ln2_s = (const float*)d_in[20];
    const float* ln2_b = (const float*)d_in[21];
    const float* W_out = (const float*)d_in[22];
    const float* b_out = (const float*)d_in[23];

    float* ws = (float*)d_ws;
    const size_t MTOT = (size_t)BB * S_LEN;       // 4096
    const size_t ZSZ = MTOT * DD;                 // 1M floats
    float* Z   = ws;                              // [0, 1M) f32
    float* Yb  = ws + ZSZ;                        // [1M, 2M) f32
    _Float16* Zh   = (_Float16*)(ws + 2 * ZSZ);          // 1M halfs
    _Float16* AYh  = (_Float16*)(ws + 2 * ZSZ + ZSZ / 2);
    _Float16* FF1h = (_Float16*)(ws + 3 * ZSZ);          // 4M halfs -> [3M,5M)
    _Float16* Qh   = (_Float16*)(ws + 5 * ZSZ);
    _Float16* Kh   = (_Float16*)(ws + 5 * ZSZ + ZSZ / 2);
    _Float16* Vh   = (_Float16*)(ws + 6 * ZSZ);
    float* tf_all  = ws + 6 * ZSZ + ZSZ / 2;             // 4096 floats
    _Float16* Whqkv = (_Float16*)(ws + 6 * ZSZ + ZSZ / 2 + 4096);
    _Float16* Who   = Whqkv + (size_t)NL * 3 * DD * DD;
    _Float16* Wh1   = Who   + (size_t)NL * DD * DD;
    _Float16* Wh2   = Wh1   + (size_t)NL * DFF * DD;
    float* Yb1 = ws + 9 * ZSZ;
    float* Yb2 = ws + 10 * ZSZ;
    float* Yb3 = ws + 11 * ZSZ;

    {
        int n4tot = N4_QKV + N4_WO + N4_W1 + N4_W2;
        cvtall_k<<<(n4tot + 255) / 256, 256, 0, stream>>>(
            Wqkv, Wo, W1, W2, Whqkv, Who, Wh1, Wh2);
    }

    embed_k<<<MTOT, 256, 0, stream>>>(ctx_x, ctx_z, qry_x, W_ctx, b_ctx, W_qry, b_qry,
                                      t_ctx, t_qry, Z, Zh, tf_all);

    for (int l = 0; l < NL; l++) {
        hgemm_k<<<dim3(MTOT / 64, (3 * DD) / 64, 1), 256, 0, stream>>>(
            Zh, Whqkv + (size_t)l * 3 * DD * DD, bqkv + (size_t)l * 3 * DD,
            nullptr, nullptr, nullptr, nullptr, nullptr,
            (int)MTOT, 3 * DD, DD, DD, 2, Qh, Kh, Vh);
        attn_k<<<BB * NH * (S_LEN / 128), 1024, 0, stream>>>(
            Qh, Kh, Vh, tf_all, alpha, AYh);
        gemmln_k<<<MTOT / 16, 256, 0, stream>>>(
            AYh, Who + (size_t)l * DD * DD, bo + (size_t)l * DD,
            Z, Zh, ln1_s + (size_t)l * DD, ln1_b + (size_t)l * DD);
        hgemm_k<<<dim3(MTOT / 64, DFF / 64, 1), 256, 0, stream>>>(
            Zh, Wh1 + (size_t)l * DFF * DD, b1 + (size_t)l * DFF,
            nullptr, nullptr, nullptr, nullptr, FF1h,
            (int)MTOT, DFF, DD, DD, 1, nullptr, nullptr, nullptr);
        hgemm_k<<<dim3(MTOT / 64, DD / 64, 4), 256, 0, stream>>>(
            FF1h, Wh2 + (size_t)l * DD * DFF, b2 + (size_t)l * DD,
            Yb, Yb1, Yb2, Yb3, nullptr,
            (int)MTOT, DD, DFF / 4, DFF, 0, nullptr, nullptr, nullptr);
        if (l < NL - 1) {
            ln4_k<<<MTOT / 4, 256, 0, stream>>>(
                Z, Yb, Yb1, Yb2, Yb3,
                ln2_s + (size_t)l * DD, ln2_b + (size_t)l * DD, Zh);
        } else {
            ln4qo_k<<<(BB * QQ) / 4, 256, 0, stream>>>(
                Z, Yb, Yb1, Yb2, Yb3,
                ln2_s + (size_t)l * DD, ln2_b + (size_t)l * DD,
                W_out, b_out, (float*)d_out);
        }
    }
}

// Round 20
// 360.784 us; speedup vs baseline: 1.3780x; 1.0214x over previous
//
#include <hip/hip_runtime.h>
#include <hip/hip_bf16.h>
#include <cstddef>

#define BB   2
#define CTX  1536
#define QQ   512
#define S_LEN 2048
#define DD   256
#define NH   8
#define DH   32
#define DFF  1024
#define NL   6
#define LIN  20
#define HOUTD 10
#define KHALF (CTX / 2)      // 768 keys per wave-group

typedef _Float16 f16x2 __attribute__((ext_vector_type(2)));
typedef _Float16 f16x4 __attribute__((ext_vector_type(4)));
typedef _Float16 f16x8 __attribute__((ext_vector_type(8)));
typedef float f32x4 __attribute__((ext_vector_type(4)));

#define N4_QKV (NL * 3 * DD * DD / 4)
#define N4_WO  (NL * DD * DD / 4)
#define N4_W1  (NL * DFF * DD / 4)
#define N4_W2  (NL * DD * DFF / 4)

// Q pre-scale: (1/sqrt(32)) * log2(e), folded into the qkv epilogue.
#define QSCALE (0.17677669529663687f * 1.44269504088896f)

// query-row remap: compact qrow (0..1023) -> global row (b*S + CTX + qi)
__device__ __forceinline__ int qremap(int r) {
    return (r >> 9) * S_LEN + CTX + (r & (QQ - 1));
}

// ---------------- fp32 -> f16 convert (all weights, one launch) ----------------
__global__ __launch_bounds__(256) void cvtall_k(
    const float* __restrict__ wqkv, const float* __restrict__ wo,
    const float* __restrict__ w1, const float* __restrict__ w2,
    _Float16* __restrict__ hqkv, _Float16* __restrict__ ho,
    _Float16* __restrict__ h1, _Float16* __restrict__ h2)
{
    int i = blockIdx.x * 256 + threadIdx.x;
    const float* s; _Float16* t; int j = i;
    if (j < N4_QKV) { s = wqkv; t = hqkv; }
    else if ((j -= N4_QKV) < N4_WO) { s = wo; t = ho; }
    else if ((j -= N4_WO) < N4_W1) { s = w1; t = h1; }
    else if ((j -= N4_W1) < N4_W2) { s = w2; t = h2; }
    else return;
    float4 v = ((const float4*)s)[j];
    f16x4 h = {(_Float16)v.x, (_Float16)v.y, (_Float16)v.z, (_Float16)v.w};
    ((f16x4*)t)[j] = h;
}

// ---------------- Embed: Z[b*S+s][d] (+f16 copy, +t_all float) ----------------
__global__ __launch_bounds__(256) void embed_k(
    const float* __restrict__ ctx_x, const float* __restrict__ ctx_z,
    const float* __restrict__ qry_x,
    const float* __restrict__ W_ctx, const float* __restrict__ b_ctx,
    const float* __restrict__ W_qry, const float* __restrict__ b_qry,
    const int* __restrict__ t_ctx, const int* __restrict__ t_qry,
    float* __restrict__ Z, _Float16* __restrict__ Zh, float* __restrict__ tf)
{
    int row = blockIdx.x;            // 0..4095
    int d = threadIdx.x;             // 0..255
    int b = row >> 11, s = row & (S_LEN - 1);
    float acc;
    if (s < CTX) {
        const float* x1 = ctx_x + (size_t)(b * CTX + s) * LIN;
        const float* x2 = ctx_z + (size_t)(b * CTX + s) * HOUTD;
        const float* w = W_ctx + (size_t)d * (LIN + HOUTD);
        acc = b_ctx[d];
        #pragma unroll
        for (int i = 0; i < LIN; i++) acc += x1[i] * w[i];
        #pragma unroll
        for (int i = 0; i < HOUTD; i++) acc += x2[i] * w[LIN + i];
        if (d == 0) tf[row] = (float)t_ctx[b * CTX + s];
    } else {
        int qi = s - CTX;
        const float* x1 = qry_x + (size_t)(b * QQ + qi) * LIN;
        const float* w = W_qry + (size_t)d * (LIN + HOUTD);
        acc = b_qry[d];
        #pragma unroll
        for (int i = 0; i < LIN; i++) acc += x1[i] * w[i];
        if (d == 0) tf[row] = (float)t_qry[b * QQ + qi];
    }
    Z[(size_t)row * DD + d] = acc;
    Zh[(size_t)row * DD + d] = (_Float16)acc;
}

// ---------------- MFMA f16 GEMM 64x64 (dbuf LDS, pad-40, split-K capable) ----------------
// mode 0: fp32 out (Y0..Y3 per blockIdx.z; bias only on z==0)
// mode 1: relu -> f16 Yh   mode 2: f16 Q(prescaled),K:[B,NH,S,DH] V:[B,NH,DH,S]
// xmap: remap X row reads through qremap (final-layer query-only GEMMs).
__global__ __launch_bounds__(256) void hgemm_k(
    const _Float16* __restrict__ X, const _Float16* __restrict__ W,
    const float* __restrict__ bias, float* __restrict__ Y0,
    float* __restrict__ Y1, float* __restrict__ Y2, float* __restrict__ Y3,
    _Float16* __restrict__ Yh,
    int M, int N, int K, int lda, int mode, int xmap,
    _Float16* __restrict__ Qh, _Float16* __restrict__ Kh, _Float16* __restrict__ Vh)
{
    __shared__ _Float16 Ah[2][64][40];
    __shared__ _Float16 Bh[2][64][40];
    const int tid = threadIdx.x;
    const int bm = blockIdx.x << 6, bn = blockIdx.y << 6;
    const int kbase = blockIdx.z * K;
    const int lr = tid >> 2;
    const int lk = (tid & 3) << 3;
    const int w = tid >> 6, lane = tid & 63;
    const int c = lane & 15, g = lane >> 4;
    const int wm = (w >> 1) << 5, wn = (w & 1) << 5;

    f32x4 acc00 = {0.f,0.f,0.f,0.f}, acc01 = {0.f,0.f,0.f,0.f};
    f32x4 acc10 = {0.f,0.f,0.f,0.f}, acc11 = {0.f,0.f,0.f,0.f};

    int xr = bm + lr;
    if (xmap) xr = qremap(xr);
    const _Float16* Xp = X + (size_t)xr * lda + kbase + lk;
    const _Float16* Wp = W + (size_t)(bn + lr) * lda + kbase + lk;

    f16x8 xa = *(const f16x8*)Xp;
    f16x8 wb = *(const f16x8*)Wp;
    const int nt = K >> 5;
    int buf = 0;
    for (int t = 0; t < nt; t++) {
        *(f16x8*)&Ah[buf][lr][lk] = xa;
        *(f16x8*)&Bh[buf][lr][lk] = wb;
        __syncthreads();
        if (t + 1 < nt) {
            xa = *(const f16x8*)(Xp + ((size_t)(t + 1) << 5));
            wb = *(const f16x8*)(Wp + ((size_t)(t + 1) << 5));
        }
        f16x8 a0 = *(const f16x8*)&Ah[buf][wm + c][g << 3];
        f16x8 a1 = *(const f16x8*)&Ah[buf][wm + 16 + c][g << 3];
        f16x8 b0 = *(const f16x8*)&Bh[buf][wn + c][g << 3];
        f16x8 b1 = *(const f16x8*)&Bh[buf][wn + 16 + c][g << 3];
        acc00 = __builtin_amdgcn_mfma_f32_16x16x32_f16(a0, b0, acc00, 0, 0, 0);
        acc01 = __builtin_amdgcn_mfma_f32_16x16x32_f16(a0, b1, acc01, 0, 0, 0);
        acc10 = __builtin_amdgcn_mfma_f32_16x16x32_f16(a1, b0, acc10, 0, 0, 0);
        acc11 = __builtin_amdgcn_mfma_f32_16x16x32_f16(a1, b1, acc11, 0, 0, 0);
        buf ^= 1;
    }

    float* Yt = (blockIdx.z == 0) ? Y0 : (blockIdx.z == 1) ? Y1
              : (blockIdx.z == 2) ? Y2 : Y3;
    f32x4 accs[2][2] = {{acc00, acc01}, {acc10, acc11}};
    #pragma unroll
    for (int fm = 0; fm < 2; fm++) {
        #pragma unroll
        for (int fn = 0; fn < 2; fn++) {
            int colb = bn + wn + (fn << 4) + c;
            float bv = (blockIdx.z == 0) ? bias[colb] : 0.0f;
            if (mode == 2) {
                int which = colb >> 8, h = (colb >> 5) & 7, d = colb & 31;
                int row0 = bm + wm + (fm << 4) + (g << 2);
                int bb2 = row0 >> 11, ss0 = row0 & (S_LEN - 1);
                int bhi = (bb2 << 3) + h;
                if (which == 2) {
                    // V: 4 consecutive ss at fixed d -> one 8B store
                    f16x4 v4 = {(_Float16)(accs[fm][fn][0] + bv),
                                (_Float16)(accs[fm][fn][1] + bv),
                                (_Float16)(accs[fm][fn][2] + bv),
                                (_Float16)(accs[fm][fn][3] + bv)};
                    *(f16x4*)(Vh + ((size_t)bhi * DH + d) * S_LEN + ss0) = v4;
                } else {
                    #pragma unroll
                    for (int r = 0; r < 4; r++) {
                        float v = accs[fm][fn][r] + bv;
                        if (which == 0)
                            Qh[((size_t)bhi * S_LEN + ss0 + r) * DH + d] = (_Float16)(v * QSCALE);
                        else
                            Kh[((size_t)bhi * S_LEN + ss0 + r) * DH + d] = (_Float16)v;
                    }
                }
            } else {
                #pragma unroll
                for (int r = 0; r < 4; r++) {
                    int row = bm + wm + (fm << 4) + (g << 2) + r;
                    float v = accs[fm][fn][r] + bv;
                    if (mode == 0) {
                        Yt[(size_t)row * N + colb] = v;
                    } else {
                        Yh[(size_t)row * N + colb] = (_Float16)fmaxf(v, 0.0f);
                    }
                }
            }
        }
    }
}

// ---------------- fused Wo GEMM + residual + LayerNorm (BM=16) ----------------
// qmap: all row indices (X reads, Z read/write, Zh write) remapped to query rows.
__global__ __launch_bounds__(256) void gemmln_k(
    const _Float16* __restrict__ X, const _Float16* __restrict__ W,
    const float* __restrict__ bias, float* __restrict__ Z,
    _Float16* __restrict__ Zh, const float* __restrict__ sw,
    const float* __restrict__ bw, int qmap)
{
    __shared__ _Float16 Ast[2][16][40];
    __shared__ _Float16 Bst[2][256][40];
    __shared__ float lred[4][16][2];
    const int tid = threadIdx.x;
    const int bm = blockIdx.x << 4;
    const int w = tid >> 6, lane = tid & 63;
    const int c = lane & 15, g = lane >> 4;
    const int br = tid >> 2, bk = (tid & 3) << 3;

    f32x4 acc[4] = {};
    const _Float16* Wp = W + (size_t)br * DD + bk;
    f16x8 p0 = *(const f16x8*)Wp;
    f16x8 p1 = *(const f16x8*)(Wp + (size_t)64 * DD);
    f16x8 p2 = *(const f16x8*)(Wp + (size_t)128 * DD);
    f16x8 p3 = *(const f16x8*)(Wp + (size_t)192 * DD);
    f16x8 xa;
    int arow = bm + br;
    if (qmap) arow = qremap(arow);
    if (tid < 64) xa = *(const f16x8*)(X + (size_t)arow * DD + bk);
    int buf = 0;
    #pragma unroll
    for (int t = 0; t < 8; t++) {
        if (tid < 64) *(f16x8*)&Ast[buf][br][bk] = xa;
        *(f16x8*)&Bst[buf][br][bk] = p0;
        *(f16x8*)&Bst[buf][br + 64][bk] = p1;
        *(f16x8*)&Bst[buf][br + 128][bk] = p2;
        *(f16x8*)&Bst[buf][br + 192][bk] = p3;
        __syncthreads();
        if (t < 7) {
            int o = (t + 1) << 5;
            if (tid < 64) xa = *(const f16x8*)(X + (size_t)arow * DD + o + bk);
            p0 = *(const f16x8*)(Wp + o);
            p1 = *(const f16x8*)(Wp + (size_t)64 * DD + o);
            p2 = *(const f16x8*)(Wp + (size_t)128 * DD + o);
            p3 = *(const f16x8*)(Wp + (size_t)192 * DD + o);
        }
        f16x8 a = *(const f16x8*)&Ast[buf][c][g << 3];
        #pragma unroll
        for (int f = 0; f < 4; f++) {
            f16x8 bfr = *(const f16x8*)&Bst[buf][(w << 6) + (f << 4) + c][g << 3];
            acc[f] = __builtin_amdgcn_mfma_f32_16x16x32_f16(a, bfr, acc[f], 0, 0, 0);
        }
        buf ^= 1;
    }

    float vals[4][4];
    float s1[4] = {0.f,0.f,0.f,0.f}, s2[4] = {0.f,0.f,0.f,0.f};
    int rows[4];
    #pragma unroll
    for (int r = 0; r < 4; r++) {
        int row = bm + (g << 2) + r;
        rows[r] = qmap ? qremap(row) : row;
    }
    #pragma unroll
    for (int f = 0; f < 4; f++) {
        int col = (w << 6) + (f << 4) + c;
        float bv = bias[col];
        #pragma unroll
        for (int r = 0; r < 4; r++) {
            float v = acc[f][r] + bv + Z[(size_t)rows[r] * DD + col];
            vals[f][r] = v; s1[r] += v; s2[r] += v * v;
        }
    }
    #pragma unroll
    for (int off = 1; off < 16; off <<= 1) {
        #pragma unroll
        for (int r = 0; r < 4; r++) {
            s1[r] += __shfl_xor(s1[r], off, 64);
            s2[r] += __shfl_xor(s2[r], off, 64);
        }
    }
    if (c == 0) {
        #pragma unroll
        for (int r = 0; r < 4; r++) {
            lred[w][(g << 2) + r][0] = s1[r];
            lred[w][(g << 2) + r][1] = s2[r];
        }
    }
    __syncthreads();
    float mu_r[4], rs_r[4];
    #pragma unroll
    for (int r = 0; r < 4; r++) {
        int lr_ = (g << 2) + r;
        float S1 = lred[0][lr_][0] + lred[1][lr_][0] + lred[2][lr_][0] + lred[3][lr_][0];
        float S2 = lred[0][lr_][1] + lred[1][lr_][1] + lred[2][lr_][1] + lred[3][lr_][1];
        float mu = S1 * (1.0f / 256.0f);
        float var = S2 * (1.0f / 256.0f) - mu * mu;
        mu_r[r] = mu; rs_r[r] = rsqrtf(var + 1e-5f);
    }
    #pragma unroll
    for (int f = 0; f < 4; f++) {
        int col = (w << 6) + (f << 4) + c;
        float swv = sw[col], bwv = bw[col];
        #pragma unroll
        for (int r = 0; r < 4; r++) {
            float o = (vals[f][r] - mu_r[r]) * rs_r[r] * swv + bwv;
            Z[(size_t)rows[r] * DD + col] = o;
            Zh[(size_t)rows[r] * DD + col] = (_Float16)o;
        }
    }
}

// ---------------- Residual + LN (Z + Y0..Y3), one WAVE per row ----------------
__global__ __launch_bounds__(256) void ln4_k(
    float* __restrict__ Z, const float* __restrict__ Y0,
    const float* __restrict__ Y1, const float* __restrict__ Y2,
    const float* __restrict__ Y3,
    const float* __restrict__ sw, const float* __restrict__ bw,
    _Float16* __restrict__ Zh)
{
    const int w = threadIdx.x >> 6, lane = threadIdx.x & 63;
    const int row = (blockIdx.x << 2) + w;
    float4 z = ((const float4*)(Z + (size_t)row * DD))[lane];
    float4 y0 = ((const float4*)(Y0 + (size_t)row * DD))[lane];
    float4 y1 = ((const float4*)(Y1 + (size_t)row * DD))[lane];
    float4 y2 = ((const float4*)(Y2 + (size_t)row * DD))[lane];
    float4 y3 = ((const float4*)(Y3 + (size_t)row * DD))[lane];
    float x0 = z.x + (y0.x + y1.x) + (y2.x + y3.x);
    float x1 = z.y + (y0.y + y1.y) + (y2.y + y3.y);
    float x2 = z.z + (y0.z + y1.z) + (y2.z + y3.z);
    float x3 = z.w + (y0.w + y1.w) + (y2.w + y3.w);
    float s1 = (x0 + x1) + (x2 + x3);
    float s2 = (x0 * x0 + x1 * x1) + (x2 * x2 + x3 * x3);
    #pragma unroll
    for (int off = 1; off < 64; off <<= 1) {
        s1 += __shfl_xor(s1, off, 64);
        s2 += __shfl_xor(s2, off, 64);
    }
    float mu = s1 * (1.0f / 256.0f);
    float var = s2 * (1.0f / 256.0f) - mu * mu;
    float rs = rsqrtf(var + 1e-5f);
    float4 sv = ((const float4*)sw)[lane];
    float4 bv = ((const float4*)bw)[lane];
    float o0 = (x0 - mu) * rs * sv.x + bv.x;
    float o1 = (x1 - mu) * rs * sv.y + bv.y;
    float o2 = (x2 - mu) * rs * sv.z + bv.z;
    float o3 = (x3 - mu) * rs * sv.w + bv.w;
    ((float4*)(Z + (size_t)row * DD))[lane] = make_float4(o0, o1, o2, o3);
    f16x4 oh = {(_Float16)o0, (_Float16)o1, (_Float16)o2, (_Float16)o3};
    ((f16x4*)(Zh + (size_t)row * DD))[lane] = oh;
}

// ---------------- Final layer: LN (query rows) + output head, fused ----------------
// Y partials are COMPACT (qrow-indexed, M=1024); Z is global-row indexed.
__global__ __launch_bounds__(256) void ln4qo_k(
    const float* __restrict__ Z, const float* __restrict__ Y0,
    const float* __restrict__ Y1, const float* __restrict__ Y2,
    const float* __restrict__ Y3,
    const float* __restrict__ sw, const float* __restrict__ bw,
    const float* __restrict__ Wout, const float* __restrict__ bout,
    float* __restrict__ out)
{
    const int w = threadIdx.x >> 6, lane = threadIdx.x & 63;
    const int qrow = (blockIdx.x << 2) + w;           // 0..1023
    const int row = qremap(qrow);
    float4 z = ((const float4*)(Z + (size_t)row * DD))[lane];
    float4 y0 = ((const float4*)(Y0 + (size_t)qrow * DD))[lane];
    float4 y1 = ((const float4*)(Y1 + (size_t)qrow * DD))[lane];
    float4 y2 = ((const float4*)(Y2 + (size_t)qrow * DD))[lane];
    float4 y3 = ((const float4*)(Y3 + (size_t)qrow * DD))[lane];
    float x0 = z.x + (y0.x + y1.x) + (y2.x + y3.x);
    float x1 = z.y + (y0.y + y1.y) + (y2.y + y3.y);
    float x2 = z.z + (y0.z + y1.z) + (y2.z + y3.z);
    float x3 = z.w + (y0.w + y1.w) + (y2.w + y3.w);
    float s1 = (x0 + x1) + (x2 + x3);
    float s2 = (x0 * x0 + x1 * x1) + (x2 * x2 + x3 * x3);
    #pragma unroll
    for (int off = 1; off < 64; off <<= 1) {
        s1 += __shfl_xor(s1, off, 64);
        s2 += __shfl_xor(s2, off, 64);
    }
    float mu = s1 * (1.0f / 256.0f);
    float var = s2 * (1.0f / 256.0f) - mu * mu;
    float rs = rsqrtf(var + 1e-5f);
    float4 sv = ((const float4*)sw)[lane];
    float4 bv = ((const float4*)bw)[lane];
    float o0 = (x0 - mu) * rs * sv.x + bv.x;
    float o1 = (x1 - mu) * rs * sv.y + bv.y;
    float o2 = (x2 - mu) * rs * sv.z + bv.z;
    float o3 = (x3 - mu) * rs * sv.w + bv.w;
    #pragma unroll
    for (int ho = 0; ho < HOUTD; ho++) {
        float4 wv = ((const float4*)(Wout + (size_t)ho * DD))[lane];
        float s = (o0 * wv.x + o1 * wv.y) + (o2 * wv.z + o3 * wv.w);
        #pragma unroll
        for (int off = 1; off < 64; off <<= 1) s += __shfl_xor(s, off, 64);
        if (lane == ho) out[(size_t)qrow * HOUTD + ho] = s + bout[ho];
    }
}

// ---------------- MFMA flash attention ----------------
// 1024 thr = 16 waves = 2 key-split wg x 8 query tiles (128 q/block).
// tshift: log2(#q-tiles per (b,h)); ibase: row base of tile 0 (0 full, CTX final).
__global__ __launch_bounds__(1024, 4) void attn_k(
    const _Float16* __restrict__ Qf, const _Float16* __restrict__ Kf,
    const _Float16* __restrict__ Vf, const float* __restrict__ tf_all,
    const float* __restrict__ alpha, _Float16* __restrict__ O,
    int tshift, int ibase)
{
    const int bh = blockIdx.x >> tshift;
    const int itile = blockIdx.x & ((1 << tshift) - 1);
    const int b = bh >> 3, h = bh & 7;
    const int tid = threadIdx.x;
    const int w16 = tid >> 6;                 // 0..15
    const int wg = w16 >> 3;                  // key-split 0/1
    const int wq = w16 & 7;                   // query tile 0..7
    const int ltid = tid & 511;               // within wave-group
    const int lane = tid & 63;
    const int c = lane & 15, g = lane >> 4;
    const int i0 = ibase + (itile << 7) + (wq << 4);
    const int jbase = wg * KHALF;

    // K: 40960  V: 34816 (=75776)  tbl: 8192 (=83968)  ptl: 8192 -> 92160
    __shared__ __align__(16) char smem[92160];
    _Float16 (*Kl)[2][128][40] = (_Float16(*)[2][128][40])smem;
    _Float16 (*Vl)[2][32][136] = (_Float16(*)[2][32][136])(smem + 40960);
    float* tbl = (float*)(smem + 75776);
    float* ptl = (float*)(smem + 83968);
    float (*sacc)[16][36] = (float(*)[16][36])smem;
    float (*sml)[2][16] = (float(*)[2][16])(smem + 36864);

    const float LOG2E = 1.44269504088896f;
    const float ah2 = alpha[h] * LOG2E;

    const _Float16* Qbh = Qf + (size_t)bh * S_LEN * DH;
    const _Float16* Kbh = Kf + (size_t)bh * S_LEN * DH;
    const _Float16* Vbh = Vf + (size_t)bh * DH * S_LEN;
    const float* tb = tf_all + b * S_LEN;

    f16x8 qfrag = *(const f16x8*)(Qbh + (size_t)(i0 + c) * DH + (g << 3));
    const float ti = tb[i0 + c];

    const int kr = ltid >> 2, kc = (ltid & 3) << 3;     // K: 128 x 32
    const int vr = ltid >> 4, vc = (ltid & 15) << 3;    // V: 32 x 128

    {
        float t0 = tb[tid], t1 = tb[tid + 1024];
        tbl[tid] = t0; tbl[tid + 1024] = t1;
        ptl[tid] = ah2 * t0; ptl[tid + 1024] = ah2 * t1;
    }

    float m2 = -3.0e38f, l = 0.0f;
    f32x4 acc0 = {0.f, 0.f, 0.f, 0.f};
    f32x4 acc1 = {0.f, 0.f, 0.f, 0.f};
    const f32x4 zero = {0.f, 0.f, 0.f, 0.f};

    f16x8 kpre = *(const f16x8*)(Kbh + (size_t)(jbase + kr) * DH + kc);
    f16x8 vpre = *(const f16x8*)(Vbh + (size_t)vr * S_LEN + jbase + vc);
    int buf = 0;

    for (int kt = 0; kt < KHALF; kt += 128) {
        *(f16x8*)&Kl[wg][buf][kr][kc] = kpre;
        *(f16x8*)&Vl[wg][buf][vr][vc] = vpre;
        __syncthreads();
        if (kt + 128 < KHALF) {
            kpre = *(const f16x8*)(Kbh + (size_t)(jbase + kt + 128 + kr) * DH + kc);
            vpre = *(const f16x8*)(Vbh + (size_t)vr * S_LEN + jbase + kt + 128 + vc);
        }
        #pragma unroll
        for (int jj = 0; jj < 128; jj += 32) {
            const int j0 = jbase + kt + jj;
            f16x8 kf0 = *(const f16x8*)&Kl[wg][buf][jj + c][g << 3];
            f16x8 kf1 = *(const f16x8*)&Kl[wg][buf][jj + 16 + c][g << 3];
            __builtin_amdgcn_s_setprio(1);
            f32x4 dA = __builtin_amdgcn_mfma_f32_16x16x32_f16(kf0, qfrag, zero, 0, 0, 0);
            f32x4 dB = __builtin_amdgcn_mfma_f32_16x16x32_f16(kf1, qfrag, zero, 0, 0, 0);
            __builtin_amdgcn_s_setprio(0);
            float4 tjA = *(const float4*)&tbl[j0 + (g << 2)];
            float4 tjB = *(const float4*)&tbl[j0 + 16 + (g << 2)];
            float4 ptA = *(const float4*)&ptl[j0 + (g << 2)];
            float4 ptB = *(const float4*)&ptl[j0 + 16 + (g << 2)];
            float sA0 = (tjA.x <= ti) ? dA[0] + ptA.x : -1e9f;
            float sA1 = (tjA.y <= ti) ? dA[1] + ptA.y : -1e9f;
            float sA2 = (tjA.z <= ti) ? dA[2] + ptA.z : -1e9f;
            float sA3 = (tjA.w <= ti) ? dA[3] + ptA.w : -1e9f;
            float sB0 = (tjB.x <= ti) ? dB[0] + ptB.x : -1e9f;
            float sB1 = (tjB.y <= ti) ? dB[1] + ptB.y : -1e9f;
            float sB2 = (tjB.z <= ti) ? dB[2] + ptB.z : -1e9f;
            float sB3 = (tjB.w <= ti) ? dB[3] + ptB.w : -1e9f;
            float pmaxl = fmaxf(fmaxf(fmaxf(sA0, sA1), fmaxf(sA2, sA3)),
                                fmaxf(fmaxf(sB0, sB1), fmaxf(sB2, sB3)));
            if (__any(pmaxl > m2 + 8.0f)) {
                float pm = fmaxf(pmaxl, __shfl_xor(pmaxl, 16, 64));
                pm = fmaxf(pm, __shfl_xor(pm, 32, 64));
                float mnew = fmaxf(m2, pm);
                float fsc = __builtin_amdgcn_exp2f(m2 - mnew);
                m2 = mnew;
                l *= fsc; acc0 *= fsc; acc1 *= fsc;
            }
            float pA0 = __builtin_amdgcn_exp2f(sA0 - m2);
            float pA1 = __builtin_amdgcn_exp2f(sA1 - m2);
            float pA2 = __builtin_amdgcn_exp2f(sA2 - m2);
            float pA3 = __builtin_amdgcn_exp2f(sA3 - m2);
            float pB0 = __builtin_amdgcn_exp2f(sB0 - m2);
            float pB1 = __builtin_amdgcn_exp2f(sB1 - m2);
            float pB2 = __builtin_amdgcn_exp2f(sB2 - m2);
            float pB3 = __builtin_amdgcn_exp2f(sB3 - m2);
            l += ((pA0 + pA1) + (pA2 + pA3)) + ((pB0 + pB1) + (pB2 + pB3));
            f16x4 pfA = {(_Float16)pA0, (_Float16)pA1, (_Float16)pA2, (_Float16)pA3};
            f16x4 pfB = {(_Float16)pB0, (_Float16)pB1, (_Float16)pB2, (_Float16)pB3};
            f16x4 vA0 = *(const f16x4*)&Vl[wg][buf][c][jj + (g << 2)];
            f16x4 vA1 = *(const f16x4*)&Vl[wg][buf][16 + c][jj + (g << 2)];
            f16x4 vB0 = *(const f16x4*)&Vl[wg][buf][c][jj + 16 + (g << 2)];
            f16x4 vB1 = *(const f16x4*)&Vl[wg][buf][16 + c][jj + 16 + (g << 2)];
            __builtin_amdgcn_s_setprio(1);
            acc0 = __builtin_amdgcn_mfma_f32_16x16x16f16(vA0, pfA, acc0, 0, 0, 0);
            acc0 = __builtin_amdgcn_mfma_f32_16x16x16f16(vB0, pfB, acc0, 0, 0, 0);
            acc1 = __builtin_amdgcn_mfma_f32_16x16x16f16(vA1, pfA, acc1, 0, 0, 0);
            acc1 = __builtin_amdgcn_mfma_f32_16x16x16f16(vB1, pfB, acc1, 0, 0, 0);
            __builtin_amdgcn_s_setprio(0);
        }
        buf ^= 1;
    }

    l += __shfl_xor(l, 16, 64);
    l += __shfl_xor(l, 32, 64);

    __syncthreads();
    *(f32x4*)&sacc[w16][c][g << 2] = acc0;
    *(f32x4*)&sacc[w16][c][16 + (g << 2)] = acc1;
    if (g == 0) { sml[w16][0][c] = m2; sml[w16][1][c] = l; }
    __syncthreads();

    {
        const int qt = tid >> 7;
        const int q = (tid >> 3) & 15;
        const int dh0 = (tid & 7) << 2;
        float m0 = sml[qt][0][q], m1 = sml[qt + 8][0][q];
        float M = fmaxf(m0, m1);
        float f0 = __builtin_amdgcn_exp2f(m0 - M);
        float f1 = __builtin_amdgcn_exp2f(m1 - M);
        float L = sml[qt][1][q] * f0 + sml[qt + 8][1][q] * f1;
        float a0 = sacc[qt][q][dh0 + 0] * f0 + sacc[qt + 8][q][dh0 + 0] * f1;
        float a1 = sacc[qt][q][dh0 + 1] * f0 + sacc[qt + 8][q][dh0 + 1] * f1;
        float a2 = sacc[qt][q][dh0 + 2] * f0 + sacc[qt + 8][q][dh0 + 2] * f1;
        float a3 = sacc[qt][q][dh0 + 3] * f0 + sacc[qt + 8][q][dh0 + 3] * f1;
        if (M < -4.9e8f) {
            float vs0 = 0.f, vs1 = 0.f, vs2 = 0.f, vs3 = 0.f;
            const _Float16* vp = Vbh + (size_t)dh0 * S_LEN + CTX;
            for (int j = 0; j < QQ; j += 8) {
                f16x8 x0 = *(const f16x8*)(vp + j);
                f16x8 x1 = *(const f16x8*)(vp + S_LEN + j);
                f16x8 x2 = *(const f16x8*)(vp + 2 * S_LEN + j);
                f16x8 x3 = *(const f16x8*)(vp + 3 * S_LEN + j);
                #pragma unroll
                for (int e = 0; e < 8; e++) {
                    vs0 += (float)x0[e]; vs1 += (float)x1[e];
                    vs2 += (float)x2[e]; vs3 += (float)x3[e];
                }
            }
            a0 += vs0; a1 += vs1; a2 += vs2; a3 += vs3;
            L += (float)QQ;
        }
        float inv = 1.0f / L;
        int row = b * S_LEN + ibase + (itile << 7) + (qt << 4) + q;
        f16x4 o = {(_Float16)(a0 * inv), (_Float16)(a1 * inv),
                   (_Float16)(a2 * inv), (_Float16)(a3 * inv)};
        *(f16x4*)(O + (size_t)row * DD + h * DH + dh0) = o;
    }
}

extern "C" void kernel_launch(void* const* d_in, const int* in_sizes, int n_in,
                              void* d_out, int out_size, void* d_ws, size_t ws_size,
                              hipStream_t stream) {
    (void)in_sizes; (void)n_in; (void)out_size; (void)ws_size;
    const float* ctx_x = (const float*)d_in[0];
    const float* ctx_z = (const float*)d_in[1];
    const float* qry_x = (const float*)d_in[2];
    const int* t_ctx = (const int*)d_in[3];
    const int* t_qry = (const int*)d_in[4];
    const float* W_ctx = (const float*)d_in[5];
    const float* b_ctx = (const float*)d_in[6];
    const float* W_qry = (const float*)d_in[7];
    const float* b_qry = (const float*)d_in[8];
    const float* alpha = (const float*)d_in[9];
    const float* Wqkv = (const float*)d_in[10];
    const float* bqkv = (const float*)d_in[11];
    const float* Wo = (const float*)d_in[12];
    const float* bo = (const float*)d_in[13];
    const float* ln1_s = (const float*)d_in[14];
    const float* ln1_b = (const float*)d_in[15];
    const float* W1 = (const float*)d_in[16];
    const float* b1 = (const float*)d_in[17];
    const float* W2 = (const float*)d_in[18];
    const float* b2 = (const float*)d_in[19];
    const float* ln2_s = (const float*)d_in[20];
    const float* ln2_b = (const float*)d_in[21];
    const float* W_out = (const float*)d_in[22];
    const float* b_out = (const float*)d_in[23];

    float* ws = (float*)d_ws;
    const size_t MTOT = (size_t)BB * S_LEN;       // 4096
    const size_t ZSZ = MTOT * DD;                 // 1M floats
    float* Z   = ws;                              // [0, 1M) f32
    float* Yb  = ws + ZSZ;                        // [1M, 2M) f32
    _Float16* Zh   = (_Float16*)(ws + 2 * ZSZ);          // 1M halfs
    _Float16* AYh  = (_Float16*)(ws + 2 * ZSZ + ZSZ / 2);
    _Float16* FF1h = (_Float16*)(ws + 3 * ZSZ);          // 4M halfs -> [3M,5M)
    _Float16* Qh   = (_Float16*)(ws + 5 * ZSZ);
    _Float16* Kh   = (_Float16*)(ws + 5 * ZSZ + ZSZ / 2);
    _Float16* Vh   = (_Float16*)(ws + 6 * ZSZ);
    float* tf_all  = ws + 6 * ZSZ + ZSZ / 2;             // 4096 floats
    _Float16* Whqkv = (_Float16*)(ws + 6 * ZSZ + ZSZ / 2 + 4096);
    _Float16* Who   = Whqkv + (size_t)NL * 3 * DD * DD;
    _Float16* Wh1   = Who   + (size_t)NL * DD * DD;
    _Float16* Wh2   = Wh1   + (size_t)NL * DFF * DD;
    float* Yb1 = ws + 9 * ZSZ;
    float* Yb2 = ws + 10 * ZSZ;
    float* Yb3 = ws + 11 * ZSZ;

    {
        int n4tot = N4_QKV + N4_WO + N4_W1 + N4_W2;
        cvtall_k<<<(n4tot + 255) / 256, 256, 0, stream>>>(
            Wqkv, Wo, W1, W2, Whqkv, Who, Wh1, Wh2);
    }

    embed_k<<<MTOT, 256, 0, stream>>>(ctx_x, ctx_z, qry_x, W_ctx, b_ctx, W_qry, b_qry,
                                      t_ctx, t_qry, Z, Zh, tf_all);

    for (int l = 0; l < NL; l++) {
        const bool last = (l == NL - 1);
        const int Mff = last ? (BB * QQ) : (int)MTOT;   // FFN rows this layer
        hgemm_k<<<dim3(MTOT / 64, (3 * DD) / 64, 1), 256, 0, stream>>>(
            Zh, Whqkv + (size_t)l * 3 * DD * DD, bqkv + (size_t)l * 3 * DD,
            nullptr, nullptr, nullptr, nullptr, nullptr,
            (int)MTOT, 3 * DD, DD, DD, 2, 0, Qh, Kh, Vh);
        if (!last) {
            attn_k<<<BB * NH * (S_LEN / 128), 1024, 0, stream>>>(
                Qh, Kh, Vh, tf_all, alpha, AYh, 4, 0);
        } else {
            attn_k<<<BB * NH * (QQ / 128), 1024, 0, stream>>>(
                Qh, Kh, Vh, tf_all, alpha, AYh, 2, CTX);
        }
        gemmln_k<<<Mff / 16, 256, 0, stream>>>(
            AYh, Who + (size_t)l * DD * DD, bo + (size_t)l * DD,
            Z, Zh, ln1_s + (size_t)l * DD, ln1_b + (size_t)l * DD, last ? 1 : 0);
        hgemm_k<<<dim3(Mff / 64, DFF / 64, 1), 256, 0, stream>>>(
            Zh, Wh1 + (size_t)l * DFF * DD, b1 + (size_t)l * DFF,
            nullptr, nullptr, nullptr, nullptr, FF1h,
            Mff, DFF, DD, DD, 1, last ? 1 : 0, nullptr, nullptr, nullptr);
        hgemm_k<<<dim3(Mff / 64, DD / 64, 4), 256, 0, stream>>>(
            FF1h, Wh2 + (size_t)l * DD * DFF, b2 + (size_t)l * DD,
            Yb, Yb1, Yb2, Yb3, nullptr,
            Mff, DD, DFF / 4, DFF, 0, 0, nullptr, nullptr, nullptr);
        if (!last) {
            ln4_k<<<MTOT / 4, 256, 0, stream>>>(
                Z, Yb, Yb1, Yb2, Yb3,
                ln2_s + (size_t)l * DD, ln2_b + (size_t)l * DD, Zh);
        } else {
            ln4qo_k<<<(BB * QQ) / 4, 256, 0, stream>>>(
                Z, Yb, Yb1, Yb2, Yb3,
                ln2_s + (size_t)l * DD, ln2_b + (size_t)l * DD,
                W_out, b_out, (float*)d_out);
        }
    }
}